// Round 6
// baseline (9761.785 us; speedup 1.0000x reference)
//
#include <hip/hip_runtime.h>
#include <math.h>

typedef __attribute__((ext_vector_type(8))) short bf16x8;
typedef __attribute__((ext_vector_type(4))) float f32x4;
typedef unsigned short u16;

namespace {
constexpr int Bc = 64, Tc = 12, Nn = 1024, Hc = 64, Ec = 10;
constexpr int NB = Nn * Bc;  // 65536
constexpr int Cc = 66;       // unified channel count (enc uses 65, col 65 zeroed)
constexpr int SA = 208;      // XA row stride ([X(66)|Y1(66)|Y2(66)|pad10])
constexpr int KP = 224;      // padded K for gate/update GEMMs (7 x 32)
constexpr int KD = Bc * Ec;  // 640, dec gram K
constexpr int TN = Tc * Nn;  // 12288
}

#define SWZ(r) (((r) >> 1) & 3)

__device__ __forceinline__ void gld16(const void* g, void* l) {
  __builtin_amdgcn_global_load_lds(
      (const __attribute__((address_space(1))) void*)g,
      (__attribute__((address_space(3))) void*)l, 16, 0, 0);
}

// split fp32 -> bf16 hi + bf16 lo (RNE both)
__device__ __forceinline__ void split_bf(float v, u16& h, u16& l) {
  unsigned u = __float_as_uint(v);
  unsigned hu = (u + 0x7FFFu + ((u >> 16) & 1u)) & 0xFFFF0000u;
  h = (u16)(hu >> 16);
  float r = v - __uint_as_float(hu);
  unsigned u2 = __float_as_uint(r);
  l = (u16)((u2 + 0x7FFFu + ((u2 >> 16) & 1u)) >> 16);
}
__device__ __forceinline__ u16 bf_rne(float v) {
  unsigned u = __float_as_uint(v);
  return (u16)((u + 0x7FFFu + ((u >> 16) & 1u)) >> 16);
}
__device__ __forceinline__ bf16x8 ldfrag(const u16* p) {
  return *(const bf16x8*)p;
}

// ---------- enc gram: G = emb @ emb^T (Kd small, fp32) ----------
__global__ __launch_bounds__(256) void k_gram(const float* __restrict__ in, int Kd,
                                              float* __restrict__ G) {
  __shared__ float At[16][64];
  __shared__ float Bt[16][64];
  int i0 = blockIdx.y * 64, j0 = blockIdx.x * 64;
  int tx = threadIdx.x & 15, ty = threadIdx.x >> 4;
  float acc[4][4] = {};
  for (int k0 = 0; k0 < Kd; k0 += 16) {
    for (int u = threadIdx.x; u < 1024; u += 256) {
      int i = u >> 4, k = u & 15;
      At[k][i] = (k0 + k < Kd) ? in[(size_t)(i0 + i) * Kd + k0 + k] : 0.f;
    }
    for (int u = threadIdx.x; u < 1024; u += 256) {
      int j = u >> 4, k = u & 15;
      Bt[k][j] = (k0 + k < Kd) ? in[(size_t)(j0 + j) * Kd + k0 + k] : 0.f;
    }
    __syncthreads();
#pragma unroll
    for (int kk = 0; kk < 16; kk++) {
      float a[4], b[4];
#pragma unroll
      for (int p = 0; p < 4; p++) a[p] = At[kk][ty * 4 + p];
#pragma unroll
      for (int q = 0; q < 4; q++) b[q] = Bt[kk][tx * 4 + q];
#pragma unroll
      for (int p = 0; p < 4; p++)
#pragma unroll
        for (int q = 0; q < 4; q++) acc[p][q] = fmaf(a[p], b[q], acc[p][q]);
    }
    __syncthreads();
  }
  for (int p = 0; p < 4; p++)
    for (int q = 0; q < 4; q++)
      G[(size_t)(i0 + ty * 4 + p) * Nn + j0 + tx * 4 + q] = acc[p][q];
}

// ---------- dec gram via split-MFMA: G = DE @ DE^T (LDS staged, 1 dispatch) ----------
__global__ __launch_bounds__(256) void k_gram_mfma(const u16* __restrict__ Dh,
                                                   const u16* __restrict__ Dl,
                                                   float* __restrict__ G) {
  __shared__ u16 lds[12288];
  const int tid = threadIdx.x;
  const int wave = tid >> 6, lane = tid & 63;
  const int i0 = blockIdx.y * 64;
  const int j0 = blockIdx.x * 128;
  const int wy = wave >> 1, wx = wave & 1;
  const int m = lane & 15, quad = lane >> 4;

  f32x4 acc[2][4];
  f32x4 z4 = {0.f, 0.f, 0.f, 0.f};
#pragma unroll
  for (int a = 0; a < 2; a++)
#pragma unroll
    for (int q = 0; q < 4; q++) acc[a][q] = z4;

  const int ar = tid >> 2;
  const int akc = (tid & 3) ^ SWZ(ar);

  for (int k0 = 0; k0 < KD; k0 += 32) {
    gld16(Dh + (size_t)(i0 + ar) * KD + k0 + akc * 8, &lds[wave * 512]);
    gld16(Dl + (size_t)(i0 + ar) * KD + k0 + akc * 8, &lds[2048 + wave * 512]);
#pragma unroll
    for (int p = 0; p < 2; p++) {
      int r = p * 64 + (tid >> 2);
      int kc = (tid & 3) ^ SWZ(r);
      gld16(Dh + (size_t)(j0 + r) * KD + k0 + kc * 8, &lds[4096 + p * 2048 + wave * 512]);
      gld16(Dl + (size_t)(j0 + r) * KD + k0 + kc * 8, &lds[8192 + p * 2048 + wave * 512]);
    }
    __syncthreads();

    bf16x8 ah[2], al[2], bh[4], bl[4];
#pragma unroll
    for (int mb = 0; mb < 2; mb++) {
      int r = wy * 32 + mb * 16 + m;
      int ci = r * 4 + (quad ^ SWZ(r));
      ah[mb] = *(const bf16x8*)&lds[ci * 8];
      al[mb] = *(const bf16x8*)&lds[2048 + ci * 8];
    }
#pragma unroll
    for (int nb = 0; nb < 4; nb++) {
      int rj = wx * 64 + nb * 16 + m;
      int cj = rj * 4 + (quad ^ SWZ(rj));
      bh[nb] = *(const bf16x8*)&lds[4096 + cj * 8];
      bl[nb] = *(const bf16x8*)&lds[8192 + cj * 8];
    }
#pragma unroll
    for (int mb = 0; mb < 2; mb++)
#pragma unroll
      for (int nb = 0; nb < 4; nb++) {
        acc[mb][nb] = __builtin_amdgcn_mfma_f32_16x16x32_bf16(ah[mb], bh[nb], acc[mb][nb], 0, 0, 0);
        acc[mb][nb] = __builtin_amdgcn_mfma_f32_16x16x32_bf16(ah[mb], bl[nb], acc[mb][nb], 0, 0, 0);
        acc[mb][nb] = __builtin_amdgcn_mfma_f32_16x16x32_bf16(al[mb], bh[nb], acc[mb][nb], 0, 0, 0);
      }
    __syncthreads();
  }

#pragma unroll
  for (int mb = 0; mb < 2; mb++)
#pragma unroll
    for (int nb = 0; nb < 4; nb++) {
      int col = j0 + wx * 64 + nb * 16 + m;
#pragma unroll
      for (int p = 0; p < 4; p++) {
        int row = i0 + wy * 32 + mb * 16 + quad * 4 + p;
        G[(size_t)row * Nn + col] = acc[mb][nb][p];
      }
    }
}

// ---------- S = row_softmax(relu(G)) -> split directly to S1h/S1l ----------
__global__ __launch_bounds__(256) void k_softmax(const float* __restrict__ G,
                                                 u16* __restrict__ S1h,
                                                 u16* __restrict__ S1l) {
  __shared__ float sred[8];
  int n = blockIdx.x;
  float v[4];
#pragma unroll
  for (int i = 0; i < 4; i++)
    v[i] = fmaxf(G[(size_t)n * Nn + threadIdx.x + i * 256], 0.f);
  float mx = fmaxf(fmaxf(v[0], v[1]), fmaxf(v[2], v[3]));
  for (int off = 32; off > 0; off >>= 1) mx = fmaxf(mx, __shfl_down(mx, off));
  if ((threadIdx.x & 63) == 0) sred[threadIdx.x >> 6] = mx;
  __syncthreads();
  float rmax = fmaxf(fmaxf(sred[0], sred[1]), fmaxf(sred[2], sred[3]));
  float s = 0.f;
#pragma unroll
  for (int i = 0; i < 4; i++) { v[i] = expf(v[i] - rmax); s += v[i]; }
  for (int off = 32; off > 0; off >>= 1) s += __shfl_down(s, off);
  if ((threadIdx.x & 63) == 0) sred[4 + (threadIdx.x >> 6)] = s;
  __syncthreads();
  float inv = 1.f / (sred[4] + sred[5] + sred[6] + sred[7]);
#pragma unroll
  for (int i = 0; i < 4; i++) {
    u16 h, l;
    split_bf(v[i] * inv, h, l);
    size_t a = (size_t)n * Nn + threadIdx.x + i * 256;
    S1h[a] = h; S1l[a] = l;
  }
}

// ---------- transpose S1h/S1l -> Sth/Stl (64x64 LDS tiles) ----------
__global__ __launch_bounds__(256) void k_tr2(const u16* __restrict__ Ah,
                                             const u16* __restrict__ Al,
                                             u16* __restrict__ Th, u16* __restrict__ Tl) {
  __shared__ u16 sm[64][72];
  int i0 = blockIdx.y * 64, j0 = blockIdx.x * 64;
  int tid = threadIdx.x;
  for (int pass = 0; pass < 2; pass++) {
    const u16* src = pass ? Al : Ah;
    u16* dst = pass ? Tl : Th;
    for (int u = tid; u < 4096; u += 256) {
      int i = u >> 6, c = u & 63;
      sm[i][c] = src[(size_t)(i0 + i) * Nn + j0 + c];
    }
    __syncthreads();
    for (int u = tid; u < 4096; u += 256) {
      int c = u >> 6, i = u & 63;
      dst[(size_t)(j0 + c) * Nn + i0 + i] = sm[i][c];
    }
    __syncthreads();
  }
}

// ---------- S2 = 2*S@S - I via direct-fragment split MFMA (no LDS) ----------
// A = S1h/l rows (i); B = Sth/l rows (j). 3-term. Out split to S2h/S2l.
__global__ __launch_bounds__(256) void k_s2_mfma(const u16* __restrict__ S1h,
                                                 const u16* __restrict__ S1l,
                                                 const u16* __restrict__ Sth,
                                                 const u16* __restrict__ Stl,
                                                 u16* __restrict__ S2h,
                                                 u16* __restrict__ S2l) {
  const int tid = threadIdx.x;
  const int wave = tid >> 6, lane = tid & 63;
  const int i0 = blockIdx.y * 64, j0 = blockIdx.x * 128;
  const int wy = wave >> 1, wx = wave & 1;
  const int m = lane & 15, quad = lane >> 4;

  const size_t aoff = (size_t)(i0 + wy * 32 + m) * Nn + quad * 8;
  const size_t boff = (size_t)(j0 + wx * 64 + m) * Nn + quad * 8;

  f32x4 acc[2][4];
  f32x4 z4 = {0.f, 0.f, 0.f, 0.f};
#pragma unroll
  for (int a = 0; a < 2; a++)
#pragma unroll
    for (int q = 0; q < 4; q++) acc[a][q] = z4;

  bf16x8 fAh[2][2], fAl[2][2], fBh[2][4], fBl[2][4];
  auto ld = [&](int k0, int s) {
#pragma unroll
    for (int mb = 0; mb < 2; mb++) {
      fAh[s][mb] = ldfrag(S1h + aoff + (size_t)mb * 16 * Nn + k0);
      fAl[s][mb] = ldfrag(S1l + aoff + (size_t)mb * 16 * Nn + k0);
    }
#pragma unroll
    for (int nb = 0; nb < 4; nb++) {
      fBh[s][nb] = ldfrag(Sth + boff + (size_t)nb * 16 * Nn + k0);
      fBl[s][nb] = ldfrag(Stl + boff + (size_t)nb * 16 * Nn + k0);
    }
  };
  ld(0, 0);
#pragma unroll 2
  for (int kt = 0; kt < 32; kt++) {
    int cur = kt & 1;
    if (kt < 31) ld((kt + 1) * 32, cur ^ 1);
#pragma unroll
    for (int mb = 0; mb < 2; mb++)
#pragma unroll
      for (int nb = 0; nb < 4; nb++) {
        acc[mb][nb] = __builtin_amdgcn_mfma_f32_16x16x32_bf16(fAh[cur][mb], fBh[cur][nb], acc[mb][nb], 0, 0, 0);
        acc[mb][nb] = __builtin_amdgcn_mfma_f32_16x16x32_bf16(fAh[cur][mb], fBl[cur][nb], acc[mb][nb], 0, 0, 0);
        acc[mb][nb] = __builtin_amdgcn_mfma_f32_16x16x32_bf16(fAl[cur][mb], fBh[cur][nb], acc[mb][nb], 0, 0, 0);
      }
  }

#pragma unroll
  for (int mb = 0; mb < 2; mb++)
#pragma unroll
    for (int nb = 0; nb < 4; nb++) {
      int col = j0 + wx * 64 + nb * 16 + m;
#pragma unroll
      for (int p = 0; p < 4; p++) {
        int row = i0 + wy * 32 + mb * 16 + quad * 4 + p;
        float v = 2.f * acc[mb][nb][p] - (row == col ? 1.f : 0.f);
        u16 vh, vl;
        split_bf(v, vh, vl);
        size_t a = (size_t)row * Nn + col;
        S2h[a] = vh; S2l[a] = vl;
      }
    }
}

// ---------- Wt prep ----------
__global__ __launch_bounds__(256) void k_prep_wt(const float* __restrict__ W, int Csrc,
                                                 int ncol, u16* __restrict__ Wh,
                                                 u16* __restrict__ Wl) {
  int idx = blockIdx.x * 256 + threadIdx.x;
  if (idx >= ncol * KP) return;
  int n = idx / KP, kp = idx % KP;
  int chunk = kp / Cc, c = kp % Cc;
  float v = 0.f;
  if (kp < 3 * Cc && c < Csrc) v = W[((size_t)chunk * Csrc + c) * ncol + n];
  u16 h, l;
  split_bf(v, h, l);
  Wh[idx] = h; Wl[idx] = l;
}

// ---------- fill enc: XA col0 = x_t (hi/lo) + Xth row (b*66+0) ----------
__global__ __launch_bounds__(256) void k_fill_enc(const float* __restrict__ x,
                                                  u16* __restrict__ XAh, u16* __restrict__ XAl,
                                                  u16* __restrict__ Xth, int t) {
  int idx = blockIdx.x * 256 + threadIdx.x;
  if (idx >= NB) return;
  int n = idx >> 6, b = idx & 63;
  float v = x[(size_t)b * TN + t * Nn + n];
  u16 h, l;
  split_bf(v, h, l);
  XAh[(size_t)idx * SA] = h; XAl[(size_t)idx * SA] = l;
  Xth[(size_t)b * Cc * Nn + n] = bf_rne(v);
}

// ---------- dec init ----------
__global__ __launch_bounds__(256) void k_dec_init(const float* __restrict__ x,
                                                  const float* __restrict__ ycov,
                                                  u16* __restrict__ XAh, u16* __restrict__ XAl,
                                                  u16* __restrict__ Xth) {
  int idx = blockIdx.x * 256 + threadIdx.x;
  if (idx >= NB) return;
  int n = idx >> 6, b = idx & 63;
  float v0 = x[(size_t)b * TN + (size_t)(Tc - 1) * Nn + n];
  float v1 = ycov[(size_t)b * TN + n];
  u16 h, l;
  split_bf(v0, h, l);
  XAh[(size_t)idx * SA] = h; XAl[(size_t)idx * SA] = l;
  split_bf(v1, h, l);
  XAh[(size_t)idx * SA + 1] = h; XAl[(size_t)idx * SA + 1] = l;
  Xth[((size_t)b * Cc) * Nn + n] = bf_rne(v0);
  Xth[((size_t)b * Cc + 1) * Nn + n] = bf_rne(v1);
}

// ---------- ygemm: Y1 = S@X, Y2 = S2@X. Direct-fragment, no LDS, no barriers ----------
// BM=64 (n), BN=128 (j=(b,c)); 4 waves 2x2, wave tile 32x64; K=1024
__global__ __launch_bounds__(256) void k_ygemm(const u16* __restrict__ S1h, const u16* __restrict__ S1l,
                                               const u16* __restrict__ S2h, const u16* __restrict__ S2l,
                                               const u16* __restrict__ Xth,
                                               u16* __restrict__ XAh, u16* __restrict__ XAl) {
  const int tid = threadIdx.x;
  const int wave = tid >> 6, lane = tid & 63;
  const int i0 = blockIdx.y * 64, j0 = blockIdx.x * 128;
  const int wy = wave >> 1, wx = wave & 1;
  const int m = lane & 15, quad = lane >> 4;

  const size_t aoff = (size_t)(i0 + wy * 32 + m) * Nn + quad * 8;
  const size_t boff = (size_t)(j0 + wx * 64 + m) * Nn + quad * 8;

  f32x4 acc1[2][4], acc2[2][4];
  f32x4 z4 = {0.f, 0.f, 0.f, 0.f};
#pragma unroll
  for (int a = 0; a < 2; a++)
#pragma unroll
    for (int q = 0; q < 4; q++) { acc1[a][q] = z4; acc2[a][q] = z4; }

  bf16x8 fA1h[2][2], fA1l[2][2], fA2h[2][2], fA2l[2][2], fB[2][4];
  auto ld = [&](int k0, int s) {
#pragma unroll
    for (int mb = 0; mb < 2; mb++) {
      size_t o = aoff + (size_t)mb * 16 * Nn + k0;
      fA1h[s][mb] = ldfrag(S1h + o);
      fA1l[s][mb] = ldfrag(S1l + o);
      fA2h[s][mb] = ldfrag(S2h + o);
      fA2l[s][mb] = ldfrag(S2l + o);
    }
#pragma unroll
    for (int nb = 0; nb < 4; nb++)
      fB[s][nb] = ldfrag(Xth + boff + (size_t)nb * 16 * Nn + k0);
  };
  ld(0, 0);
#pragma unroll 2
  for (int kt = 0; kt < 32; kt++) {
    int cur = kt & 1;
    if (kt < 31) ld((kt + 1) * 32, cur ^ 1);
#pragma unroll
    for (int mb = 0; mb < 2; mb++)
#pragma unroll
      for (int nb = 0; nb < 4; nb++) {
        acc1[mb][nb] = __builtin_amdgcn_mfma_f32_16x16x32_bf16(fA1h[cur][mb], fB[cur][nb], acc1[mb][nb], 0, 0, 0);
        acc1[mb][nb] = __builtin_amdgcn_mfma_f32_16x16x32_bf16(fA1l[cur][mb], fB[cur][nb], acc1[mb][nb], 0, 0, 0);
        acc2[mb][nb] = __builtin_amdgcn_mfma_f32_16x16x32_bf16(fA2h[cur][mb], fB[cur][nb], acc2[mb][nb], 0, 0, 0);
        acc2[mb][nb] = __builtin_amdgcn_mfma_f32_16x16x32_bf16(fA2l[cur][mb], fB[cur][nb], acc2[mb][nb], 0, 0, 0);
      }
  }

#pragma unroll
  for (int mb = 0; mb < 2; mb++)
#pragma unroll
    for (int nb = 0; nb < 4; nb++) {
      int col = j0 + wx * 64 + nb * 16 + m;
      int bb = col / Cc, cc = col % Cc;
#pragma unroll
      for (int p = 0; p < 4; p++) {
        int row = i0 + wy * 32 + mb * 16 + quad * 4 + p;
        size_t base = ((size_t)row * 64 + bb) * SA;
        u16 vh, vl;
        split_bf(acc1[mb][nb][p], vh, vl);
        XAh[base + 66 + cc] = vh; XAl[base + 66 + cc] = vl;
        split_bf(acc2[mb][nb][p], vh, vl);
        XAh[base + 132 + cc] = vh; XAl[base + 132 + cc] = vl;
      }
    }
}

// ---------- gate: sigmoid(XA@W^T+b) -> Rb; z*h -> XA state cols + Xth ----------
// BM=128, BN=128, K=224. Direct-fragment, no LDS.
__global__ __launch_bounds__(256) void k_gate(const u16* __restrict__ XAh, const u16* __restrict__ XAl,
                                              const u16* __restrict__ Wh, const u16* __restrict__ Wl,
                                              const float* __restrict__ bias,
                                              const float* __restrict__ hst,
                                              float* __restrict__ Rb,
                                              u16* __restrict__ XAho, u16* __restrict__ XAlo,
                                              u16* __restrict__ Xth, int off) {
  const int tid = threadIdx.x;
  const int wave = tid >> 6, lane = tid & 63;
  const int r0 = blockIdx.x * 128;
  const int wy = wave >> 1, wx = wave & 1;
  const int m = lane & 15, quad = lane >> 4;

  const size_t aoff = (size_t)(r0 + wy * 64 + m) * SA + quad * 8;
  const size_t boff = (size_t)(wx * 64 + m) * KP + quad * 8;

  f32x4 acc[4][4];
  f32x4 z4 = {0.f, 0.f, 0.f, 0.f};
#pragma unroll
  for (int a = 0; a < 4; a++)
#pragma unroll
    for (int q = 0; q < 4; q++) acc[a][q] = z4;

  bf16x8 fAh[2][4], fAl[2][4], fBh[2][4], fBl[2][4];
  auto ld = [&](int k0, int s) {
#pragma unroll
    for (int mb = 0; mb < 4; mb++) {
      size_t o = aoff + (size_t)mb * 16 * SA + k0;
      fAh[s][mb] = ldfrag(XAh + o);
      fAl[s][mb] = ldfrag(XAl + o);
    }
#pragma unroll
    for (int nb = 0; nb < 4; nb++) {
      size_t o = boff + (size_t)nb * 16 * KP + k0;
      fBh[s][nb] = ldfrag(Wh + o);
      fBl[s][nb] = ldfrag(Wl + o);
    }
  };
  ld(0, 0);
#pragma unroll
  for (int kt = 0; kt < 7; kt++) {
    int cur = kt & 1;
    if (kt < 6) ld((kt + 1) * 32, cur ^ 1);
#pragma unroll
    for (int mb = 0; mb < 4; mb++)
#pragma unroll
      for (int nb = 0; nb < 4; nb++) {
        acc[mb][nb] = __builtin_amdgcn_mfma_f32_16x16x32_bf16(fAh[cur][mb], fBh[cur][nb], acc[mb][nb], 0, 0, 0);
        acc[mb][nb] = __builtin_amdgcn_mfma_f32_16x16x32_bf16(fAh[cur][mb], fBl[cur][nb], acc[mb][nb], 0, 0, 0);
        acc[mb][nb] = __builtin_amdgcn_mfma_f32_16x16x32_bf16(fAl[cur][mb], fBh[cur][nb], acc[mb][nb], 0, 0, 0);
      }
  }

#pragma unroll
  for (int mb = 0; mb < 4; mb++)
#pragma unroll
    for (int nb = 0; nb < 4; nb++) {
      int col = wx * 64 + nb * 16 + m;
      float bv = bias[col];
#pragma unroll
      for (int p = 0; p < 4; p++) {
        int row = r0 + wy * 64 + mb * 16 + quad * 4 + p;
        float sg = 1.f / (1.f + expf(-(acc[mb][nb][p] + bv)));
        if (col < 64) {
          float v = sg * hst[(size_t)row * 64 + col];
          u16 vh, vl;
          split_bf(v, vh, vl);
          size_t a = (size_t)row * SA + off + col;
          XAho[a] = vh; XAlo[a] = vl;
          int n = row >> 6, b = row & 63;
          Xth[((size_t)b * Cc + off + col) * Nn + n] = bf_rne(v);
        } else {
          Rb[(size_t)row * 64 + col - 64] = sg;
        }
      }
    }
}

// ---------- update: hc=tanh(XA@Wu^T+b); h=r*h+(1-r)*hc -> Hst, XA state, Xth ----------
// BM=128, BN=64, K=224. Direct-fragment, no LDS.
__global__ __launch_bounds__(256) void k_upd(const u16* __restrict__ XAh, const u16* __restrict__ XAl,
                                             const u16* __restrict__ Wh, const u16* __restrict__ Wl,
                                             const float* __restrict__ bias,
                                             const float* __restrict__ Rb,
                                             float* __restrict__ h,
                                             u16* __restrict__ XAho, u16* __restrict__ XAlo,
                                             u16* __restrict__ Xth, int off_next) {
  const int tid = threadIdx.x;
  const int wave = tid >> 6, lane = tid & 63;
  const int r0 = blockIdx.x * 128;
  const int wy = wave >> 1, wx = wave & 1;
  const int m = lane & 15, quad = lane >> 4;

  const size_t aoff = (size_t)(r0 + wy * 64 + m) * SA + quad * 8;
  const size_t boff = (size_t)(wx * 32 + m) * KP + quad * 8;

  f32x4 acc[4][2];
  f32x4 z4 = {0.f, 0.f, 0.f, 0.f};
#pragma unroll
  for (int a = 0; a < 4; a++) { acc[a][0] = z4; acc[a][1] = z4; }

  bf16x8 fAh[2][4], fAl[2][4], fBh[2][2], fBl[2][2];
  auto ld = [&](int k0, int s) {
#pragma unroll
    for (int mb = 0; mb < 4; mb++) {
      size_t o = aoff + (size_t)mb * 16 * SA + k0;
      fAh[s][mb] = ldfrag(XAh + o);
      fAl[s][mb] = ldfrag(XAl + o);
    }
#pragma unroll
    for (int nb = 0; nb < 2; nb++) {
      size_t o = boff + (size_t)nb * 16 * KP + k0;
      fBh[s][nb] = ldfrag(Wh + o);
      fBl[s][nb] = ldfrag(Wl + o);
    }
  };
  ld(0, 0);
#pragma unroll
  for (int kt = 0; kt < 7; kt++) {
    int cur = kt & 1;
    if (kt < 6) ld((kt + 1) * 32, cur ^ 1);
#pragma unroll
    for (int mb = 0; mb < 4; mb++)
#pragma unroll
      for (int nb = 0; nb < 2; nb++) {
        acc[mb][nb] = __builtin_amdgcn_mfma_f32_16x16x32_bf16(fAh[cur][mb], fBh[cur][nb], acc[mb][nb], 0, 0, 0);
        acc[mb][nb] = __builtin_amdgcn_mfma_f32_16x16x32_bf16(fAh[cur][mb], fBl[cur][nb], acc[mb][nb], 0, 0, 0);
        acc[mb][nb] = __builtin_amdgcn_mfma_f32_16x16x32_bf16(fAl[cur][mb], fBh[cur][nb], acc[mb][nb], 0, 0, 0);
      }
  }

#pragma unroll
  for (int mb = 0; mb < 4; mb++)
#pragma unroll
    for (int nb = 0; nb < 2; nb++) {
      int col = wx * 32 + nb * 16 + m;
      float bv = bias[col];
#pragma unroll
      for (int p = 0; p < 4; p++) {
        int row = r0 + wy * 64 + mb * 16 + quad * 4 + p;
        float hc = tanhf(acc[mb][nb][p] + bv);
        size_t idx = (size_t)row * 64 + col;
        float rr = Rb[idx];
        float hn = rr * h[idx] + (1.f - rr) * hc;
        h[idx] = hn;
        u16 vh, vl;
        split_bf(hn, vh, vl);
        size_t a = (size_t)row * SA + off_next + col;
        XAho[a] = vh; XAlo[a] = vl;
        int n = row >> 6, b = row & 63;
        Xth[((size_t)b * Cc + off_next + col) * Nn + n] = bf_rne(hn);
      }
    }
}

// ---------- de = h @ FC_E, split output ----------
__global__ __launch_bounds__(256) void k_de(const float* __restrict__ h,
                                            const float* __restrict__ fc,
                                            u16* __restrict__ Dh, u16* __restrict__ Dl) {
  __shared__ float fcs[Hc * Ec];
  for (int j = threadIdx.x; j < Hc * Ec; j += 256) fcs[j] = fc[j];
  __syncthreads();
  int idx = blockIdx.x * 256 + threadIdx.x;
  if (idx >= Nn * KD) return;
  int n = idx / KD;
  int rem = idx % KD;
  int b = rem / Ec, e = rem % Ec;
  const float* hp = h + (size_t)n * (Bc * Hc) + (size_t)b * Hc;
  float acc = 0.f;
#pragma unroll 8
  for (int hh = 0; hh < Hc; hh++) acc = fmaf(hp[hh], fcs[hh * Ec + e], acc);
  u16 vh, vl;
  split_bf(acc, vh, vl);
  Dh[idx] = vh; Dl[idx] = vl;
}

// ---------- proj + fill next dec step ----------
__global__ __launch_bounds__(256) void k_proj_fill(const float* __restrict__ h,
                                                   const float* __restrict__ pw,
                                                   const float* __restrict__ pb,
                                                   const float* __restrict__ ycov,
                                                   u16* __restrict__ XAh, u16* __restrict__ XAl,
                                                   u16* __restrict__ Xth,
                                                   float* __restrict__ out, int t) {
  int idx = blockIdx.x * 256 + threadIdx.x;
  if (idx >= NB) return;
  int n = idx >> 6, b = idx & 63;
  const float* hp = h + (size_t)idx * Hc;
  float acc = pb[0];
#pragma unroll 8
  for (int i = 0; i < Hc; i++) acc = fmaf(hp[i], pw[i], acc);
  out[(size_t)b * TN + (size_t)t * Nn + n] = acc;
  if (t + 1 < Tc) {
    float v1 = ycov[(size_t)b * TN + (size_t)(t + 1) * Nn + n];
    u16 hh, ll;
    split_bf(acc, hh, ll);
    XAh[(size_t)idx * SA] = hh; XAl[(size_t)idx * SA] = ll;
    split_bf(v1, hh, ll);
    XAh[(size_t)idx * SA + 1] = hh; XAl[(size_t)idx * SA + 1] = ll;
    Xth[((size_t)b * Cc) * Nn + n] = bf_rne(acc);
    Xth[((size_t)b * Cc + 1) * Nn + n] = bf_rne(v1);
  }
}

extern "C" void kernel_launch(void* const* d_in, const int* in_sizes, int n_in,
                              void* d_out, int out_size, void* d_ws, size_t ws_size,
                              hipStream_t stream) {
  (void)in_sizes; (void)n_in; (void)out_size; (void)ws_size;
  const float* x    = (const float*)d_in[0];
  const float* ycov = (const float*)d_in[1];
  const float* emb  = (const float*)d_in[2];
  const float* fce  = (const float*)d_in[3];
  const float* egw  = (const float*)d_in[4];
  const float* egb  = (const float*)d_in[5];
  const float* euw  = (const float*)d_in[6];
  const float* eub  = (const float*)d_in[7];
  const float* dgw  = (const float*)d_in[8];
  const float* dgb  = (const float*)d_in[9];
  const float* duw  = (const float*)d_in[10];
  const float* dub  = (const float*)d_in[11];
  const float* pw   = (const float*)d_in[12];
  const float* pb   = (const float*)d_in[13];
  float* out = (float*)d_out;

  char* wsb = (char*)d_ws;
  size_t off = 0;
  auto alloc = [&](size_t bytes) {
    void* p = wsb + off;
    off = (off + bytes + 255) & ~(size_t)255;
    return p;
  };
  float* Gf = (float*)alloc((size_t)Nn * Nn * 4);
  u16* S1h = (u16*)alloc((size_t)Nn * Nn * 2);
  u16* S1l = (u16*)alloc((size_t)Nn * Nn * 2);
  u16* S2h = (u16*)alloc((size_t)Nn * Nn * 2);
  u16* S2l = (u16*)alloc((size_t)Nn * Nn * 2);
  u16* Sth = (u16*)alloc((size_t)Nn * Nn * 2);
  u16* Stl = (u16*)alloc((size_t)Nn * Nn * 2);
  float* Hst = (float*)alloc((size_t)NB * Hc * 4);
  u16* XAh = (u16*)alloc((size_t)(NB + 4) * SA * 2);
  u16* XAl = (u16*)alloc((size_t)(NB + 4) * SA * 2);
  u16* Xth = (u16*)alloc((size_t)Bc * Cc * Nn * 2);
  float* Rb = (float*)alloc((size_t)NB * Hc * 4);
  u16* DEh = (u16*)alloc((size_t)Nn * KD * 2);
  u16* DEl = (u16*)alloc((size_t)Nn * KD * 2);
  u16* WgeH = (u16*)alloc(128 * KP * 2); u16* WgeL = (u16*)alloc(128 * KP * 2);
  u16* WueH = (u16*)alloc(64 * KP * 2);  u16* WueL = (u16*)alloc(64 * KP * 2);
  u16* WgdH = (u16*)alloc(128 * KP * 2); u16* WgdL = (u16*)alloc(128 * KP * 2);
  u16* WudH = (u16*)alloc(64 * KP * 2);  u16* WudL = (u16*)alloc(64 * KP * 2);

  hipMemsetAsync(Hst, 0, (size_t)NB * Hc * 4, stream);
  hipMemsetAsync(XAh, 0, (size_t)(NB + 4) * SA * 2, stream);
  hipMemsetAsync(XAl, 0, (size_t)(NB + 4) * SA * 2, stream);
  hipMemsetAsync(Xth, 0, (size_t)Bc * Cc * Nn * 2, stream);

  k_prep_wt<<<(128 * KP + 255) / 256, 256, 0, stream>>>(egw, 65, 128, WgeH, WgeL);
  k_prep_wt<<<(64 * KP + 255) / 256, 256, 0, stream>>>(euw, 65, 64, WueH, WueL);
  k_prep_wt<<<(128 * KP + 255) / 256, 256, 0, stream>>>(dgw, 66, 128, WgdH, WgdL);
  k_prep_wt<<<(64 * KP + 255) / 256, 256, 0, stream>>>(duw, 66, 64, WudH, WudL);

  // encoder supports
  k_gram<<<dim3(16, 16), 256, 0, stream>>>(emb, Ec, Gf);
  k_softmax<<<Nn, 256, 0, stream>>>(Gf, S1h, S1l);
  k_tr2<<<dim3(16, 16), 256, 0, stream>>>(S1h, S1l, Sth, Stl);
  k_s2_mfma<<<dim3(8, 16), 256, 0, stream>>>(S1h, S1l, Sth, Stl, S2h, S2l);

  const int gNB = NB / 256;

  for (int t = 0; t < Tc; t++) {
    k_fill_enc<<<gNB, 256, 0, stream>>>(x, XAh, XAl, Xth, t);
    k_ygemm<<<dim3(33, 16), 256, 0, stream>>>(S1h, S1l, S2h, S2l, Xth, XAh, XAl);
    k_gate<<<512, 256, 0, stream>>>(XAh, XAl, WgeH, WgeL, egb, Hst, Rb, XAh, XAl, Xth, 1);
    k_ygemm<<<dim3(33, 16), 256, 0, stream>>>(S1h, S1l, S2h, S2l, Xth, XAh, XAl);
    k_upd<<<512, 256, 0, stream>>>(XAh, XAl, WueH, WueL, eub, Rb, Hst, XAh, XAl, Xth,
                                   (t == Tc - 1) ? 2 : 1);
  }

  // decoder supports
  k_de<<<(Nn * KD + 255) / 256, 256, 0, stream>>>(Hst, fce, DEh, DEl);
  k_gram_mfma<<<dim3(8, 16), 256, 0, stream>>>(DEh, DEl, Gf);
  k_softmax<<<Nn, 256, 0, stream>>>(Gf, S1h, S1l);
  k_tr2<<<dim3(16, 16), 256, 0, stream>>>(S1h, S1l, Sth, Stl);
  k_s2_mfma<<<dim3(8, 16), 256, 0, stream>>>(S1h, S1l, Sth, Stl, S2h, S2l);
  k_dec_init<<<gNB, 256, 0, stream>>>(x, ycov, XAh, XAl, Xth);

  for (int t = 0; t < Tc; t++) {
    k_ygemm<<<dim3(33, 16), 256, 0, stream>>>(S1h, S1l, S2h, S2l, Xth, XAh, XAl);
    k_gate<<<512, 256, 0, stream>>>(XAh, XAl, WgdH, WgdL, dgb, Hst, Rb, XAh, XAl, Xth, 2);
    k_ygemm<<<dim3(33, 16), 256, 0, stream>>>(S1h, S1l, S2h, S2l, Xth, XAh, XAl);
    k_upd<<<512, 256, 0, stream>>>(XAh, XAl, WudH, WudL, dub, Rb, Hst, XAh, XAl, Xth, 2);
    k_proj_fill<<<gNB, 256, 0, stream>>>(Hst, pw, pb, ycov, XAh, XAl, Xth, out, t);
  }
}

// Round 7
// 5669.476 us; speedup vs baseline: 1.7218x; 1.7218x over previous
//
#include <hip/hip_runtime.h>
#include <math.h>

typedef __attribute__((ext_vector_type(8))) short bf16x8;
typedef __attribute__((ext_vector_type(4))) float f32x4;
typedef unsigned short u16;

namespace {
constexpr int Bc = 64, Tc = 12, Nn = 1024, Hc = 64, Ec = 10;
constexpr int NB = Nn * Bc;  // 65536
constexpr int Cc = 66;       // unified channel count (enc uses 65, col 65 zeroed)
constexpr int SA = 208;      // XA row stride ([X(66)|Y1(66)|Y2(66)|pad10])
constexpr int KP = 224;      // padded K for gate/update GEMMs (7 x 32)
constexpr int KD = Bc * Ec;  // 640, dec gram K
constexpr int TN = Tc * Nn;  // 12288
}

#define SWZ(r) (((r) >> 1) & 3)

__device__ __forceinline__ void gld16(const void* g, void* l) {
  __builtin_amdgcn_global_load_lds(
      (const __attribute__((address_space(1))) void*)g,
      (__attribute__((address_space(3))) void*)l, 16, 0, 0);
}

// split fp32 -> bf16 hi + bf16 lo (RNE both)
__device__ __forceinline__ void split_bf(float v, u16& h, u16& l) {
  unsigned u = __float_as_uint(v);
  unsigned hu = (u + 0x7FFFu + ((u >> 16) & 1u)) & 0xFFFF0000u;
  h = (u16)(hu >> 16);
  float r = v - __uint_as_float(hu);
  unsigned u2 = __float_as_uint(r);
  l = (u16)((u2 + 0x7FFFu + ((u2 >> 16) & 1u)) >> 16);
}
__device__ __forceinline__ u16 bf_rne(float v) {
  unsigned u = __float_as_uint(v);
  return (u16)((u + 0x7FFFu + ((u >> 16) & 1u)) >> 16);
}
__device__ __forceinline__ bf16x8 ldfrag(const u16* p) {
  return *(const bf16x8*)p;
}

// ---------- enc gram: G = emb @ emb^T (Kd small, fp32) ----------
__global__ __launch_bounds__(256) void k_gram(const float* __restrict__ in, int Kd,
                                              float* __restrict__ G) {
  __shared__ float At[16][64];
  __shared__ float Bt[16][64];
  int i0 = blockIdx.y * 64, j0 = blockIdx.x * 64;
  int tx = threadIdx.x & 15, ty = threadIdx.x >> 4;
  float acc[4][4] = {};
  for (int k0 = 0; k0 < Kd; k0 += 16) {
    for (int u = threadIdx.x; u < 1024; u += 256) {
      int i = u >> 4, k = u & 15;
      At[k][i] = (k0 + k < Kd) ? in[(size_t)(i0 + i) * Kd + k0 + k] : 0.f;
    }
    for (int u = threadIdx.x; u < 1024; u += 256) {
      int j = u >> 4, k = u & 15;
      Bt[k][j] = (k0 + k < Kd) ? in[(size_t)(j0 + j) * Kd + k0 + k] : 0.f;
    }
    __syncthreads();
#pragma unroll
    for (int kk = 0; kk < 16; kk++) {
      float a[4], b[4];
#pragma unroll
      for (int p = 0; p < 4; p++) a[p] = At[kk][ty * 4 + p];
#pragma unroll
      for (int q = 0; q < 4; q++) b[q] = Bt[kk][tx * 4 + q];
#pragma unroll
      for (int p = 0; p < 4; p++)
#pragma unroll
        for (int q = 0; q < 4; q++) acc[p][q] = fmaf(a[p], b[q], acc[p][q]);
    }
    __syncthreads();
  }
  for (int p = 0; p < 4; p++)
    for (int q = 0; q < 4; q++)
      G[(size_t)(i0 + ty * 4 + p) * Nn + j0 + tx * 4 + q] = acc[p][q];
}

// ---------- dec gram via split-MFMA: G = DE @ DE^T (LDS staged) ----------
__global__ __launch_bounds__(256) void k_gram_mfma(const u16* __restrict__ Dh,
                                                   const u16* __restrict__ Dl,
                                                   float* __restrict__ G) {
  __shared__ u16 lds[12288];
  const int tid = threadIdx.x;
  const int wave = tid >> 6, lane = tid & 63;
  const int i0 = blockIdx.y * 64;
  const int j0 = blockIdx.x * 128;
  const int wy = wave >> 1, wx = wave & 1;
  const int m = lane & 15, quad = lane >> 4;

  f32x4 acc[2][4];
  f32x4 z4 = {0.f, 0.f, 0.f, 0.f};
#pragma unroll
  for (int a = 0; a < 2; a++)
#pragma unroll
    for (int q = 0; q < 4; q++) acc[a][q] = z4;

  const int ar = tid >> 2;
  const int akc = (tid & 3) ^ SWZ(ar);

  for (int k0 = 0; k0 < KD; k0 += 32) {
    gld16(Dh + (size_t)(i0 + ar) * KD + k0 + akc * 8, &lds[wave * 512]);
    gld16(Dl + (size_t)(i0 + ar) * KD + k0 + akc * 8, &lds[2048 + wave * 512]);
#pragma unroll
    for (int p = 0; p < 2; p++) {
      int r = p * 64 + (tid >> 2);
      int kc = (tid & 3) ^ SWZ(r);
      gld16(Dh + (size_t)(j0 + r) * KD + k0 + kc * 8, &lds[4096 + p * 2048 + wave * 512]);
      gld16(Dl + (size_t)(j0 + r) * KD + k0 + kc * 8, &lds[8192 + p * 2048 + wave * 512]);
    }
    __syncthreads();

    bf16x8 ah[2], al[2], bh[4], bl[4];
#pragma unroll
    for (int mb = 0; mb < 2; mb++) {
      int r = wy * 32 + mb * 16 + m;
      int ci = r * 4 + (quad ^ SWZ(r));
      ah[mb] = *(const bf16x8*)&lds[ci * 8];
      al[mb] = *(const bf16x8*)&lds[2048 + ci * 8];
    }
#pragma unroll
    for (int nb = 0; nb < 4; nb++) {
      int rj = wx * 64 + nb * 16 + m;
      int cj = rj * 4 + (quad ^ SWZ(rj));
      bh[nb] = *(const bf16x8*)&lds[4096 + cj * 8];
      bl[nb] = *(const bf16x8*)&lds[8192 + cj * 8];
    }
#pragma unroll
    for (int mb = 0; mb < 2; mb++)
#pragma unroll
      for (int nb = 0; nb < 4; nb++) {
        acc[mb][nb] = __builtin_amdgcn_mfma_f32_16x16x32_bf16(ah[mb], bh[nb], acc[mb][nb], 0, 0, 0);
        acc[mb][nb] = __builtin_amdgcn_mfma_f32_16x16x32_bf16(ah[mb], bl[nb], acc[mb][nb], 0, 0, 0);
        acc[mb][nb] = __builtin_amdgcn_mfma_f32_16x16x32_bf16(al[mb], bh[nb], acc[mb][nb], 0, 0, 0);
      }
    __syncthreads();
  }

#pragma unroll
  for (int mb = 0; mb < 2; mb++)
#pragma unroll
    for (int nb = 0; nb < 4; nb++) {
      int col = j0 + wx * 64 + nb * 16 + m;
#pragma unroll
      for (int p = 0; p < 4; p++) {
        int row = i0 + wy * 32 + mb * 16 + quad * 4 + p;
        G[(size_t)row * Nn + col] = acc[mb][nb][p];
      }
    }
}

// ---------- S = row_softmax(relu(G)) -> split directly to S1h/S1l ----------
__global__ __launch_bounds__(256) void k_softmax(const float* __restrict__ G,
                                                 u16* __restrict__ S1h,
                                                 u16* __restrict__ S1l) {
  __shared__ float sred[8];
  int n = blockIdx.x;
  float v[4];
#pragma unroll
  for (int i = 0; i < 4; i++)
    v[i] = fmaxf(G[(size_t)n * Nn + threadIdx.x + i * 256], 0.f);
  float mx = fmaxf(fmaxf(v[0], v[1]), fmaxf(v[2], v[3]));
  for (int off = 32; off > 0; off >>= 1) mx = fmaxf(mx, __shfl_down(mx, off));
  if ((threadIdx.x & 63) == 0) sred[threadIdx.x >> 6] = mx;
  __syncthreads();
  float rmax = fmaxf(fmaxf(sred[0], sred[1]), fmaxf(sred[2], sred[3]));
  float s = 0.f;
#pragma unroll
  for (int i = 0; i < 4; i++) { v[i] = expf(v[i] - rmax); s += v[i]; }
  for (int off = 32; off > 0; off >>= 1) s += __shfl_down(s, off);
  if ((threadIdx.x & 63) == 0) sred[4 + (threadIdx.x >> 6)] = s;
  __syncthreads();
  float inv = 1.f / (sred[4] + sred[5] + sred[6] + sred[7]);
#pragma unroll
  for (int i = 0; i < 4; i++) {
    u16 h, l;
    split_bf(v[i] * inv, h, l);
    size_t a = (size_t)n * Nn + threadIdx.x + i * 256;
    S1h[a] = h; S1l[a] = l;
  }
}

// ---------- transpose S1h/S1l -> Sth/Stl ----------
__global__ __launch_bounds__(256) void k_tr2(const u16* __restrict__ Ah,
                                             const u16* __restrict__ Al,
                                             u16* __restrict__ Th, u16* __restrict__ Tl) {
  __shared__ u16 sm[64][72];
  int i0 = blockIdx.y * 64, j0 = blockIdx.x * 64;
  int tid = threadIdx.x;
  for (int pass = 0; pass < 2; pass++) {
    const u16* src = pass ? Al : Ah;
    u16* dst = pass ? Tl : Th;
    for (int u = tid; u < 4096; u += 256) {
      int i = u >> 6, c = u & 63;
      sm[i][c] = src[(size_t)(i0 + i) * Nn + j0 + c];
    }
    __syncthreads();
    for (int u = tid; u < 4096; u += 256) {
      int c = u >> 6, i = u & 63;
      dst[(size_t)(j0 + c) * Nn + i0 + i] = sm[i][c];
    }
    __syncthreads();
  }
}

// ---------- S2 = 2*S@S - I via direct-fragment split MFMA ----------
__global__ __launch_bounds__(256) void k_s2_mfma(const u16* __restrict__ S1h,
                                                 const u16* __restrict__ S1l,
                                                 const u16* __restrict__ Sth,
                                                 const u16* __restrict__ Stl,
                                                 u16* __restrict__ S2h,
                                                 u16* __restrict__ S2l) {
  const int tid = threadIdx.x;
  const int wave = tid >> 6, lane = tid & 63;
  const int i0 = blockIdx.y * 64, j0 = blockIdx.x * 128;
  const int wy = wave >> 1, wx = wave & 1;
  const int m = lane & 15, quad = lane >> 4;

  const size_t aoff = (size_t)(i0 + wy * 32 + m) * Nn + quad * 8;
  const size_t boff = (size_t)(j0 + wx * 64 + m) * Nn + quad * 8;

  f32x4 acc[2][4];
  f32x4 z4 = {0.f, 0.f, 0.f, 0.f};
#pragma unroll
  for (int a = 0; a < 2; a++)
#pragma unroll
    for (int q = 0; q < 4; q++) acc[a][q] = z4;

  bf16x8 fAh[2][2], fAl[2][2], fBh[2][4], fBl[2][4];
  auto ld = [&](int k0, int s) {
#pragma unroll
    for (int mb = 0; mb < 2; mb++) {
      fAh[s][mb] = ldfrag(S1h + aoff + (size_t)mb * 16 * Nn + k0);
      fAl[s][mb] = ldfrag(S1l + aoff + (size_t)mb * 16 * Nn + k0);
    }
#pragma unroll
    for (int nb = 0; nb < 4; nb++) {
      fBh[s][nb] = ldfrag(Sth + boff + (size_t)nb * 16 * Nn + k0);
      fBl[s][nb] = ldfrag(Stl + boff + (size_t)nb * 16 * Nn + k0);
    }
  };
  ld(0, 0);
#pragma unroll 2
  for (int kt = 0; kt < 32; kt++) {
    int cur = kt & 1;
    if (kt < 31) ld((kt + 1) * 32, cur ^ 1);
#pragma unroll
    for (int mb = 0; mb < 2; mb++)
#pragma unroll
      for (int nb = 0; nb < 4; nb++) {
        acc[mb][nb] = __builtin_amdgcn_mfma_f32_16x16x32_bf16(fAh[cur][mb], fBh[cur][nb], acc[mb][nb], 0, 0, 0);
        acc[mb][nb] = __builtin_amdgcn_mfma_f32_16x16x32_bf16(fAh[cur][mb], fBl[cur][nb], acc[mb][nb], 0, 0, 0);
        acc[mb][nb] = __builtin_amdgcn_mfma_f32_16x16x32_bf16(fAl[cur][mb], fBh[cur][nb], acc[mb][nb], 0, 0, 0);
      }
  }

#pragma unroll
  for (int mb = 0; mb < 2; mb++)
#pragma unroll
    for (int nb = 0; nb < 4; nb++) {
      int col = j0 + wx * 64 + nb * 16 + m;
#pragma unroll
      for (int p = 0; p < 4; p++) {
        int row = i0 + wy * 32 + mb * 16 + quad * 4 + p;
        float v = 2.f * acc[mb][nb][p] - (row == col ? 1.f : 0.f);
        u16 vh, vl;
        split_bf(v, vh, vl);
        size_t a = (size_t)row * Nn + col;
        S2h[a] = vh; S2l[a] = vl;
      }
    }
}

// ---------- Wt prep ----------
__global__ __launch_bounds__(256) void k_prep_wt(const float* __restrict__ W, int Csrc,
                                                 int ncol, u16* __restrict__ Wh,
                                                 u16* __restrict__ Wl) {
  int idx = blockIdx.x * 256 + threadIdx.x;
  if (idx >= ncol * KP) return;
  int n = idx / KP, kp = idx % KP;
  int chunk = kp / Cc, c = kp % Cc;
  float v = 0.f;
  if (kp < 3 * Cc && c < Csrc) v = W[((size_t)chunk * Csrc + c) * ncol + n];
  u16 h, l;
  split_bf(v, h, l);
  Wh[idx] = h; Wl[idx] = l;
}

// ---------- fill enc ----------
__global__ __launch_bounds__(256) void k_fill_enc(const float* __restrict__ x,
                                                  u16* __restrict__ XAh, u16* __restrict__ XAl,
                                                  u16* __restrict__ Xth, int t) {
  int idx = blockIdx.x * 256 + threadIdx.x;
  if (idx >= NB) return;
  int n = idx >> 6, b = idx & 63;
  float v = x[(size_t)b * TN + t * Nn + n];
  u16 h, l;
  split_bf(v, h, l);
  XAh[(size_t)idx * SA] = h; XAl[(size_t)idx * SA] = l;
  Xth[(size_t)b * Cc * Nn + n] = bf_rne(v);
}

// ---------- dec init ----------
__global__ __launch_bounds__(256) void k_dec_init(const float* __restrict__ x,
                                                  const float* __restrict__ ycov,
                                                  u16* __restrict__ XAh, u16* __restrict__ XAl,
                                                  u16* __restrict__ Xth) {
  int idx = blockIdx.x * 256 + threadIdx.x;
  if (idx >= NB) return;
  int n = idx >> 6, b = idx & 63;
  float v0 = x[(size_t)b * TN + (size_t)(Tc - 1) * Nn + n];
  float v1 = ycov[(size_t)b * TN + n];
  u16 h, l;
  split_bf(v0, h, l);
  XAh[(size_t)idx * SA] = h; XAl[(size_t)idx * SA] = l;
  split_bf(v1, h, l);
  XAh[(size_t)idx * SA + 1] = h; XAl[(size_t)idx * SA + 1] = l;
  Xth[((size_t)b * Cc) * Nn + n] = bf_rne(v0);
  Xth[((size_t)b * Cc + 1) * Nn + n] = bf_rne(v1);
}

// ---------- ygemm: Y1 = S@X, Y2 = S2@X. LDS-staged, double-buffered, XCD-clustered ----------
// 528 blocks: b -> xcd = b&7, s = b>>3; i0 = (2*xcd + (s&1))*64; j0 = (s>>1)*128.
// Each XCD sees only 2 i0 tiles -> A working set 1MB, fits 4MB per-XCD L2.
__global__ __launch_bounds__(256) void k_ygemm(const u16* __restrict__ S1h, const u16* __restrict__ S1l,
                                               const u16* __restrict__ S2h, const u16* __restrict__ S2l,
                                               const u16* __restrict__ Xth,
                                               u16* __restrict__ XAh, u16* __restrict__ XAl) {
  __shared__ u16 lds[2][12288];  // per buf: A 4x2048 (S1h,S1l,S2h,S2l) + B 2x2048 = 24KB; dbuf 48KB
  const int tid = threadIdx.x;
  const int wave = tid >> 6, lane = tid & 63;
  const int b = blockIdx.x;
  const int xcd = b & 7, s = b >> 3;
  const int i0 = (2 * xcd + (s & 1)) * 64;
  const int j0 = (s >> 1) * 128;
  const int wy = wave >> 1, wx = wave & 1;
  const int m = lane & 15, quad = lane >> 4;

  f32x4 acc1[2][4], acc2[2][4];
  f32x4 z4 = {0.f, 0.f, 0.f, 0.f};
#pragma unroll
  for (int a = 0; a < 2; a++)
#pragma unroll
    for (int q = 0; q < 4; q++) { acc1[a][q] = z4; acc2[a][q] = z4; }

  const int ar = tid >> 2;
  const int akc = (tid & 3) ^ SWZ(ar);
  const u16* amat[4] = {S1h, S1l, S2h, S2l};

  auto stage = [&](int k0, int buf) {
#pragma unroll
    for (int sm = 0; sm < 4; sm++)
      gld16(amat[sm] + (size_t)(i0 + ar) * Nn + k0 + akc * 8,
            &lds[buf][sm * 2048 + wave * 512]);
#pragma unroll
    for (int p = 0; p < 2; p++) {
      int r = p * 64 + (tid >> 2);
      int kc = (tid & 3) ^ SWZ(r);
      gld16(Xth + (size_t)(j0 + r) * Nn + k0 + kc * 8,
            &lds[buf][8192 + p * 2048 + wave * 512]);
    }
  };

  stage(0, 0);
  for (int kt = 0; kt < 32; kt++) {
    int cur = kt & 1;
    __syncthreads();  // drains staging of buf[cur]; also fences prior reads of buf[cur^1]
    if (kt < 31) stage((kt + 1) * 32, cur ^ 1);

    bf16x8 a1h[2], a1l[2], a2h[2], a2l[2], bh[4];
#pragma unroll
    for (int mb = 0; mb < 2; mb++) {
      int r = wy * 32 + mb * 16 + m;
      int ci = r * 4 + (quad ^ SWZ(r));
      a1h[mb] = *(const bf16x8*)&lds[cur][0 * 2048 + ci * 8];
      a1l[mb] = *(const bf16x8*)&lds[cur][1 * 2048 + ci * 8];
      a2h[mb] = *(const bf16x8*)&lds[cur][2 * 2048 + ci * 8];
      a2l[mb] = *(const bf16x8*)&lds[cur][3 * 2048 + ci * 8];
    }
#pragma unroll
    for (int nb = 0; nb < 4; nb++) {
      int rj = wx * 64 + nb * 16 + m;
      int cj = rj * 4 + (quad ^ SWZ(rj));
      bh[nb] = *(const bf16x8*)&lds[cur][8192 + cj * 8];
    }
#pragma unroll
    for (int mb = 0; mb < 2; mb++)
#pragma unroll
      for (int nb = 0; nb < 4; nb++) {
        acc1[mb][nb] = __builtin_amdgcn_mfma_f32_16x16x32_bf16(a1h[mb], bh[nb], acc1[mb][nb], 0, 0, 0);
        acc1[mb][nb] = __builtin_amdgcn_mfma_f32_16x16x32_bf16(a1l[mb], bh[nb], acc1[mb][nb], 0, 0, 0);
        acc2[mb][nb] = __builtin_amdgcn_mfma_f32_16x16x32_bf16(a2h[mb], bh[nb], acc2[mb][nb], 0, 0, 0);
        acc2[mb][nb] = __builtin_amdgcn_mfma_f32_16x16x32_bf16(a2l[mb], bh[nb], acc2[mb][nb], 0, 0, 0);
      }
  }

#pragma unroll
  for (int mb = 0; mb < 2; mb++)
#pragma unroll
    for (int nb = 0; nb < 4; nb++) {
      int col = j0 + wx * 64 + nb * 16 + m;
      int bb = col / Cc, cc = col % Cc;
#pragma unroll
      for (int p = 0; p < 4; p++) {
        int row = i0 + wy * 32 + mb * 16 + quad * 4 + p;
        size_t base = ((size_t)row * 64 + bb) * SA;
        u16 vh, vl;
        split_bf(acc1[mb][nb][p], vh, vl);
        XAh[base + 66 + cc] = vh; XAl[base + 66 + cc] = vl;
        split_bf(acc2[mb][nb][p], vh, vl);
        XAh[base + 132 + cc] = vh; XAl[base + 132 + cc] = vl;
      }
    }
}

// ---------- gate: sigmoid(XA@W^T+b) -> Rb; z*h -> XA state cols + Xth (R5 LDS form) ----------
__global__ __launch_bounds__(256) void k_gate(const u16* __restrict__ XAh, const u16* __restrict__ XAl,
                                              const u16* __restrict__ Wh, const u16* __restrict__ Wl,
                                              const float* __restrict__ bias,
                                              const float* __restrict__ hst,
                                              float* __restrict__ Rb,
                                              u16* __restrict__ XAho, u16* __restrict__ XAlo,
                                              u16* __restrict__ Xth, int off) {
  __shared__ u16 lds[4 * 4096];  // 32KB
  const int tid = threadIdx.x;
  const int wave = tid >> 6, lane = tid & 63;
  const int r0 = blockIdx.x * 128;
  const int wy = wave >> 1, wx = wave & 1;
  const int m = lane & 15, quad = lane >> 4;

  f32x4 acc[4][4];
  f32x4 z4 = {0.f, 0.f, 0.f, 0.f};
#pragma unroll
  for (int a = 0; a < 4; a++)
#pragma unroll
    for (int q = 0; q < 4; q++) acc[a][q] = z4;

  for (int kt = 0; kt < 7; kt++) {
    int k0 = kt * 32;
#pragma unroll
    for (int p = 0; p < 2; p++) {
      int r = p * 64 + (tid >> 2);
      int kc = (tid & 3) ^ SWZ(r);
      gld16(XAh + (size_t)(r0 + r) * SA + k0 + kc * 8, &lds[p * 2048 + wave * 512]);
      gld16(XAl + (size_t)(r0 + r) * SA + k0 + kc * 8, &lds[4096 + p * 2048 + wave * 512]);
      gld16(Wh + (size_t)r * KP + k0 + kc * 8, &lds[8192 + p * 2048 + wave * 512]);
      gld16(Wl + (size_t)r * KP + k0 + kc * 8, &lds[12288 + p * 2048 + wave * 512]);
    }
    __syncthreads();

    bf16x8 ah[4], al[4], bh[4], bl[4];
#pragma unroll
    for (int mb = 0; mb < 4; mb++) {
      int r = wy * 64 + mb * 16 + m;
      int ci = r * 4 + (quad ^ SWZ(r));
      ah[mb] = *(const bf16x8*)&lds[ci * 8];
      al[mb] = *(const bf16x8*)&lds[4096 + ci * 8];
    }
#pragma unroll
    for (int nb = 0; nb < 4; nb++) {
      int rj = wx * 64 + nb * 16 + m;
      int cj = rj * 4 + (quad ^ SWZ(rj));
      bh[nb] = *(const bf16x8*)&lds[8192 + cj * 8];
      bl[nb] = *(const bf16x8*)&lds[12288 + cj * 8];
    }
#pragma unroll
    for (int mb = 0; mb < 4; mb++)
#pragma unroll
      for (int nb = 0; nb < 4; nb++) {
        acc[mb][nb] = __builtin_amdgcn_mfma_f32_16x16x32_bf16(ah[mb], bh[nb], acc[mb][nb], 0, 0, 0);
        acc[mb][nb] = __builtin_amdgcn_mfma_f32_16x16x32_bf16(ah[mb], bl[nb], acc[mb][nb], 0, 0, 0);
        acc[mb][nb] = __builtin_amdgcn_mfma_f32_16x16x32_bf16(al[mb], bh[nb], acc[mb][nb], 0, 0, 0);
      }
    __syncthreads();
  }

#pragma unroll
  for (int mb = 0; mb < 4; mb++)
#pragma unroll
    for (int nb = 0; nb < 4; nb++) {
      int col = wx * 64 + nb * 16 + m;
      float bv = bias[col];
#pragma unroll
      for (int p = 0; p < 4; p++) {
        int row = r0 + wy * 64 + mb * 16 + quad * 4 + p;
        float sg = 1.f / (1.f + expf(-(acc[mb][nb][p] + bv)));
        if (col < 64) {
          float v = sg * hst[(size_t)row * 64 + col];
          u16 vh, vl;
          split_bf(v, vh, vl);
          size_t a = (size_t)row * SA + off + col;
          XAho[a] = vh; XAlo[a] = vl;
          int n = row >> 6, b = row & 63;
          Xth[((size_t)b * Cc + off + col) * Nn + n] = bf_rne(v);
        } else {
          Rb[(size_t)row * 64 + col - 64] = sg;
        }
      }
    }
}

// ---------- update (R5 LDS form) ----------
__global__ __launch_bounds__(256) void k_upd(const u16* __restrict__ XAh, const u16* __restrict__ XAl,
                                             const u16* __restrict__ Wh, const u16* __restrict__ Wl,
                                             const float* __restrict__ bias,
                                             const float* __restrict__ Rb,
                                             float* __restrict__ h,
                                             u16* __restrict__ XAho, u16* __restrict__ XAlo,
                                             u16* __restrict__ Xth, int off_next) {
  __shared__ u16 lds[2 * 4096 + 2 * 2048];  // 24KB
  const int tid = threadIdx.x;
  const int wave = tid >> 6, lane = tid & 63;
  const int r0 = blockIdx.x * 128;
  const int wy = wave >> 1, wx = wave & 1;
  const int m = lane & 15, quad = lane >> 4;

  f32x4 acc[4][2];
  f32x4 z4 = {0.f, 0.f, 0.f, 0.f};
#pragma unroll
  for (int a = 0; a < 4; a++) { acc[a][0] = z4; acc[a][1] = z4; }

  for (int kt = 0; kt < 7; kt++) {
    int k0 = kt * 32;
#pragma unroll
    for (int p = 0; p < 2; p++) {
      int r = p * 64 + (tid >> 2);
      int kc = (tid & 3) ^ SWZ(r);
      gld16(XAh + (size_t)(r0 + r) * SA + k0 + kc * 8, &lds[p * 2048 + wave * 512]);
      gld16(XAl + (size_t)(r0 + r) * SA + k0 + kc * 8, &lds[4096 + p * 2048 + wave * 512]);
    }
    {
      int r = tid >> 2;
      int kc = (tid & 3) ^ SWZ(r);
      gld16(Wh + (size_t)r * KP + k0 + kc * 8, &lds[8192 + wave * 512]);
      gld16(Wl + (size_t)r * KP + k0 + kc * 8, &lds[10240 + wave * 512]);
    }
    __syncthreads();

    bf16x8 ah[4], al[4], bh[2], bl[2];
#pragma unroll
    for (int mb = 0; mb < 4; mb++) {
      int r = wy * 64 + mb * 16 + m;
      int ci = r * 4 + (quad ^ SWZ(r));
      ah[mb] = *(const bf16x8*)&lds[ci * 8];
      al[mb] = *(const bf16x8*)&lds[4096 + ci * 8];
    }
#pragma unroll
    for (int nb = 0; nb < 2; nb++) {
      int rj = wx * 32 + nb * 16 + m;
      int cj = rj * 4 + (quad ^ SWZ(rj));
      bh[nb] = *(const bf16x8*)&lds[8192 + cj * 8];
      bl[nb] = *(const bf16x8*)&lds[10240 + cj * 8];
    }
#pragma unroll
    for (int mb = 0; mb < 4; mb++)
#pragma unroll
      for (int nb = 0; nb < 2; nb++) {
        acc[mb][nb] = __builtin_amdgcn_mfma_f32_16x16x32_bf16(ah[mb], bh[nb], acc[mb][nb], 0, 0, 0);
        acc[mb][nb] = __builtin_amdgcn_mfma_f32_16x16x32_bf16(ah[mb], bl[nb], acc[mb][nb], 0, 0, 0);
        acc[mb][nb] = __builtin_amdgcn_mfma_f32_16x16x32_bf16(al[mb], bh[nb], acc[mb][nb], 0, 0, 0);
      }
    __syncthreads();
  }

#pragma unroll
  for (int mb = 0; mb < 4; mb++)
#pragma unroll
    for (int nb = 0; nb < 2; nb++) {
      int col = wx * 32 + nb * 16 + m;
      float bv = bias[col];
#pragma unroll
      for (int p = 0; p < 4; p++) {
        int row = r0 + wy * 64 + mb * 16 + quad * 4 + p;
        float hc = tanhf(acc[mb][nb][p] + bv);
        size_t idx = (size_t)row * 64 + col;
        float rr = Rb[idx];
        float hn = rr * h[idx] + (1.f - rr) * hc;
        h[idx] = hn;
        u16 vh, vl;
        split_bf(hn, vh, vl);
        size_t a = (size_t)row * SA + off_next + col;
        XAho[a] = vh; XAlo[a] = vl;
        int n = row >> 6, b = row & 63;
        Xth[((size_t)b * Cc + off_next + col) * Nn + n] = bf_rne(hn);
      }
    }
}

// ---------- de = h @ FC_E, split output ----------
__global__ __launch_bounds__(256) void k_de(const float* __restrict__ h,
                                            const float* __restrict__ fc,
                                            u16* __restrict__ Dh, u16* __restrict__ Dl) {
  __shared__ float fcs[Hc * Ec];
  for (int j = threadIdx.x; j < Hc * Ec; j += 256) fcs[j] = fc[j];
  __syncthreads();
  int idx = blockIdx.x * 256 + threadIdx.x;
  if (idx >= Nn * KD) return;
  int n = idx / KD;
  int rem = idx % KD;
  int b = rem / Ec, e = rem % Ec;
  const float* hp = h + (size_t)n * (Bc * Hc) + (size_t)b * Hc;
  float acc = 0.f;
#pragma unroll 8
  for (int hh = 0; hh < Hc; hh++) acc = fmaf(hp[hh], fcs[hh * Ec + e], acc);
  u16 vh, vl;
  split_bf(acc, vh, vl);
  Dh[idx] = vh; Dl[idx] = vl;
}

// ---------- proj + fill next dec step ----------
__global__ __launch_bounds__(256) void k_proj_fill(const float* __restrict__ h,
                                                   const float* __restrict__ pw,
                                                   const float* __restrict__ pb,
                                                   const float* __restrict__ ycov,
                                                   u16* __restrict__ XAh, u16* __restrict__ XAl,
                                                   u16* __restrict__ Xth,
                                                   float* __restrict__ out, int t) {
  int idx = blockIdx.x * 256 + threadIdx.x;
  if (idx >= NB) return;
  int n = idx >> 6, b = idx & 63;
  const float* hp = h + (size_t)idx * Hc;
  float acc = pb[0];
#pragma unroll 8
  for (int i = 0; i < Hc; i++) acc = fmaf(hp[i], pw[i], acc);
  out[(size_t)b * TN + (size_t)t * Nn + n] = acc;
  if (t + 1 < Tc) {
    float v1 = ycov[(size_t)b * TN + (size_t)(t + 1) * Nn + n];
    u16 hh, ll;
    split_bf(acc, hh, ll);
    XAh[(size_t)idx * SA] = hh; XAl[(size_t)idx * SA] = ll;
    split_bf(v1, hh, ll);
    XAh[(size_t)idx * SA + 1] = hh; XAl[(size_t)idx * SA + 1] = ll;
    Xth[((size_t)b * Cc) * Nn + n] = bf_rne(acc);
    Xth[((size_t)b * Cc + 1) * Nn + n] = bf_rne(v1);
  }
}

extern "C" void kernel_launch(void* const* d_in, const int* in_sizes, int n_in,
                              void* d_out, int out_size, void* d_ws, size_t ws_size,
                              hipStream_t stream) {
  (void)in_sizes; (void)n_in; (void)out_size; (void)ws_size;
  const float* x    = (const float*)d_in[0];
  const float* ycov = (const float*)d_in[1];
  const float* emb  = (const float*)d_in[2];
  const float* fce  = (const float*)d_in[3];
  const float* egw  = (const float*)d_in[4];
  const float* egb  = (const float*)d_in[5];
  const float* euw  = (const float*)d_in[6];
  const float* eub  = (const float*)d_in[7];
  const float* dgw  = (const float*)d_in[8];
  const float* dgb  = (const float*)d_in[9];
  const float* duw  = (const float*)d_in[10];
  const float* dub  = (const float*)d_in[11];
  const float* pw   = (const float*)d_in[12];
  const float* pb   = (const float*)d_in[13];
  float* out = (float*)d_out;

  char* wsb = (char*)d_ws;
  size_t off = 0;
  auto alloc = [&](size_t bytes) {
    void* p = wsb + off;
    off = (off + bytes + 255) & ~(size_t)255;
    return p;
  };
  float* Gf = (float*)alloc((size_t)Nn * Nn * 4);
  u16* S1h = (u16*)alloc((size_t)Nn * Nn * 2);
  u16* S1l = (u16*)alloc((size_t)Nn * Nn * 2);
  u16* S2h = (u16*)alloc((size_t)Nn * Nn * 2);
  u16* S2l = (u16*)alloc((size_t)Nn * Nn * 2);
  u16* Sth = (u16*)alloc((size_t)Nn * Nn * 2);
  u16* Stl = (u16*)alloc((size_t)Nn * Nn * 2);
  float* Hst = (float*)alloc((size_t)NB * Hc * 4);
  u16* XAh = (u16*)alloc((size_t)(NB + 4) * SA * 2);
  u16* XAl = (u16*)alloc((size_t)(NB + 4) * SA * 2);
  u16* Xth = (u16*)alloc((size_t)Bc * Cc * Nn * 2);
  float* Rb = (float*)alloc((size_t)NB * Hc * 4);
  u16* DEh = (u16*)alloc((size_t)Nn * KD * 2);
  u16* DEl = (u16*)alloc((size_t)Nn * KD * 2);
  u16* WgeH = (u16*)alloc(128 * KP * 2); u16* WgeL = (u16*)alloc(128 * KP * 2);
  u16* WueH = (u16*)alloc(64 * KP * 2);  u16* WueL = (u16*)alloc(64 * KP * 2);
  u16* WgdH = (u16*)alloc(128 * KP * 2); u16* WgdL = (u16*)alloc(128 * KP * 2);
  u16* WudH = (u16*)alloc(64 * KP * 2);  u16* WudL = (u16*)alloc(64 * KP * 2);

  hipMemsetAsync(Hst, 0, (size_t)NB * Hc * 4, stream);
  hipMemsetAsync(XAh, 0, (size_t)(NB + 4) * SA * 2, stream);
  hipMemsetAsync(XAl, 0, (size_t)(NB + 4) * SA * 2, stream);
  hipMemsetAsync(Xth, 0, (size_t)Bc * Cc * Nn * 2, stream);

  k_prep_wt<<<(128 * KP + 255) / 256, 256, 0, stream>>>(egw, 65, 128, WgeH, WgeL);
  k_prep_wt<<<(64 * KP + 255) / 256, 256, 0, stream>>>(euw, 65, 64, WueH, WueL);
  k_prep_wt<<<(128 * KP + 255) / 256, 256, 0, stream>>>(dgw, 66, 128, WgdH, WgdL);
  k_prep_wt<<<(64 * KP + 255) / 256, 256, 0, stream>>>(duw, 66, 64, WudH, WudL);

  // encoder supports
  k_gram<<<dim3(16, 16), 256, 0, stream>>>(emb, Ec, Gf);
  k_softmax<<<Nn, 256, 0, stream>>>(Gf, S1h, S1l);
  k_tr2<<<dim3(16, 16), 256, 0, stream>>>(S1h, S1l, Sth, Stl);
  k_s2_mfma<<<dim3(8, 16), 256, 0, stream>>>(S1h, S1l, Sth, Stl, S2h, S2l);

  const int gNB = NB / 256;

  for (int t = 0; t < Tc; t++) {
    k_fill_enc<<<gNB, 256, 0, stream>>>(x, XAh, XAl, Xth, t);
    k_ygemm<<<528, 256, 0, stream>>>(S1h, S1l, S2h, S2l, Xth, XAh, XAl);
    k_gate<<<512, 256, 0, stream>>>(XAh, XAl, WgeH, WgeL, egb, Hst, Rb, XAh, XAl, Xth, 1);
    k_ygemm<<<528, 256, 0, stream>>>(S1h, S1l, S2h, S2l, Xth, XAh, XAl);
    k_upd<<<512, 256, 0, stream>>>(XAh, XAl, WueH, WueL, eub, Rb, Hst, XAh, XAl, Xth,
                                   (t == Tc - 1) ? 2 : 1);
  }

  // decoder supports
  k_de<<<(Nn * KD + 255) / 256, 256, 0, stream>>>(Hst, fce, DEh, DEl);
  k_gram_mfma<<<dim3(8, 16), 256, 0, stream>>>(DEh, DEl, Gf);
  k_softmax<<<Nn, 256, 0, stream>>>(Gf, S1h, S1l);
  k_tr2<<<dim3(16, 16), 256, 0, stream>>>(S1h, S1l, Sth, Stl);
  k_s2_mfma<<<dim3(8, 16), 256, 0, stream>>>(S1h, S1l, Sth, Stl, S2h, S2l);
  k_dec_init<<<gNB, 256, 0, stream>>>(x, ycov, XAh, XAl, Xth);

  for (int t = 0; t < Tc; t++) {
    k_ygemm<<<528, 256, 0, stream>>>(S1h, S1l, S2h, S2l, Xth, XAh, XAl);
    k_gate<<<512, 256, 0, stream>>>(XAh, XAl, WgdH, WgdL, dgb, Hst, Rb, XAh, XAl, Xth, 2);
    k_ygemm<<<528, 256, 0, stream>>>(S1h, S1l, S2h, S2l, Xth, XAh, XAl);
    k_upd<<<512, 256, 0, stream>>>(XAh, XAl, WudH, WudL, dub, Rb, Hst, XAh, XAl, Xth, 2);
    k_proj_fill<<<gNB, 256, 0, stream>>>(Hst, pw, pb, ycov, XAh, XAl, Xth, out, t);
  }
}

// Round 8
// 5433.581 us; speedup vs baseline: 1.7966x; 1.0434x over previous
//
#include <hip/hip_runtime.h>
#include <math.h>

typedef __attribute__((ext_vector_type(8))) short bf16x8;
typedef __attribute__((ext_vector_type(4))) float f32x4;
typedef unsigned short u16;

namespace {
constexpr int Bc = 64, Tc = 12, Nn = 1024, Hc = 64, Ec = 10;
constexpr int NB = Nn * Bc;  // 65536
constexpr int Cc = 66;       // unified channel count (enc uses 65, col 65 zeroed)
constexpr int SA = 208;      // XA row stride ([X(66)|Y1(66)|Y2(66)|pad10])
constexpr int KP = 224;      // padded K for gate/update GEMMs (7 x 32); W rows >=198 are zero
constexpr int KD = Bc * Ec;  // 640, dec gram K
constexpr int TN = Tc * Nn;  // 12288
}

#define SWZ(r) (((r) >> 1) & 3)

__device__ __forceinline__ void gld16(const void* g, void* l) {
  __builtin_amdgcn_global_load_lds(
      (const __attribute__((address_space(1))) void*)g,
      (__attribute__((address_space(3))) void*)l, 16, 0, 0);
}

__device__ __forceinline__ void split_bf(float v, u16& h, u16& l) {
  unsigned u = __float_as_uint(v);
  unsigned hu = (u + 0x7FFFu + ((u >> 16) & 1u)) & 0xFFFF0000u;
  h = (u16)(hu >> 16);
  float r = v - __uint_as_float(hu);
  unsigned u2 = __float_as_uint(r);
  l = (u16)((u2 + 0x7FFFu + ((u2 >> 16) & 1u)) >> 16);
}
__device__ __forceinline__ u16 bf_rne(float v) {
  unsigned u = __float_as_uint(v);
  return (u16)((u + 0x7FFFu + ((u >> 16) & 1u)) >> 16);
}
__device__ __forceinline__ float bf_to_f(u16 v) {
  return __uint_as_float(((unsigned)v) << 16);
}
__device__ __forceinline__ bf16x8 ldfrag(const u16* p) { return *(const bf16x8*)p; }

// ---------- enc gram: G = emb @ emb^T (Kd small, fp32) ----------
__global__ __launch_bounds__(256) void k_gram(const float* __restrict__ in, int Kd,
                                              float* __restrict__ G) {
  __shared__ float At[16][64];
  __shared__ float Bt[16][64];
  int i0 = blockIdx.y * 64, j0 = blockIdx.x * 64;
  int tx = threadIdx.x & 15, ty = threadIdx.x >> 4;
  float acc[4][4] = {};
  for (int k0 = 0; k0 < Kd; k0 += 16) {
    for (int u = threadIdx.x; u < 1024; u += 256) {
      int i = u >> 4, k = u & 15;
      At[k][i] = (k0 + k < Kd) ? in[(size_t)(i0 + i) * Kd + k0 + k] : 0.f;
    }
    for (int u = threadIdx.x; u < 1024; u += 256) {
      int j = u >> 4, k = u & 15;
      Bt[k][j] = (k0 + k < Kd) ? in[(size_t)(j0 + j) * Kd + k0 + k] : 0.f;
    }
    __syncthreads();
#pragma unroll
    for (int kk = 0; kk < 16; kk++) {
      float a[4], b[4];
#pragma unroll
      for (int p = 0; p < 4; p++) a[p] = At[kk][ty * 4 + p];
#pragma unroll
      for (int q = 0; q < 4; q++) b[q] = Bt[kk][tx * 4 + q];
#pragma unroll
      for (int p = 0; p < 4; p++)
#pragma unroll
        for (int q = 0; q < 4; q++) acc[p][q] = fmaf(a[p], b[q], acc[p][q]);
    }
    __syncthreads();
  }
  for (int p = 0; p < 4; p++)
    for (int q = 0; q < 4; q++)
      G[(size_t)(i0 + ty * 4 + p) * Nn + j0 + tx * 4 + q] = acc[p][q];
}

// ---------- dec gram via split-MFMA: G = DE @ DE^T ----------
__global__ __launch_bounds__(256) void k_gram_mfma(const u16* __restrict__ Dh,
                                                   const u16* __restrict__ Dl,
                                                   float* __restrict__ G) {
  __shared__ u16 lds[12288];
  const int tid = threadIdx.x;
  const int wave = tid >> 6, lane = tid & 63;
  const int i0 = blockIdx.y * 64;
  const int j0 = blockIdx.x * 128;
  const int wy = wave >> 1, wx = wave & 1;
  const int m = lane & 15, quad = lane >> 4;

  f32x4 acc[2][4];
  f32x4 z4 = {0.f, 0.f, 0.f, 0.f};
#pragma unroll
  for (int a = 0; a < 2; a++)
#pragma unroll
    for (int q = 0; q < 4; q++) acc[a][q] = z4;

  const int ar = tid >> 2;
  const int akc = (tid & 3) ^ SWZ(ar);

  for (int k0 = 0; k0 < KD; k0 += 32) {
    gld16(Dh + (size_t)(i0 + ar) * KD + k0 + akc * 8, &lds[wave * 512]);
    gld16(Dl + (size_t)(i0 + ar) * KD + k0 + akc * 8, &lds[2048 + wave * 512]);
#pragma unroll
    for (int p = 0; p < 2; p++) {
      int r = p * 64 + (tid >> 2);
      int kc = (tid & 3) ^ SWZ(r);
      gld16(Dh + (size_t)(j0 + r) * KD + k0 + kc * 8, &lds[4096 + p * 2048 + wave * 512]);
      gld16(Dl + (size_t)(j0 + r) * KD + k0 + kc * 8, &lds[8192 + p * 2048 + wave * 512]);
    }
    __syncthreads();

    bf16x8 ah[2], al[2], bh[4], bl[4];
#pragma unroll
    for (int mb = 0; mb < 2; mb++) {
      int r = wy * 32 + mb * 16 + m;
      int ci = r * 4 + (quad ^ SWZ(r));
      ah[mb] = *(const bf16x8*)&lds[ci * 8];
      al[mb] = *(const bf16x8*)&lds[2048 + ci * 8];
    }
#pragma unroll
    for (int nb = 0; nb < 4; nb++) {
      int rj = wx * 64 + nb * 16 + m;
      int cj = rj * 4 + (quad ^ SWZ(rj));
      bh[nb] = *(const bf16x8*)&lds[4096 + cj * 8];
      bl[nb] = *(const bf16x8*)&lds[8192 + cj * 8];
    }
#pragma unroll
    for (int mb = 0; mb < 2; mb++)
#pragma unroll
      for (int nb = 0; nb < 4; nb++) {
        acc[mb][nb] = __builtin_amdgcn_mfma_f32_16x16x32_bf16(ah[mb], bh[nb], acc[mb][nb], 0, 0, 0);
        acc[mb][nb] = __builtin_amdgcn_mfma_f32_16x16x32_bf16(ah[mb], bl[nb], acc[mb][nb], 0, 0, 0);
        acc[mb][nb] = __builtin_amdgcn_mfma_f32_16x16x32_bf16(al[mb], bh[nb], acc[mb][nb], 0, 0, 0);
      }
    __syncthreads();
  }

#pragma unroll
  for (int mb = 0; mb < 2; mb++)
#pragma unroll
    for (int nb = 0; nb < 4; nb++) {
      int col = j0 + wx * 64 + nb * 16 + m;
#pragma unroll
      for (int p = 0; p < 4; p++) {
        int row = i0 + wy * 32 + mb * 16 + quad * 4 + p;
        G[(size_t)row * Nn + col] = acc[mb][nb][p];
      }
    }
}

// ---------- S = row_softmax(relu(G)) -> split to S1h/S1l ----------
__global__ __launch_bounds__(256) void k_softmax(const float* __restrict__ G,
                                                 u16* __restrict__ S1h,
                                                 u16* __restrict__ S1l) {
  __shared__ float sred[8];
  int n = blockIdx.x;
  float v[4];
#pragma unroll
  for (int i = 0; i < 4; i++)
    v[i] = fmaxf(G[(size_t)n * Nn + threadIdx.x + i * 256], 0.f);
  float mx = fmaxf(fmaxf(v[0], v[1]), fmaxf(v[2], v[3]));
  for (int off = 32; off > 0; off >>= 1) mx = fmaxf(mx, __shfl_down(mx, off));
  if ((threadIdx.x & 63) == 0) sred[threadIdx.x >> 6] = mx;
  __syncthreads();
  float rmax = fmaxf(fmaxf(sred[0], sred[1]), fmaxf(sred[2], sred[3]));
  float s = 0.f;
#pragma unroll
  for (int i = 0; i < 4; i++) { v[i] = expf(v[i] - rmax); s += v[i]; }
  for (int off = 32; off > 0; off >>= 1) s += __shfl_down(s, off);
  if ((threadIdx.x & 63) == 0) sred[4 + (threadIdx.x >> 6)] = s;
  __syncthreads();
  float inv = 1.f / (sred[4] + sred[5] + sred[6] + sred[7]);
#pragma unroll
  for (int i = 0; i < 4; i++) {
    u16 h, l;
    split_bf(v[i] * inv, h, l);
    size_t a = (size_t)n * Nn + threadIdx.x + i * 256;
    S1h[a] = h; S1l[a] = l;
  }
}

// ---------- transpose S1h/S1l -> Sth/Stl ----------
__global__ __launch_bounds__(256) void k_tr2(const u16* __restrict__ Ah,
                                             const u16* __restrict__ Al,
                                             u16* __restrict__ Th, u16* __restrict__ Tl) {
  __shared__ u16 sm[64][72];
  int i0 = blockIdx.y * 64, j0 = blockIdx.x * 64;
  int tid = threadIdx.x;
  for (int pass = 0; pass < 2; pass++) {
    const u16* src = pass ? Al : Ah;
    u16* dst = pass ? Tl : Th;
    for (int u = tid; u < 4096; u += 256) {
      int i = u >> 6, c = u & 63;
      sm[i][c] = src[(size_t)(i0 + i) * Nn + j0 + c];
    }
    __syncthreads();
    for (int u = tid; u < 4096; u += 256) {
      int c = u >> 6, i = u & 63;
      dst[(size_t)(j0 + c) * Nn + i0 + i] = sm[i][c];
    }
    __syncthreads();
  }
}

// ---------- S2 = 2*S@S - I via direct-fragment split MFMA ----------
__global__ __launch_bounds__(256) void k_s2_mfma(const u16* __restrict__ S1h,
                                                 const u16* __restrict__ S1l,
                                                 const u16* __restrict__ Sth,
                                                 const u16* __restrict__ Stl,
                                                 u16* __restrict__ S2h,
                                                 u16* __restrict__ S2l) {
  const int tid = threadIdx.x;
  const int wave = tid >> 6, lane = tid & 63;
  const int i0 = blockIdx.y * 64, j0 = blockIdx.x * 128;
  const int wy = wave >> 1, wx = wave & 1;
  const int m = lane & 15, quad = lane >> 4;

  const size_t aoff = (size_t)(i0 + wy * 32 + m) * Nn + quad * 8;
  const size_t boff = (size_t)(j0 + wx * 64 + m) * Nn + quad * 8;

  f32x4 acc[2][4];
  f32x4 z4 = {0.f, 0.f, 0.f, 0.f};
#pragma unroll
  for (int a = 0; a < 2; a++)
#pragma unroll
    for (int q = 0; q < 4; q++) acc[a][q] = z4;

  bf16x8 fAh[2][2], fAl[2][2], fBh[2][4], fBl[2][4];
  auto ld = [&](int k0, int s) {
#pragma unroll
    for (int mb = 0; mb < 2; mb++) {
      fAh[s][mb] = ldfrag(S1h + aoff + (size_t)mb * 16 * Nn + k0);
      fAl[s][mb] = ldfrag(S1l + aoff + (size_t)mb * 16 * Nn + k0);
    }
#pragma unroll
    for (int nb = 0; nb < 4; nb++) {
      fBh[s][nb] = ldfrag(Sth + boff + (size_t)nb * 16 * Nn + k0);
      fBl[s][nb] = ldfrag(Stl + boff + (size_t)nb * 16 * Nn + k0);
    }
  };
  ld(0, 0);
#pragma unroll 2
  for (int kt = 0; kt < 32; kt++) {
    int cur = kt & 1;
    if (kt < 31) ld((kt + 1) * 32, cur ^ 1);
#pragma unroll
    for (int mb = 0; mb < 2; mb++)
#pragma unroll
      for (int nb = 0; nb < 4; nb++) {
        acc[mb][nb] = __builtin_amdgcn_mfma_f32_16x16x32_bf16(fAh[cur][mb], fBh[cur][nb], acc[mb][nb], 0, 0, 0);
        acc[mb][nb] = __builtin_amdgcn_mfma_f32_16x16x32_bf16(fAh[cur][mb], fBl[cur][nb], acc[mb][nb], 0, 0, 0);
        acc[mb][nb] = __builtin_amdgcn_mfma_f32_16x16x32_bf16(fAl[cur][mb], fBh[cur][nb], acc[mb][nb], 0, 0, 0);
      }
  }

#pragma unroll
  for (int mb = 0; mb < 2; mb++)
#pragma unroll
    for (int nb = 0; nb < 4; nb++) {
      int col = j0 + wx * 64 + nb * 16 + m;
#pragma unroll
      for (int p = 0; p < 4; p++) {
        int row = i0 + wy * 32 + mb * 16 + quad * 4 + p;
        float v = 2.f * acc[mb][nb][p] - (row == col ? 1.f : 0.f);
        u16 vh, vl;
        split_bf(v, vh, vl);
        size_t a = (size_t)row * Nn + col;
        S2h[a] = vh; S2l[a] = vl;
      }
    }
}

// ---------- Wt prep (split hi/lo, zero-padded rows kp>=198) ----------
__global__ __launch_bounds__(256) void k_prep_wt(const float* __restrict__ W, int Csrc,
                                                 int ncol, u16* __restrict__ Wh,
                                                 u16* __restrict__ Wl) {
  int idx = blockIdx.x * 256 + threadIdx.x;
  if (idx >= ncol * KP) return;
  int n = idx / KP, kp = idx % KP;
  int chunk = kp / Cc, c = kp % Cc;
  float v = 0.f;
  if (kp < 3 * Cc && c < Csrc) v = W[((size_t)chunk * Csrc + c) * ncol + n];
  u16 h, l;
  split_bf(v, h, l);
  Wh[idx] = h; Wl[idx] = l;
}

// ---------- fill enc ----------
__global__ __launch_bounds__(256) void k_fill_enc(const float* __restrict__ x,
                                                  u16* __restrict__ XAh,
                                                  u16* __restrict__ Xth, int t) {
  int idx = blockIdx.x * 256 + threadIdx.x;
  if (idx >= NB) return;
  int n = idx >> 6, b = idx & 63;
  u16 h = bf_rne(x[(size_t)b * TN + t * Nn + n]);
  XAh[(size_t)idx * SA] = h;
  Xth[(size_t)b * Cc * Nn + n] = h;
}

// ---------- dec init ----------
__global__ __launch_bounds__(256) void k_dec_init(const float* __restrict__ x,
                                                  const float* __restrict__ ycov,
                                                  u16* __restrict__ XAh,
                                                  u16* __restrict__ Xth) {
  int idx = blockIdx.x * 256 + threadIdx.x;
  if (idx >= NB) return;
  int n = idx >> 6, b = idx & 63;
  u16 h0 = bf_rne(x[(size_t)b * TN + (size_t)(Tc - 1) * Nn + n]);
  u16 h1 = bf_rne(ycov[(size_t)b * TN + n]);
  XAh[(size_t)idx * SA] = h0;
  XAh[(size_t)idx * SA + 1] = h1;
  Xth[((size_t)b * Cc) * Nn + n] = h0;
  Xth[((size_t)b * Cc + 1) * Nn + n] = h1;
}

// ---------- ygemm: Y1 = S@X, Y2 = S2@X. BM=128 BN=128, LDS 40KB, XCD i0-cluster ----------
// 264 blocks: xcd = b&7 -> i0 = xcd*128 (A set 1MB/XCD); s = b>>3 -> j0 = s*128.
// LDS (u16): A mats sm*4096 (128x32 each), B at 16384. 20480 u16 = 40KB -> 2 blocks/CU.
__global__ __launch_bounds__(256, 2) void k_ygemm(const u16* __restrict__ S1h, const u16* __restrict__ S1l,
                                                  const u16* __restrict__ S2h, const u16* __restrict__ S2l,
                                                  const u16* __restrict__ Xth,
                                                  u16* __restrict__ XA) {
  __shared__ u16 lds[20480];
  const int tid = threadIdx.x;
  const int wave = tid >> 6, lane = tid & 63;
  const int b = blockIdx.x;
  const int i0 = (b & 7) * 128;
  const int j0 = (b >> 3) * 128;
  const int wy = wave >> 1, wx = wave & 1;
  const int m = lane & 15, quad = lane >> 4;

  f32x4 acc1[4][4], acc2[4][4];
  f32x4 z4 = {0.f, 0.f, 0.f, 0.f};
#pragma unroll
  for (int a = 0; a < 4; a++)
#pragma unroll
    for (int q = 0; q < 4; q++) { acc1[a][q] = z4; acc2[a][q] = z4; }

  const u16* amat[4] = {S1h, S1l, S2h, S2l};

  for (int k0 = 0; k0 < Nn; k0 += 32) {
    // stage A (4 mats x 128 rows x 32 K) + B (128 x 32)
#pragma unroll
    for (int sm = 0; sm < 4; sm++)
#pragma unroll
      for (int c = 0; c < 2; c++) {
        int ci = c * 256 + tid;
        int r = ci >> 2, kc = (ci & 3) ^ SWZ(r);
        gld16(amat[sm] + (size_t)(i0 + r) * Nn + k0 + kc * 8,
              &lds[sm * 4096 + c * 2048 + wave * 512]);
      }
#pragma unroll
    for (int c = 0; c < 2; c++) {
      int ci = c * 256 + tid;
      int r = ci >> 2, kc = (ci & 3) ^ SWZ(r);
      gld16(Xth + (size_t)(j0 + r) * Nn + k0 + kc * 8,
            &lds[16384 + c * 2048 + wave * 512]);
    }
    __syncthreads();

    bf16x8 bfr[4];
#pragma unroll
    for (int nb = 0; nb < 4; nb++) {
      int rj = wx * 64 + nb * 16 + m;
      int cj = rj * 4 + (quad ^ SWZ(rj));
      bfr[nb] = *(const bf16x8*)&lds[16384 + cj * 8];
    }
#pragma unroll
    for (int sm = 0; sm < 4; sm++) {
      bf16x8 af[4];
#pragma unroll
      for (int mb = 0; mb < 4; mb++) {
        int r = wy * 64 + mb * 16 + m;
        int ci = r * 4 + (quad ^ SWZ(r));
        af[mb] = *(const bf16x8*)&lds[sm * 4096 + ci * 8];
      }
      if (sm < 2) {
#pragma unroll
        for (int mb = 0; mb < 4; mb++)
#pragma unroll
          for (int nb = 0; nb < 4; nb++)
            acc1[mb][nb] = __builtin_amdgcn_mfma_f32_16x16x32_bf16(af[mb], bfr[nb], acc1[mb][nb], 0, 0, 0);
      } else {
#pragma unroll
        for (int mb = 0; mb < 4; mb++)
#pragma unroll
          for (int nb = 0; nb < 4; nb++)
            acc2[mb][nb] = __builtin_amdgcn_mfma_f32_16x16x32_bf16(af[mb], bfr[nb], acc2[mb][nb], 0, 0, 0);
      }
    }
    __syncthreads();
  }

#pragma unroll
  for (int mb = 0; mb < 4; mb++)
#pragma unroll
    for (int nb = 0; nb < 4; nb++) {
      int col = j0 + wx * 64 + nb * 16 + m;
      int bb = col / Cc, cc = col % Cc;
#pragma unroll
      for (int p = 0; p < 4; p++) {
        int row = i0 + wy * 64 + mb * 16 + quad * 4 + p;
        size_t base = ((size_t)row * 64 + bb) * SA;
        XA[base + 66 + cc] = bf_rne(acc1[mb][nb][p]);
        XA[base + 132 + cc] = bf_rne(acc2[mb][nb][p]);
      }
    }
}

// ---------- gate: sigmoid(XA@W^T+b); A single bf16, W split 2-term ----------
// BM=128, BN=128, K=224. LDS 24KB.
__global__ __launch_bounds__(256) void k_gate(const u16* __restrict__ XA,
                                              const u16* __restrict__ Wh, const u16* __restrict__ Wl,
                                              const float* __restrict__ bias,
                                              const float* __restrict__ hst,
                                              u16* __restrict__ Rb,
                                              u16* __restrict__ XAo,
                                              u16* __restrict__ Xth, int off) {
  __shared__ u16 lds[12288];  // A 4096 | Wh 4096 | Wl 4096
  const int tid = threadIdx.x;
  const int wave = tid >> 6, lane = tid & 63;
  const int r0 = blockIdx.x * 128;
  const int wy = wave >> 1, wx = wave & 1;
  const int m = lane & 15, quad = lane >> 4;

  f32x4 acc[4][4];
  f32x4 z4 = {0.f, 0.f, 0.f, 0.f};
#pragma unroll
  for (int a = 0; a < 4; a++)
#pragma unroll
    for (int q = 0; q < 4; q++) acc[a][q] = z4;

  for (int kt = 0; kt < 7; kt++) {
    int k0 = kt * 32;
#pragma unroll
    for (int c = 0; c < 2; c++) {
      int ci = c * 256 + tid;
      int r = ci >> 2, kc = (ci & 3) ^ SWZ(r);
      gld16(XA + (size_t)(r0 + r) * SA + k0 + kc * 8, &lds[c * 2048 + wave * 512]);
      gld16(Wh + (size_t)r * KP + k0 + kc * 8, &lds[4096 + c * 2048 + wave * 512]);
      gld16(Wl + (size_t)r * KP + k0 + kc * 8, &lds[8192 + c * 2048 + wave * 512]);
    }
    __syncthreads();

    bf16x8 af[4], bh[4], bl[4];
#pragma unroll
    for (int mb = 0; mb < 4; mb++) {
      int r = wy * 64 + mb * 16 + m;
      int ci = r * 4 + (quad ^ SWZ(r));
      af[mb] = *(const bf16x8*)&lds[ci * 8];
    }
#pragma unroll
    for (int nb = 0; nb < 4; nb++) {
      int rj = wx * 64 + nb * 16 + m;
      int cj = rj * 4 + (quad ^ SWZ(rj));
      bh[nb] = *(const bf16x8*)&lds[4096 + cj * 8];
      bl[nb] = *(const bf16x8*)&lds[8192 + cj * 8];
    }
#pragma unroll
    for (int mb = 0; mb < 4; mb++)
#pragma unroll
      for (int nb = 0; nb < 4; nb++) {
        acc[mb][nb] = __builtin_amdgcn_mfma_f32_16x16x32_bf16(af[mb], bh[nb], acc[mb][nb], 0, 0, 0);
        acc[mb][nb] = __builtin_amdgcn_mfma_f32_16x16x32_bf16(af[mb], bl[nb], acc[mb][nb], 0, 0, 0);
      }
    __syncthreads();
  }

#pragma unroll
  for (int mb = 0; mb < 4; mb++)
#pragma unroll
    for (int nb = 0; nb < 4; nb++) {
      int col = wx * 64 + nb * 16 + m;
      float bv = bias[col];
#pragma unroll
      for (int p = 0; p < 4; p++) {
        int row = r0 + wy * 64 + mb * 16 + quad * 4 + p;
        float sg = 1.f / (1.f + expf(-(acc[mb][nb][p] + bv)));
        if (col < 64) {
          float v = sg * hst[(size_t)row * 64 + col];
          u16 vh = bf_rne(v);
          XAo[(size_t)row * SA + off + col] = vh;
          int n = row >> 6, b = row & 63;
          Xth[((size_t)b * Cc + off + col) * Nn + n] = vh;
        } else {
          Rb[(size_t)row * 64 + col - 64] = bf_rne(sg);
        }
      }
    }
}

// ---------- update: hc=tanh(XA@Wu^T+b); h=r*h+(1-r)*hc ----------
// BM=128, BN=64, K=224. LDS 16KB.
__global__ __launch_bounds__(256) void k_upd(const u16* __restrict__ XA,
                                             const u16* __restrict__ Wh, const u16* __restrict__ Wl,
                                             const float* __restrict__ bias,
                                             const u16* __restrict__ Rb,
                                             float* __restrict__ h,
                                             u16* __restrict__ XAo,
                                             u16* __restrict__ Xth, int off_next) {
  __shared__ u16 lds[8192];  // A 4096 | Wh 2048 | Wl 2048
  const int tid = threadIdx.x;
  const int wave = tid >> 6, lane = tid & 63;
  const int r0 = blockIdx.x * 128;
  const int wy = wave >> 1, wx = wave & 1;
  const int m = lane & 15, quad = lane >> 4;

  f32x4 acc[4][2];
  f32x4 z4 = {0.f, 0.f, 0.f, 0.f};
#pragma unroll
  for (int a = 0; a < 4; a++) { acc[a][0] = z4; acc[a][1] = z4; }

  for (int kt = 0; kt < 7; kt++) {
    int k0 = kt * 32;
#pragma unroll
    for (int c = 0; c < 2; c++) {
      int ci = c * 256 + tid;
      int r = ci >> 2, kc = (ci & 3) ^ SWZ(r);
      gld16(XA + (size_t)(r0 + r) * SA + k0 + kc * 8, &lds[c * 2048 + wave * 512]);
    }
    {
      int ci = tid;
      int r = ci >> 2, kc = (ci & 3) ^ SWZ(r);
      gld16(Wh + (size_t)r * KP + k0 + kc * 8, &lds[4096 + wave * 512]);
      gld16(Wl + (size_t)r * KP + k0 + kc * 8, &lds[6144 + wave * 512]);
    }
    __syncthreads();

    bf16x8 af[4], bh[2], bl[2];
#pragma unroll
    for (int mb = 0; mb < 4; mb++) {
      int r = wy * 64 + mb * 16 + m;
      int ci = r * 4 + (quad ^ SWZ(r));
      af[mb] = *(const bf16x8*)&lds[ci * 8];
    }
#pragma unroll
    for (int nb = 0; nb < 2; nb++) {
      int rj = wx * 32 + nb * 16 + m;
      int cj = rj * 4 + (quad ^ SWZ(rj));
      bh[nb] = *(const bf16x8*)&lds[4096 + cj * 8];
      bl[nb] = *(const bf16x8*)&lds[6144 + cj * 8];
    }
#pragma unroll
    for (int mb = 0; mb < 4; mb++)
#pragma unroll
      for (int nb = 0; nb < 2; nb++) {
        acc[mb][nb] = __builtin_amdgcn_mfma_f32_16x16x32_bf16(af[mb], bh[nb], acc[mb][nb], 0, 0, 0);
        acc[mb][nb] = __builtin_amdgcn_mfma_f32_16x16x32_bf16(af[mb], bl[nb], acc[mb][nb], 0, 0, 0);
      }
    __syncthreads();
  }

#pragma unroll
  for (int mb = 0; mb < 4; mb++)
#pragma unroll
    for (int nb = 0; nb < 2; nb++) {
      int col = wx * 32 + nb * 16 + m;
      float bv = bias[col];
#pragma unroll
      for (int p = 0; p < 4; p++) {
        int row = r0 + wy * 64 + mb * 16 + quad * 4 + p;
        float hc = tanhf(acc[mb][nb][p] + bv);
        size_t idx = (size_t)row * 64 + col;
        float rr = bf_to_f(Rb[idx]);
        float hn = rr * h[idx] + (1.f - rr) * hc;
        h[idx] = hn;
        u16 vh = bf_rne(hn);
        XAo[(size_t)row * SA + off_next + col] = vh;
        int n = row >> 6, b = row & 63;
        Xth[((size_t)b * Cc + off_next + col) * Nn + n] = vh;
      }
    }
}

// ---------- de = h @ FC_E, split output ----------
__global__ __launch_bounds__(256) void k_de(const float* __restrict__ h,
                                            const float* __restrict__ fc,
                                            u16* __restrict__ Dh, u16* __restrict__ Dl) {
  __shared__ float fcs[Hc * Ec];
  for (int j = threadIdx.x; j < Hc * Ec; j += 256) fcs[j] = fc[j];
  __syncthreads();
  int idx = blockIdx.x * 256 + threadIdx.x;
  if (idx >= Nn * KD) return;
  int n = idx / KD;
  int rem = idx % KD;
  int b = rem / Ec, e = rem % Ec;
  const float* hp = h + (size_t)n * (Bc * Hc) + (size_t)b * Hc;
  float acc = 0.f;
#pragma unroll 8
  for (int hh = 0; hh < Hc; hh++) acc = fmaf(hp[hh], fcs[hh * Ec + e], acc);
  u16 vh, vl;
  split_bf(acc, vh, vl);
  Dh[idx] = vh; Dl[idx] = vl;
}

// ---------- proj + fill next dec step ----------
__global__ __launch_bounds__(256) void k_proj_fill(const float* __restrict__ h,
                                                   const float* __restrict__ pw,
                                                   const float* __restrict__ pb,
                                                   const float* __restrict__ ycov,
                                                   u16* __restrict__ XAh,
                                                   u16* __restrict__ Xth,
                                                   float* __restrict__ out, int t) {
  int idx = blockIdx.x * 256 + threadIdx.x;
  if (idx >= NB) return;
  int n = idx >> 6, b = idx & 63;
  const float* hp = h + (size_t)idx * Hc;
  float acc = pb[0];
#pragma unroll 8
  for (int i = 0; i < Hc; i++) acc = fmaf(hp[i], pw[i], acc);
  out[(size_t)b * TN + (size_t)t * Nn + n] = acc;
  if (t + 1 < Tc) {
    u16 h0 = bf_rne(acc);
    u16 h1 = bf_rne(ycov[(size_t)b * TN + (size_t)(t + 1) * Nn + n]);
    XAh[(size_t)idx * SA] = h0;
    XAh[(size_t)idx * SA + 1] = h1;
    Xth[((size_t)b * Cc) * Nn + n] = h0;
    Xth[((size_t)b * Cc + 1) * Nn + n] = h1;
  }
}

extern "C" void kernel_launch(void* const* d_in, const int* in_sizes, int n_in,
                              void* d_out, int out_size, void* d_ws, size_t ws_size,
                              hipStream_t stream) {
  (void)in_sizes; (void)n_in; (void)out_size; (void)ws_size;
  const float* x    = (const float*)d_in[0];
  const float* ycov = (const float*)d_in[1];
  const float* emb  = (const float*)d_in[2];
  const float* fce  = (const float*)d_in[3];
  const float* egw  = (const float*)d_in[4];
  const float* egb  = (const float*)d_in[5];
  const float* euw  = (const float*)d_in[6];
  const float* eub  = (const float*)d_in[7];
  const float* dgw  = (const float*)d_in[8];
  const float* dgb  = (const float*)d_in[9];
  const float* duw  = (const float*)d_in[10];
  const float* dub  = (const float*)d_in[11];
  const float* pw   = (const float*)d_in[12];
  const float* pb   = (const float*)d_in[13];
  float* out = (float*)d_out;

  char* wsb = (char*)d_ws;
  size_t off = 0;
  auto alloc = [&](size_t bytes) {
    void* p = wsb + off;
    off = (off + bytes + 255) & ~(size_t)255;
    return p;
  };
  float* Gf = (float*)alloc((size_t)Nn * Nn * 4);
  u16* S1h = (u16*)alloc((size_t)Nn * Nn * 2);
  u16* S1l = (u16*)alloc((size_t)Nn * Nn * 2);
  u16* S2h = (u16*)alloc((size_t)Nn * Nn * 2);
  u16* S2l = (u16*)alloc((size_t)Nn * Nn * 2);
  u16* Sth = (u16*)alloc((size_t)Nn * Nn * 2);
  u16* Stl = (u16*)alloc((size_t)Nn * Nn * 2);
  float* Hst = (float*)alloc((size_t)NB * Hc * 4);
  u16* XAh = (u16*)alloc((size_t)(NB + 4) * SA * 2);
  u16* Xth = (u16*)alloc((size_t)Bc * Cc * Nn * 2);
  u16* Rb = (u16*)alloc((size_t)NB * Hc * 2);
  u16* DEh = (u16*)alloc((size_t)Nn * KD * 2);
  u16* DEl = (u16*)alloc((size_t)Nn * KD * 2);
  u16* WgeH = (u16*)alloc(128 * KP * 2); u16* WgeL = (u16*)alloc(128 * KP * 2);
  u16* WueH = (u16*)alloc(64 * KP * 2);  u16* WueL = (u16*)alloc(64 * KP * 2);
  u16* WgdH = (u16*)alloc(128 * KP * 2); u16* WgdL = (u16*)alloc(128 * KP * 2);
  u16* WudH = (u16*)alloc(64 * KP * 2);  u16* WudL = (u16*)alloc(64 * KP * 2);

  hipMemsetAsync(Hst, 0, (size_t)NB * Hc * 4, stream);
  hipMemsetAsync(XAh, 0, (size_t)(NB + 4) * SA * 2, stream);
  hipMemsetAsync(Xth, 0, (size_t)Bc * Cc * Nn * 2, stream);

  k_prep_wt<<<(128 * KP + 255) / 256, 256, 0, stream>>>(egw, 65, 128, WgeH, WgeL);
  k_prep_wt<<<(64 * KP + 255) / 256, 256, 0, stream>>>(euw, 65, 64, WueH, WueL);
  k_prep_wt<<<(128 * KP + 255) / 256, 256, 0, stream>>>(dgw, 66, 128, WgdH, WgdL);
  k_prep_wt<<<(64 * KP + 255) / 256, 256, 0, stream>>>(duw, 66, 64, WudH, WudL);

  // encoder supports
  k_gram<<<dim3(16, 16), 256, 0, stream>>>(emb, Ec, Gf);
  k_softmax<<<Nn, 256, 0, stream>>>(Gf, S1h, S1l);
  k_tr2<<<dim3(16, 16), 256, 0, stream>>>(S1h, S1l, Sth, Stl);
  k_s2_mfma<<<dim3(8, 16), 256, 0, stream>>>(S1h, S1l, Sth, Stl, S2h, S2l);

  const int gNB = NB / 256;

  for (int t = 0; t < Tc; t++) {
    k_fill_enc<<<gNB, 256, 0, stream>>>(x, XAh, Xth, t);
    k_ygemm<<<264, 256, 0, stream>>>(S1h, S1l, S2h, S2l, Xth, XAh);
    k_gate<<<512, 256, 0, stream>>>(XAh, WgeH, WgeL, egb, Hst, Rb, XAh, Xth, 1);
    k_ygemm<<<264, 256, 0, stream>>>(S1h, S1l, S2h, S2l, Xth, XAh);
    k_upd<<<512, 256, 0, stream>>>(XAh, WueH, WueL, eub, Rb, Hst, XAh, Xth,
                                   (t == Tc - 1) ? 2 : 1);
  }

  // decoder supports
  k_de<<<(Nn * KD + 255) / 256, 256, 0, stream>>>(Hst, fce, DEh, DEl);
  k_gram_mfma<<<dim3(8, 16), 256, 0, stream>>>(DEh, DEl, Gf);
  k_softmax<<<Nn, 256, 0, stream>>>(Gf, S1h, S1l);
  k_tr2<<<dim3(16, 16), 256, 0, stream>>>(S1h, S1l, Sth, Stl);
  k_s2_mfma<<<dim3(8, 16), 256, 0, stream>>>(S1h, S1l, Sth, Stl, S2h, S2l);
  k_dec_init<<<gNB, 256, 0, stream>>>(x, ycov, XAh, Xth);

  for (int t = 0; t < Tc; t++) {
    k_ygemm<<<264, 256, 0, stream>>>(S1h, S1l, S2h, S2l, Xth, XAh);
    k_gate<<<512, 256, 0, stream>>>(XAh, WgdH, WgdL, dgb, Hst, Rb, XAh, Xth, 2);
    k_ygemm<<<264, 256, 0, stream>>>(S1h, S1l, S2h, S2l, Xth, XAh);
    k_upd<<<512, 256, 0, stream>>>(XAh, WudH, WudL, dub, Rb, Hst, XAh, Xth, 2);
    k_proj_fill<<<gNB, 256, 0, stream>>>(Hst, pw, pb, ycov, XAh, Xth, out, t);
  }
}

// Round 9
// 4036.305 us; speedup vs baseline: 2.4185x; 1.3462x over previous
//
#include <hip/hip_runtime.h>
#include <math.h>

typedef __attribute__((ext_vector_type(8))) short bf16x8;
typedef __attribute__((ext_vector_type(4))) float f32x4;
typedef unsigned short u16;

namespace {
constexpr int Bc = 64, Tc = 12, Nn = 1024, Hc = 64, Ec = 10;
constexpr int NB = Nn * Bc;  // 65536
constexpr int Cc = 66;       // unified channel count (enc uses 65, col 65 zeroed)
constexpr int SA = 208;      // XA row stride ([X(66)|Y1(66)|Y2(66)|pad10])
constexpr int KP = 224;      // padded K for gate/update GEMMs (7 x 32)
constexpr int KD = Bc * Ec;  // 640, dec gram K
constexpr int TN = Tc * Nn;  // 12288
}

#define SWZ(r) (((r) >> 1) & 3)

__device__ __forceinline__ void gld16(const void* g, void* l) {
  __builtin_amdgcn_global_load_lds(
      (const __attribute__((address_space(1))) void*)g,
      (__attribute__((address_space(3))) void*)l, 16, 0, 0);
}

__device__ __forceinline__ void split_bf(float v, u16& h, u16& l) {
  unsigned u = __float_as_uint(v);
  unsigned hu = (u + 0x7FFFu + ((u >> 16) & 1u)) & 0xFFFF0000u;
  h = (u16)(hu >> 16);
  float r = v - __uint_as_float(hu);
  unsigned u2 = __float_as_uint(r);
  l = (u16)((u2 + 0x7FFFu + ((u2 >> 16) & 1u)) >> 16);
}
__device__ __forceinline__ u16 bf_rne(float v) {
  unsigned u = __float_as_uint(v);
  return (u16)((u + 0x7FFFu + ((u >> 16) & 1u)) >> 16);
}
__device__ __forceinline__ float bf_to_f(u16 v) {
  return __uint_as_float(((unsigned)v) << 16);
}
__device__ __forceinline__ bf16x8 ldfrag(const u16* p) { return *(const bf16x8*)p; }

// ---------- enc gram: G = emb @ emb^T (Kd small, fp32) ----------
__global__ __launch_bounds__(256) void k_gram(const float* __restrict__ in, int Kd,
                                              float* __restrict__ G) {
  __shared__ float At[16][64];
  __shared__ float Bt[16][64];
  int i0 = blockIdx.y * 64, j0 = blockIdx.x * 64;
  int tx = threadIdx.x & 15, ty = threadIdx.x >> 4;
  float acc[4][4] = {};
  for (int k0 = 0; k0 < Kd; k0 += 16) {
    for (int u = threadIdx.x; u < 1024; u += 256) {
      int i = u >> 4, k = u & 15;
      At[k][i] = (k0 + k < Kd) ? in[(size_t)(i0 + i) * Kd + k0 + k] : 0.f;
    }
    for (int u = threadIdx.x; u < 1024; u += 256) {
      int j = u >> 4, k = u & 15;
      Bt[k][j] = (k0 + k < Kd) ? in[(size_t)(j0 + j) * Kd + k0 + k] : 0.f;
    }
    __syncthreads();
#pragma unroll
    for (int kk = 0; kk < 16; kk++) {
      float a[4], b[4];
#pragma unroll
      for (int p = 0; p < 4; p++) a[p] = At[kk][ty * 4 + p];
#pragma unroll
      for (int q = 0; q < 4; q++) b[q] = Bt[kk][tx * 4 + q];
#pragma unroll
      for (int p = 0; p < 4; p++)
#pragma unroll
        for (int q = 0; q < 4; q++) acc[p][q] = fmaf(a[p], b[q], acc[p][q]);
    }
    __syncthreads();
  }
  for (int p = 0; p < 4; p++)
    for (int q = 0; q < 4; q++)
      G[(size_t)(i0 + ty * 4 + p) * Nn + j0 + tx * 4 + q] = acc[p][q];
}

// ---------- dec gram via split-MFMA: G = DE @ DE^T ----------
__global__ __launch_bounds__(256) void k_gram_mfma(const u16* __restrict__ Dh,
                                                   const u16* __restrict__ Dl,
                                                   float* __restrict__ G) {
  __shared__ u16 lds[12288];
  const int tid = threadIdx.x;
  const int wave = tid >> 6, lane = tid & 63;
  const int i0 = blockIdx.y * 64;
  const int j0 = blockIdx.x * 128;
  const int wy = wave >> 1, wx = wave & 1;
  const int m = lane & 15, quad = lane >> 4;

  f32x4 acc[2][4];
  f32x4 z4 = {0.f, 0.f, 0.f, 0.f};
#pragma unroll
  for (int a = 0; a < 2; a++)
#pragma unroll
    for (int q = 0; q < 4; q++) acc[a][q] = z4;

  const int ar = tid >> 2;
  const int akc = (tid & 3) ^ SWZ(ar);

  for (int k0 = 0; k0 < KD; k0 += 32) {
    gld16(Dh + (size_t)(i0 + ar) * KD + k0 + akc * 8, &lds[wave * 512]);
    gld16(Dl + (size_t)(i0 + ar) * KD + k0 + akc * 8, &lds[2048 + wave * 512]);
#pragma unroll
    for (int p = 0; p < 2; p++) {
      int r = p * 64 + (tid >> 2);
      int kc = (tid & 3) ^ SWZ(r);
      gld16(Dh + (size_t)(j0 + r) * KD + k0 + kc * 8, &lds[4096 + p * 2048 + wave * 512]);
      gld16(Dl + (size_t)(j0 + r) * KD + k0 + kc * 8, &lds[8192 + p * 2048 + wave * 512]);
    }
    __syncthreads();

    bf16x8 ah[2], al[2], bh[4], bl[4];
#pragma unroll
    for (int mb = 0; mb < 2; mb++) {
      int r = wy * 32 + mb * 16 + m;
      int ci = r * 4 + (quad ^ SWZ(r));
      ah[mb] = *(const bf16x8*)&lds[ci * 8];
      al[mb] = *(const bf16x8*)&lds[2048 + ci * 8];
    }
#pragma unroll
    for (int nb = 0; nb < 4; nb++) {
      int rj = wx * 64 + nb * 16 + m;
      int cj = rj * 4 + (quad ^ SWZ(rj));
      bh[nb] = *(const bf16x8*)&lds[4096 + cj * 8];
      bl[nb] = *(const bf16x8*)&lds[8192 + cj * 8];
    }
#pragma unroll
    for (int mb = 0; mb < 2; mb++)
#pragma unroll
      for (int nb = 0; nb < 4; nb++) {
        acc[mb][nb] = __builtin_amdgcn_mfma_f32_16x16x32_bf16(ah[mb], bh[nb], acc[mb][nb], 0, 0, 0);
        acc[mb][nb] = __builtin_amdgcn_mfma_f32_16x16x32_bf16(ah[mb], bl[nb], acc[mb][nb], 0, 0, 0);
        acc[mb][nb] = __builtin_amdgcn_mfma_f32_16x16x32_bf16(al[mb], bh[nb], acc[mb][nb], 0, 0, 0);
      }
    __syncthreads();
  }

#pragma unroll
  for (int mb = 0; mb < 2; mb++)
#pragma unroll
    for (int nb = 0; nb < 4; nb++) {
      int col = j0 + wx * 64 + nb * 16 + m;
#pragma unroll
      for (int p = 0; p < 4; p++) {
        int row = i0 + wy * 32 + mb * 16 + quad * 4 + p;
        G[(size_t)row * Nn + col] = acc[mb][nb][p];
      }
    }
}

// ---------- S = row_softmax(relu(G)) -> split to S1h/S1l (split feeds k_s2_mfma) ----------
__global__ __launch_bounds__(256) void k_softmax(const float* __restrict__ G,
                                                 u16* __restrict__ S1h,
                                                 u16* __restrict__ S1l) {
  __shared__ float sred[8];
  int n = blockIdx.x;
  float v[4];
#pragma unroll
  for (int i = 0; i < 4; i++)
    v[i] = fmaxf(G[(size_t)n * Nn + threadIdx.x + i * 256], 0.f);
  float mx = fmaxf(fmaxf(v[0], v[1]), fmaxf(v[2], v[3]));
  for (int off = 32; off > 0; off >>= 1) mx = fmaxf(mx, __shfl_down(mx, off));
  if ((threadIdx.x & 63) == 0) sred[threadIdx.x >> 6] = mx;
  __syncthreads();
  float rmax = fmaxf(fmaxf(sred[0], sred[1]), fmaxf(sred[2], sred[3]));
  float s = 0.f;
#pragma unroll
  for (int i = 0; i < 4; i++) { v[i] = expf(v[i] - rmax); s += v[i]; }
  for (int off = 32; off > 0; off >>= 1) s += __shfl_down(s, off);
  if ((threadIdx.x & 63) == 0) sred[4 + (threadIdx.x >> 6)] = s;
  __syncthreads();
  float inv = 1.f / (sred[4] + sred[5] + sred[6] + sred[7]);
#pragma unroll
  for (int i = 0; i < 4; i++) {
    u16 h, l;
    split_bf(v[i] * inv, h, l);
    size_t a = (size_t)n * Nn + threadIdx.x + i * 256;
    S1h[a] = h; S1l[a] = l;
  }
}

// ---------- transpose S1h/S1l -> Sth/Stl ----------
__global__ __launch_bounds__(256) void k_tr2(const u16* __restrict__ Ah,
                                             const u16* __restrict__ Al,
                                             u16* __restrict__ Th, u16* __restrict__ Tl) {
  __shared__ u16 sm[64][72];
  int i0 = blockIdx.y * 64, j0 = blockIdx.x * 64;
  int tid = threadIdx.x;
  for (int pass = 0; pass < 2; pass++) {
    const u16* src = pass ? Al : Ah;
    u16* dst = pass ? Tl : Th;
    for (int u = tid; u < 4096; u += 256) {
      int i = u >> 6, c = u & 63;
      sm[i][c] = src[(size_t)(i0 + i) * Nn + j0 + c];
    }
    __syncthreads();
    for (int u = tid; u < 4096; u += 256) {
      int c = u >> 6, i = u & 63;
      dst[(size_t)(j0 + c) * Nn + i0 + i] = sm[i][c];
    }
    __syncthreads();
  }
}

// ---------- S2 = 2*S@S - I via direct-fragment split MFMA (3-term inside, bf16 out) ----------
__global__ __launch_bounds__(256) void k_s2_mfma(const u16* __restrict__ S1h,
                                                 const u16* __restrict__ S1l,
                                                 const u16* __restrict__ Sth,
                                                 const u16* __restrict__ Stl,
                                                 u16* __restrict__ S2h) {
  const int tid = threadIdx.x;
  const int wave = tid >> 6, lane = tid & 63;
  const int i0 = blockIdx.y * 64, j0 = blockIdx.x * 128;
  const int wy = wave >> 1, wx = wave & 1;
  const int m = lane & 15, quad = lane >> 4;

  const size_t aoff = (size_t)(i0 + wy * 32 + m) * Nn + quad * 8;
  const size_t boff = (size_t)(j0 + wx * 64 + m) * Nn + quad * 8;

  f32x4 acc[2][4];
  f32x4 z4 = {0.f, 0.f, 0.f, 0.f};
#pragma unroll
  for (int a = 0; a < 2; a++)
#pragma unroll
    for (int q = 0; q < 4; q++) acc[a][q] = z4;

  bf16x8 fAh[2][2], fAl[2][2], fBh[2][4], fBl[2][4];
  auto ld = [&](int k0, int s) {
#pragma unroll
    for (int mb = 0; mb < 2; mb++) {
      fAh[s][mb] = ldfrag(S1h + aoff + (size_t)mb * 16 * Nn + k0);
      fAl[s][mb] = ldfrag(S1l + aoff + (size_t)mb * 16 * Nn + k0);
    }
#pragma unroll
    for (int nb = 0; nb < 4; nb++) {
      fBh[s][nb] = ldfrag(Sth + boff + (size_t)nb * 16 * Nn + k0);
      fBl[s][nb] = ldfrag(Stl + boff + (size_t)nb * 16 * Nn + k0);
    }
  };
  ld(0, 0);
#pragma unroll 2
  for (int kt = 0; kt < 32; kt++) {
    int cur = kt & 1;
    if (kt < 31) ld((kt + 1) * 32, cur ^ 1);
#pragma unroll
    for (int mb = 0; mb < 2; mb++)
#pragma unroll
      for (int nb = 0; nb < 4; nb++) {
        acc[mb][nb] = __builtin_amdgcn_mfma_f32_16x16x32_bf16(fAh[cur][mb], fBh[cur][nb], acc[mb][nb], 0, 0, 0);
        acc[mb][nb] = __builtin_amdgcn_mfma_f32_16x16x32_bf16(fAh[cur][mb], fBl[cur][nb], acc[mb][nb], 0, 0, 0);
        acc[mb][nb] = __builtin_amdgcn_mfma_f32_16x16x32_bf16(fAl[cur][mb], fBh[cur][nb], acc[mb][nb], 0, 0, 0);
      }
  }

#pragma unroll
  for (int mb = 0; mb < 2; mb++)
#pragma unroll
    for (int nb = 0; nb < 4; nb++) {
      int col = j0 + wx * 64 + nb * 16 + m;
#pragma unroll
      for (int p = 0; p < 4; p++) {
        int row = i0 + wy * 32 + mb * 16 + quad * 4 + p;
        float v = 2.f * acc[mb][nb][p] - (row == col ? 1.f : 0.f);
        S2h[(size_t)row * Nn + col] = bf_rne(v);
      }
    }
}

// ---------- Wt prep (split hi/lo) ----------
__global__ __launch_bounds__(256) void k_prep_wt(const float* __restrict__ W, int Csrc,
                                                 int ncol, u16* __restrict__ Wh,
                                                 u16* __restrict__ Wl) {
  int idx = blockIdx.x * 256 + threadIdx.x;
  if (idx >= ncol * KP) return;
  int n = idx / KP, kp = idx % KP;
  int chunk = kp / Cc, c = kp % Cc;
  float v = 0.f;
  if (kp < 3 * Cc && c < Csrc) v = W[((size_t)chunk * Csrc + c) * ncol + n];
  u16 h, l;
  split_bf(v, h, l);
  Wh[idx] = h; Wl[idx] = l;
}

// ---------- fill enc ----------
__global__ __launch_bounds__(256) void k_fill_enc(const float* __restrict__ x,
                                                  u16* __restrict__ XAh,
                                                  u16* __restrict__ Xth, int t) {
  int idx = blockIdx.x * 256 + threadIdx.x;
  if (idx >= NB) return;
  int n = idx >> 6, b = idx & 63;
  u16 h = bf_rne(x[(size_t)b * TN + t * Nn + n]);
  XAh[(size_t)idx * SA] = h;
  Xth[(size_t)b * Cc * Nn + n] = h;
}

// ---------- dec init ----------
__global__ __launch_bounds__(256) void k_dec_init(const float* __restrict__ x,
                                                  const float* __restrict__ ycov,
                                                  u16* __restrict__ XAh,
                                                  u16* __restrict__ Xth) {
  int idx = blockIdx.x * 256 + threadIdx.x;
  if (idx >= NB) return;
  int n = idx >> 6, b = idx & 63;
  u16 h0 = bf_rne(x[(size_t)b * TN + (size_t)(Tc - 1) * Nn + n]);
  u16 h1 = bf_rne(ycov[(size_t)b * TN + n]);
  XAh[(size_t)idx * SA] = h0;
  XAh[(size_t)idx * SA + 1] = h1;
  Xth[((size_t)b * Cc) * Nn + n] = h0;
  Xth[((size_t)b * Cc + 1) * Nn + n] = h1;
}

// ---------- ygemm: Y1 = S1@X, Y2 = S2@X. Single-bf16 S, dbuf LDS, XCD i0-cluster ----------
// 264 blocks: xcd = b&7 -> i0 = xcd*128; s = b>>3 -> j0 = s*128.
// LDS per buf (u16): S1 4096 | S2 4096 | B 4096 = 24KB; dbuf = 48KB.
__global__ __launch_bounds__(256, 2) void k_ygemm(const u16* __restrict__ S1h,
                                                  const u16* __restrict__ S2h,
                                                  const u16* __restrict__ Xth,
                                                  u16* __restrict__ XA) {
  __shared__ u16 lds[2][12288];
  const int tid = threadIdx.x;
  const int wave = tid >> 6, lane = tid & 63;
  const int b = blockIdx.x;
  const int i0 = (b & 7) * 128;
  const int j0 = (b >> 3) * 128;
  const int wy = wave >> 1, wx = wave & 1;
  const int m = lane & 15, quad = lane >> 4;

  f32x4 acc1[4][4], acc2[4][4];
  f32x4 z4 = {0.f, 0.f, 0.f, 0.f};
#pragma unroll
  for (int a = 0; a < 4; a++)
#pragma unroll
    for (int q = 0; q < 4; q++) { acc1[a][q] = z4; acc2[a][q] = z4; }

  auto stage = [&](int k0, int buf) {
#pragma unroll
    for (int c = 0; c < 2; c++) {
      int ci = c * 256 + tid;
      int r = ci >> 2, kc = (ci & 3) ^ SWZ(r);
      gld16(S1h + (size_t)(i0 + r) * Nn + k0 + kc * 8, &lds[buf][c * 2048 + wave * 512]);
      gld16(S2h + (size_t)(i0 + r) * Nn + k0 + kc * 8, &lds[buf][4096 + c * 2048 + wave * 512]);
      gld16(Xth + (size_t)(j0 + r) * Nn + k0 + kc * 8, &lds[buf][8192 + c * 2048 + wave * 512]);
    }
  };

  stage(0, 0);
  for (int kt = 0; kt < 32; kt++) {
    int cur = kt & 1;
    __syncthreads();  // drains stage(buf[cur]); fences prior reads of buf[cur^1]
    if (kt < 31) stage((kt + 1) * 32, cur ^ 1);

    bf16x8 bfr[4];
#pragma unroll
    for (int nb = 0; nb < 4; nb++) {
      int rj = wx * 64 + nb * 16 + m;
      int cj = rj * 4 + (quad ^ SWZ(rj));
      bfr[nb] = *(const bf16x8*)&lds[cur][8192 + cj * 8];
    }
    bf16x8 a1[4], a2[4];
#pragma unroll
    for (int mb = 0; mb < 4; mb++) {
      int r = wy * 64 + mb * 16 + m;
      int ci = r * 4 + (quad ^ SWZ(r));
      a1[mb] = *(const bf16x8*)&lds[cur][ci * 8];
      a2[mb] = *(const bf16x8*)&lds[cur][4096 + ci * 8];
    }
#pragma unroll
    for (int mb = 0; mb < 4; mb++)
#pragma unroll
      for (int nb = 0; nb < 4; nb++) {
        acc1[mb][nb] = __builtin_amdgcn_mfma_f32_16x16x32_bf16(a1[mb], bfr[nb], acc1[mb][nb], 0, 0, 0);
        acc2[mb][nb] = __builtin_amdgcn_mfma_f32_16x16x32_bf16(a2[mb], bfr[nb], acc2[mb][nb], 0, 0, 0);
      }
  }

#pragma unroll
  for (int mb = 0; mb < 4; mb++)
#pragma unroll
    for (int nb = 0; nb < 4; nb++) {
      int col = j0 + wx * 64 + nb * 16 + m;
      int bb = col / Cc, cc = col % Cc;
#pragma unroll
      for (int p = 0; p < 4; p++) {
        int row = i0 + wy * 64 + mb * 16 + quad * 4 + p;
        size_t base = ((size_t)row * 64 + bb) * SA;
        XA[base + 66 + cc] = bf_rne(acc1[mb][nb][p]);
        XA[base + 132 + cc] = bf_rne(acc2[mb][nb][p]);
      }
    }
}

// ---------- gate: sigmoid(XA@W^T+b); A single bf16, W split 2-term ----------
__global__ __launch_bounds__(256) void k_gate(const u16* __restrict__ XA,
                                              const u16* __restrict__ Wh, const u16* __restrict__ Wl,
                                              const float* __restrict__ bias,
                                              const float* __restrict__ hst,
                                              u16* __restrict__ Rb,
                                              u16* __restrict__ XAo,
                                              u16* __restrict__ Xth, int off) {
  __shared__ u16 lds[12288];  // A 4096 | Wh 4096 | Wl 4096
  const int tid = threadIdx.x;
  const int wave = tid >> 6, lane = tid & 63;
  const int r0 = blockIdx.x * 128;
  const int wy = wave >> 1, wx = wave & 1;
  const int m = lane & 15, quad = lane >> 4;

  f32x4 acc[4][4];
  f32x4 z4 = {0.f, 0.f, 0.f, 0.f};
#pragma unroll
  for (int a = 0; a < 4; a++)
#pragma unroll
    for (int q = 0; q < 4; q++) acc[a][q] = z4;

  for (int kt = 0; kt < 7; kt++) {
    int k0 = kt * 32;
#pragma unroll
    for (int c = 0; c < 2; c++) {
      int ci = c * 256 + tid;
      int r = ci >> 2, kc = (ci & 3) ^ SWZ(r);
      gld16(XA + (size_t)(r0 + r) * SA + k0 + kc * 8, &lds[c * 2048 + wave * 512]);
      gld16(Wh + (size_t)r * KP + k0 + kc * 8, &lds[4096 + c * 2048 + wave * 512]);
      gld16(Wl + (size_t)r * KP + k0 + kc * 8, &lds[8192 + c * 2048 + wave * 512]);
    }
    __syncthreads();

    bf16x8 af[4], bh[4], bl[4];
#pragma unroll
    for (int mb = 0; mb < 4; mb++) {
      int r = wy * 64 + mb * 16 + m;
      int ci = r * 4 + (quad ^ SWZ(r));
      af[mb] = *(const bf16x8*)&lds[ci * 8];
    }
#pragma unroll
    for (int nb = 0; nb < 4; nb++) {
      int rj = wx * 64 + nb * 16 + m;
      int cj = rj * 4 + (quad ^ SWZ(rj));
      bh[nb] = *(const bf16x8*)&lds[4096 + cj * 8];
      bl[nb] = *(const bf16x8*)&lds[8192 + cj * 8];
    }
#pragma unroll
    for (int mb = 0; mb < 4; mb++)
#pragma unroll
      for (int nb = 0; nb < 4; nb++) {
        acc[mb][nb] = __builtin_amdgcn_mfma_f32_16x16x32_bf16(af[mb], bh[nb], acc[mb][nb], 0, 0, 0);
        acc[mb][nb] = __builtin_amdgcn_mfma_f32_16x16x32_bf16(af[mb], bl[nb], acc[mb][nb], 0, 0, 0);
      }
    __syncthreads();
  }

#pragma unroll
  for (int mb = 0; mb < 4; mb++)
#pragma unroll
    for (int nb = 0; nb < 4; nb++) {
      int col = wx * 64 + nb * 16 + m;
      float bv = bias[col];
#pragma unroll
      for (int p = 0; p < 4; p++) {
        int row = r0 + wy * 64 + mb * 16 + quad * 4 + p;
        float sg = 1.f / (1.f + expf(-(acc[mb][nb][p] + bv)));
        if (col < 64) {
          float v = sg * hst[(size_t)row * 64 + col];
          u16 vh = bf_rne(v);
          XAo[(size_t)row * SA + off + col] = vh;
          int n = row >> 6, b = row & 63;
          Xth[((size_t)b * Cc + off + col) * Nn + n] = vh;
        } else {
          Rb[(size_t)row * 64 + col - 64] = bf_rne(sg);
        }
      }
    }
}

// ---------- update: hc=tanh(XA@Wu^T+b); h=r*h+(1-r)*hc ----------
__global__ __launch_bounds__(256) void k_upd(const u16* __restrict__ XA,
                                             const u16* __restrict__ Wh, const u16* __restrict__ Wl,
                                             const float* __restrict__ bias,
                                             const u16* __restrict__ Rb,
                                             float* __restrict__ h,
                                             u16* __restrict__ XAo,
                                             u16* __restrict__ Xth, int off_next) {
  __shared__ u16 lds[8192];  // A 4096 | Wh 2048 | Wl 2048
  const int tid = threadIdx.x;
  const int wave = tid >> 6, lane = tid & 63;
  const int r0 = blockIdx.x * 128;
  const int wy = wave >> 1, wx = wave & 1;
  const int m = lane & 15, quad = lane >> 4;

  f32x4 acc[4][2];
  f32x4 z4 = {0.f, 0.f, 0.f, 0.f};
#pragma unroll
  for (int a = 0; a < 4; a++) { acc[a][0] = z4; acc[a][1] = z4; }

  for (int kt = 0; kt < 7; kt++) {
    int k0 = kt * 32;
#pragma unroll
    for (int c = 0; c < 2; c++) {
      int ci = c * 256 + tid;
      int r = ci >> 2, kc = (ci & 3) ^ SWZ(r);
      gld16(XA + (size_t)(r0 + r) * SA + k0 + kc * 8, &lds[c * 2048 + wave * 512]);
    }
    {
      int ci = tid;
      int r = ci >> 2, kc = (ci & 3) ^ SWZ(r);
      gld16(Wh + (size_t)r * KP + k0 + kc * 8, &lds[4096 + wave * 512]);
      gld16(Wl + (size_t)r * KP + k0 + kc * 8, &lds[6144 + wave * 512]);
    }
    __syncthreads();

    bf16x8 af[4], bh[2], bl[2];
#pragma unroll
    for (int mb = 0; mb < 4; mb++) {
      int r = wy * 64 + mb * 16 + m;
      int ci = r * 4 + (quad ^ SWZ(r));
      af[mb] = *(const bf16x8*)&lds[ci * 8];
    }
#pragma unroll
    for (int nb = 0; nb < 2; nb++) {
      int rj = wx * 32 + nb * 16 + m;
      int cj = rj * 4 + (quad ^ SWZ(rj));
      bh[nb] = *(const bf16x8*)&lds[4096 + cj * 8];
      bl[nb] = *(const bf16x8*)&lds[6144 + cj * 8];
    }
#pragma unroll
    for (int mb = 0; mb < 4; mb++)
#pragma unroll
      for (int nb = 0; nb < 2; nb++) {
        acc[mb][nb] = __builtin_amdgcn_mfma_f32_16x16x32_bf16(af[mb], bh[nb], acc[mb][nb], 0, 0, 0);
        acc[mb][nb] = __builtin_amdgcn_mfma_f32_16x16x32_bf16(af[mb], bl[nb], acc[mb][nb], 0, 0, 0);
      }
    __syncthreads();
  }

#pragma unroll
  for (int mb = 0; mb < 4; mb++)
#pragma unroll
    for (int nb = 0; nb < 2; nb++) {
      int col = wx * 32 + nb * 16 + m;
      float bv = bias[col];
#pragma unroll
      for (int p = 0; p < 4; p++) {
        int row = r0 + wy * 64 + mb * 16 + quad * 4 + p;
        float hc = tanhf(acc[mb][nb][p] + bv);
        size_t idx = (size_t)row * 64 + col;
        float rr = bf_to_f(Rb[idx]);
        float hn = rr * h[idx] + (1.f - rr) * hc;
        h[idx] = hn;
        u16 vh = bf_rne(hn);
        XAo[(size_t)row * SA + off_next + col] = vh;
        int n = row >> 6, b = row & 63;
        Xth[((size_t)b * Cc + off_next + col) * Nn + n] = vh;
      }
    }
}

// ---------- de = h @ FC_E, split output ----------
__global__ __launch_bounds__(256) void k_de(const float* __restrict__ h,
                                            const float* __restrict__ fc,
                                            u16* __restrict__ Dh, u16* __restrict__ Dl) {
  __shared__ float fcs[Hc * Ec];
  for (int j = threadIdx.x; j < Hc * Ec; j += 256) fcs[j] = fc[j];
  __syncthreads();
  int idx = blockIdx.x * 256 + threadIdx.x;
  if (idx >= Nn * KD) return;
  int n = idx / KD;
  int rem = idx % KD;
  int b = rem / Ec, e = rem % Ec;
  const float* hp = h + (size_t)n * (Bc * Hc) + (size_t)b * Hc;
  float acc = 0.f;
#pragma unroll 8
  for (int hh = 0; hh < Hc; hh++) acc = fmaf(hp[hh], fcs[hh * Ec + e], acc);
  u16 vh, vl;
  split_bf(acc, vh, vl);
  Dh[idx] = vh; Dl[idx] = vl;
}

// ---------- proj + fill next dec step ----------
__global__ __launch_bounds__(256) void k_proj_fill(const float* __restrict__ h,
                                                   const float* __restrict__ pw,
                                                   const float* __restrict__ pb,
                                                   const float* __restrict__ ycov,
                                                   u16* __restrict__ XAh,
                                                   u16* __restrict__ Xth,
                                                   float* __restrict__ out, int t) {
  int idx = blockIdx.x * 256 + threadIdx.x;
  if (idx >= NB) return;
  int n = idx >> 6, b = idx & 63;
  const float* hp = h + (size_t)idx * Hc;
  float acc = pb[0];
#pragma unroll 8
  for (int i = 0; i < Hc; i++) acc = fmaf(hp[i], pw[i], acc);
  out[(size_t)b * TN + (size_t)t * Nn + n] = acc;
  if (t + 1 < Tc) {
    u16 h0 = bf_rne(acc);
    u16 h1 = bf_rne(ycov[(size_t)b * TN + (size_t)(t + 1) * Nn + n]);
    XAh[(size_t)idx * SA] = h0;
    XAh[(size_t)idx * SA + 1] = h1;
    Xth[((size_t)b * Cc) * Nn + n] = h0;
    Xth[((size_t)b * Cc + 1) * Nn + n] = h1;
  }
}

extern "C" void kernel_launch(void* const* d_in, const int* in_sizes, int n_in,
                              void* d_out, int out_size, void* d_ws, size_t ws_size,
                              hipStream_t stream) {
  (void)in_sizes; (void)n_in; (void)out_size; (void)ws_size;
  const float* x    = (const float*)d_in[0];
  const float* ycov = (const float*)d_in[1];
  const float* emb  = (const float*)d_in[2];
  const float* fce  = (const float*)d_in[3];
  const float* egw  = (const float*)d_in[4];
  const float* egb  = (const float*)d_in[5];
  const float* euw  = (const float*)d_in[6];
  const float* eub  = (const float*)d_in[7];
  const float* dgw  = (const float*)d_in[8];
  const float* dgb  = (const float*)d_in[9];
  const float* duw  = (const float*)d_in[10];
  const float* dub  = (const float*)d_in[11];
  const float* pw   = (const float*)d_in[12];
  const float* pb   = (const float*)d_in[13];
  float* out = (float*)d_out;

  char* wsb = (char*)d_ws;
  size_t off = 0;
  auto alloc = [&](size_t bytes) {
    void* p = wsb + off;
    off = (off + bytes + 255) & ~(size_t)255;
    return p;
  };
  float* Gf = (float*)alloc((size_t)Nn * Nn * 4);
  u16* S1h = (u16*)alloc((size_t)Nn * Nn * 2);
  u16* S1l = (u16*)alloc((size_t)Nn * Nn * 2);
  u16* S2h = (u16*)alloc((size_t)Nn * Nn * 2);
  u16* Sth = (u16*)alloc((size_t)Nn * Nn * 2);
  u16* Stl = (u16*)alloc((size_t)Nn * Nn * 2);
  float* Hst = (float*)alloc((size_t)NB * Hc * 4);
  u16* XAh = (u16*)alloc((size_t)(NB + 4) * SA * 2);
  u16* Xth = (u16*)alloc((size_t)Bc * Cc * Nn * 2);
  u16* Rb = (u16*)alloc((size_t)NB * Hc * 2);
  u16* DEh = (u16*)alloc((size_t)Nn * KD * 2);
  u16* DEl = (u16*)alloc((size_t)Nn * KD * 2);
  u16* WgeH = (u16*)alloc(128 * KP * 2); u16* WgeL = (u16*)alloc(128 * KP * 2);
  u16* WueH = (u16*)alloc(64 * KP * 2);  u16* WueL = (u16*)alloc(64 * KP * 2);
  u16* WgdH = (u16*)alloc(128 * KP * 2); u16* WgdL = (u16*)alloc(128 * KP * 2);
  u16* WudH = (u16*)alloc(64 * KP * 2);  u16* WudL = (u16*)alloc(64 * KP * 2);

  hipMemsetAsync(Hst, 0, (size_t)NB * Hc * 4, stream);
  hipMemsetAsync(XAh, 0, (size_t)(NB + 4) * SA * 2, stream);
  hipMemsetAsync(Xth, 0, (size_t)Bc * Cc * Nn * 2, stream);

  k_prep_wt<<<(128 * KP + 255) / 256, 256, 0, stream>>>(egw, 65, 128, WgeH, WgeL);
  k_prep_wt<<<(64 * KP + 255) / 256, 256, 0, stream>>>(euw, 65, 64, WueH, WueL);
  k_prep_wt<<<(128 * KP + 255) / 256, 256, 0, stream>>>(dgw, 66, 128, WgdH, WgdL);
  k_prep_wt<<<(64 * KP + 255) / 256, 256, 0, stream>>>(duw, 66, 64, WudH, WudL);

  // encoder supports
  k_gram<<<dim3(16, 16), 256, 0, stream>>>(emb, Ec, Gf);
  k_softmax<<<Nn, 256, 0, stream>>>(Gf, S1h, S1l);
  k_tr2<<<dim3(16, 16), 256, 0, stream>>>(S1h, S1l, Sth, Stl);
  k_s2_mfma<<<dim3(8, 16), 256, 0, stream>>>(S1h, S1l, Sth, Stl, S2h);

  const int gNB = NB / 256;

  for (int t = 0; t < Tc; t++) {
    k_fill_enc<<<gNB, 256, 0, stream>>>(x, XAh, Xth, t);
    k_ygemm<<<264, 256, 0, stream>>>(S1h, S2h, Xth, XAh);
    k_gate<<<512, 256, 0, stream>>>(XAh, WgeH, WgeL, egb, Hst, Rb, XAh, Xth, 1);
    k_ygemm<<<264, 256, 0, stream>>>(S1h, S2h, Xth, XAh);
    k_upd<<<512, 256, 0, stream>>>(XAh, WueH, WueL, eub, Rb, Hst, XAh, Xth,
                                   (t == Tc - 1) ? 2 : 1);
  }

  // decoder supports
  k_de<<<(Nn * KD + 255) / 256, 256, 0, stream>>>(Hst, fce, DEh, DEl);
  k_gram_mfma<<<dim3(8, 16), 256, 0, stream>>>(DEh, DEl, Gf);
  k_softmax<<<Nn, 256, 0, stream>>>(Gf, S1h, S1l);
  k_tr2<<<dim3(16, 16), 256, 0, stream>>>(S1h, S1l, Sth, Stl);
  k_s2_mfma<<<dim3(8, 16), 256, 0, stream>>>(S1h, S1l, Sth, Stl, S2h);
  k_dec_init<<<gNB, 256, 0, stream>>>(x, ycov, XAh, Xth);

  for (int t = 0; t < Tc; t++) {
    k_ygemm<<<264, 256, 0, stream>>>(S1h, S2h, Xth, XAh);
    k_gate<<<512, 256, 0, stream>>>(XAh, WgdH, WgdL, dgb, Hst, Rb, XAh, Xth, 2);
    k_ygemm<<<264, 256, 0, stream>>>(S1h, S2h, Xth, XAh);
    k_upd<<<512, 256, 0, stream>>>(XAh, WudH, WudL, dub, Rb, Hst, XAh, Xth, 2);
    k_proj_fill<<<gNB, 256, 0, stream>>>(Hst, pw, pb, ycov, XAh, Xth, out, t);
  }
}

// Round 10
// 3329.335 us; speedup vs baseline: 2.9321x; 1.2123x over previous
//
#include <hip/hip_runtime.h>
#include <math.h>

typedef __attribute__((ext_vector_type(8))) short bf16x8;
typedef __attribute__((ext_vector_type(4))) float f32x4;
typedef unsigned short u16;

namespace {
constexpr int Bc = 64, Tc = 12, Nn = 1024, Hc = 64, Ec = 10;
constexpr int NB = Nn * Bc;  // 65536
constexpr int Cc = 66;       // unified channel count (enc uses 65, col 65 zeroed)
constexpr int SA = 208;      // XA row stride ([X(66)|Y1(66)|Y2(66)|pad10])
constexpr int KP = 224;      // padded K for gate/update GEMMs (7 x 32)
constexpr int KD = Bc * Ec;  // 640, dec gram K
constexpr int TN = Tc * Nn;  // 12288
// Row index convention (R10): rid = b*Nn + n  (b outer, n inner).
}

#define SWZ(r) (((r) >> 1) & 3)

__device__ __forceinline__ void gld16(const void* g, void* l) {
  __builtin_amdgcn_global_load_lds(
      (const __attribute__((address_space(1))) void*)g,
      (__attribute__((address_space(3))) void*)l, 16, 0, 0);
}

__device__ __forceinline__ void split_bf(float v, u16& h, u16& l) {
  unsigned u = __float_as_uint(v);
  unsigned hu = (u + 0x7FFFu + ((u >> 16) & 1u)) & 0xFFFF0000u;
  h = (u16)(hu >> 16);
  float r = v - __uint_as_float(hu);
  unsigned u2 = __float_as_uint(r);
  l = (u16)((u2 + 0x7FFFu + ((u2 >> 16) & 1u)) >> 16);
}
__device__ __forceinline__ u16 bf_rne(float v) {
  unsigned u = __float_as_uint(v);
  return (u16)((u + 0x7FFFu + ((u >> 16) & 1u)) >> 16);
}
__device__ __forceinline__ float bf_to_f(u16 v) {
  return __uint_as_float(((unsigned)v) << 16);
}
__device__ __forceinline__ bf16x8 ldfrag(const u16* p) { return *(const bf16x8*)p; }

// ---------- enc gram: G = emb @ emb^T (Kd small, fp32) ----------
__global__ __launch_bounds__(256) void k_gram(const float* __restrict__ in, int Kd,
                                              float* __restrict__ G) {
  __shared__ float At[16][64];
  __shared__ float Bt[16][64];
  int i0 = blockIdx.y * 64, j0 = blockIdx.x * 64;
  int tx = threadIdx.x & 15, ty = threadIdx.x >> 4;
  float acc[4][4] = {};
  for (int k0 = 0; k0 < Kd; k0 += 16) {
    for (int u = threadIdx.x; u < 1024; u += 256) {
      int i = u >> 4, k = u & 15;
      At[k][i] = (k0 + k < Kd) ? in[(size_t)(i0 + i) * Kd + k0 + k] : 0.f;
    }
    for (int u = threadIdx.x; u < 1024; u += 256) {
      int j = u >> 4, k = u & 15;
      Bt[k][j] = (k0 + k < Kd) ? in[(size_t)(j0 + j) * Kd + k0 + k] : 0.f;
    }
    __syncthreads();
#pragma unroll
    for (int kk = 0; kk < 16; kk++) {
      float a[4], b[4];
#pragma unroll
      for (int p = 0; p < 4; p++) a[p] = At[kk][ty * 4 + p];
#pragma unroll
      for (int q = 0; q < 4; q++) b[q] = Bt[kk][tx * 4 + q];
#pragma unroll
      for (int p = 0; p < 4; p++)
#pragma unroll
        for (int q = 0; q < 4; q++) acc[p][q] = fmaf(a[p], b[q], acc[p][q]);
    }
    __syncthreads();
  }
  for (int p = 0; p < 4; p++)
    for (int q = 0; q < 4; q++)
      G[(size_t)(i0 + ty * 4 + p) * Nn + j0 + tx * 4 + q] = acc[p][q];
}

// ---------- dec gram via split-MFMA: G = DE @ DE^T ----------
__global__ __launch_bounds__(256) void k_gram_mfma(const u16* __restrict__ Dh,
                                                   const u16* __restrict__ Dl,
                                                   float* __restrict__ G) {
  __shared__ u16 lds[12288];
  const int tid = threadIdx.x;
  const int wave = tid >> 6, lane = tid & 63;
  const int i0 = blockIdx.y * 64;
  const int j0 = blockIdx.x * 128;
  const int wy = wave >> 1, wx = wave & 1;
  const int m = lane & 15, quad = lane >> 4;

  f32x4 acc[2][4];
  f32x4 z4 = {0.f, 0.f, 0.f, 0.f};
#pragma unroll
  for (int a = 0; a < 2; a++)
#pragma unroll
    for (int q = 0; q < 4; q++) acc[a][q] = z4;

  const int ar = tid >> 2;
  const int akc = (tid & 3) ^ SWZ(ar);

  for (int k0 = 0; k0 < KD; k0 += 32) {
    gld16(Dh + (size_t)(i0 + ar) * KD + k0 + akc * 8, &lds[wave * 512]);
    gld16(Dl + (size_t)(i0 + ar) * KD + k0 + akc * 8, &lds[2048 + wave * 512]);
#pragma unroll
    for (int p = 0; p < 2; p++) {
      int r = p * 64 + (tid >> 2);
      int kc = (tid & 3) ^ SWZ(r);
      gld16(Dh + (size_t)(j0 + r) * KD + k0 + kc * 8, &lds[4096 + p * 2048 + wave * 512]);
      gld16(Dl + (size_t)(j0 + r) * KD + k0 + kc * 8, &lds[8192 + p * 2048 + wave * 512]);
    }
    __syncthreads();

    bf16x8 ah[2], al[2], bh[4], bl[4];
#pragma unroll
    for (int mb = 0; mb < 2; mb++) {
      int r = wy * 32 + mb * 16 + m;
      int ci = r * 4 + (quad ^ SWZ(r));
      ah[mb] = *(const bf16x8*)&lds[ci * 8];
      al[mb] = *(const bf16x8*)&lds[2048 + ci * 8];
    }
#pragma unroll
    for (int nb = 0; nb < 4; nb++) {
      int rj = wx * 64 + nb * 16 + m;
      int cj = rj * 4 + (quad ^ SWZ(rj));
      bh[nb] = *(const bf16x8*)&lds[4096 + cj * 8];
      bl[nb] = *(const bf16x8*)&lds[8192 + cj * 8];
    }
#pragma unroll
    for (int mb = 0; mb < 2; mb++)
#pragma unroll
      for (int nb = 0; nb < 4; nb++) {
        acc[mb][nb] = __builtin_amdgcn_mfma_f32_16x16x32_bf16(ah[mb], bh[nb], acc[mb][nb], 0, 0, 0);
        acc[mb][nb] = __builtin_amdgcn_mfma_f32_16x16x32_bf16(ah[mb], bl[nb], acc[mb][nb], 0, 0, 0);
        acc[mb][nb] = __builtin_amdgcn_mfma_f32_16x16x32_bf16(al[mb], bh[nb], acc[mb][nb], 0, 0, 0);
      }
    __syncthreads();
  }

#pragma unroll
  for (int mb = 0; mb < 2; mb++)
#pragma unroll
    for (int nb = 0; nb < 4; nb++) {
      int col = j0 + wx * 64 + nb * 16 + m;
#pragma unroll
      for (int p = 0; p < 4; p++) {
        int row = i0 + wy * 32 + mb * 16 + quad * 4 + p;
        G[(size_t)row * Nn + col] = acc[mb][nb][p];
      }
    }
}

// ---------- S = row_softmax(relu(G)) -> split to S1h/S1l ----------
__global__ __launch_bounds__(256) void k_softmax(const float* __restrict__ G,
                                                 u16* __restrict__ S1h,
                                                 u16* __restrict__ S1l) {
  __shared__ float sred[8];
  int n = blockIdx.x;
  float v[4];
#pragma unroll
  for (int i = 0; i < 4; i++)
    v[i] = fmaxf(G[(size_t)n * Nn + threadIdx.x + i * 256], 0.f);
  float mx = fmaxf(fmaxf(v[0], v[1]), fmaxf(v[2], v[3]));
  for (int off = 32; off > 0; off >>= 1) mx = fmaxf(mx, __shfl_down(mx, off));
  if ((threadIdx.x & 63) == 0) sred[threadIdx.x >> 6] = mx;
  __syncthreads();
  float rmax = fmaxf(fmaxf(sred[0], sred[1]), fmaxf(sred[2], sred[3]));
  float s = 0.f;
#pragma unroll
  for (int i = 0; i < 4; i++) { v[i] = expf(v[i] - rmax); s += v[i]; }
  for (int off = 32; off > 0; off >>= 1) s += __shfl_down(s, off);
  if ((threadIdx.x & 63) == 0) sred[4 + (threadIdx.x >> 6)] = s;
  __syncthreads();
  float inv = 1.f / (sred[4] + sred[5] + sred[6] + sred[7]);
#pragma unroll
  for (int i = 0; i < 4; i++) {
    u16 h, l;
    split_bf(v[i] * inv, h, l);
    size_t a = (size_t)n * Nn + threadIdx.x + i * 256;
    S1h[a] = h; S1l[a] = l;
  }
}

// ---------- transpose S1h/S1l -> Sth/Stl ----------
__global__ __launch_bounds__(256) void k_tr2(const u16* __restrict__ Ah,
                                             const u16* __restrict__ Al,
                                             u16* __restrict__ Th, u16* __restrict__ Tl) {
  __shared__ u16 sm[64][72];
  int i0 = blockIdx.y * 64, j0 = blockIdx.x * 64;
  int tid = threadIdx.x;
  for (int pass = 0; pass < 2; pass++) {
    const u16* src = pass ? Al : Ah;
    u16* dst = pass ? Tl : Th;
    for (int u = tid; u < 4096; u += 256) {
      int i = u >> 6, c = u & 63;
      sm[i][c] = src[(size_t)(i0 + i) * Nn + j0 + c];
    }
    __syncthreads();
    for (int u = tid; u < 4096; u += 256) {
      int c = u >> 6, i = u & 63;
      dst[(size_t)(j0 + c) * Nn + i0 + i] = sm[i][c];
    }
    __syncthreads();
  }
}

// ---------- S2 = 2*S@S - I via direct-fragment split MFMA (3-term, bf16 out) ----------
__global__ __launch_bounds__(256) void k_s2_mfma(const u16* __restrict__ S1h,
                                                 const u16* __restrict__ S1l,
                                                 const u16* __restrict__ Sth,
                                                 const u16* __restrict__ Stl,
                                                 u16* __restrict__ S2h) {
  const int tid = threadIdx.x;
  const int wave = tid >> 6, lane = tid & 63;
  const int i0 = blockIdx.y * 64, j0 = blockIdx.x * 128;
  const int wy = wave >> 1, wx = wave & 1;
  const int m = lane & 15, quad = lane >> 4;

  const size_t aoff = (size_t)(i0 + wy * 32 + m) * Nn + quad * 8;
  const size_t boff = (size_t)(j0 + wx * 64 + m) * Nn + quad * 8;

  f32x4 acc[2][4];
  f32x4 z4 = {0.f, 0.f, 0.f, 0.f};
#pragma unroll
  for (int a = 0; a < 2; a++)
#pragma unroll
    for (int q = 0; q < 4; q++) acc[a][q] = z4;

  bf16x8 fAh[2][2], fAl[2][2], fBh[2][4], fBl[2][4];
  auto ld = [&](int k0, int s) {
#pragma unroll
    for (int mb = 0; mb < 2; mb++) {
      fAh[s][mb] = ldfrag(S1h + aoff + (size_t)mb * 16 * Nn + k0);
      fAl[s][mb] = ldfrag(S1l + aoff + (size_t)mb * 16 * Nn + k0);
    }
#pragma unroll
    for (int nb = 0; nb < 4; nb++) {
      fBh[s][nb] = ldfrag(Sth + boff + (size_t)nb * 16 * Nn + k0);
      fBl[s][nb] = ldfrag(Stl + boff + (size_t)nb * 16 * Nn + k0);
    }
  };
  ld(0, 0);
#pragma unroll 2
  for (int kt = 0; kt < 32; kt++) {
    int cur = kt & 1;
    if (kt < 31) ld((kt + 1) * 32, cur ^ 1);
#pragma unroll
    for (int mb = 0; mb < 2; mb++)
#pragma unroll
      for (int nb = 0; nb < 4; nb++) {
        acc[mb][nb] = __builtin_amdgcn_mfma_f32_16x16x32_bf16(fAh[cur][mb], fBh[cur][nb], acc[mb][nb], 0, 0, 0);
        acc[mb][nb] = __builtin_amdgcn_mfma_f32_16x16x32_bf16(fAh[cur][mb], fBl[cur][nb], acc[mb][nb], 0, 0, 0);
        acc[mb][nb] = __builtin_amdgcn_mfma_f32_16x16x32_bf16(fAl[cur][mb], fBh[cur][nb], acc[mb][nb], 0, 0, 0);
      }
  }

#pragma unroll
  for (int mb = 0; mb < 2; mb++)
#pragma unroll
    for (int nb = 0; nb < 4; nb++) {
      int col = j0 + wx * 64 + nb * 16 + m;
#pragma unroll
      for (int p = 0; p < 4; p++) {
        int row = i0 + wy * 32 + mb * 16 + quad * 4 + p;
        float v = 2.f * acc[mb][nb][p] - (row == col ? 1.f : 0.f);
        S2h[(size_t)row * Nn + col] = bf_rne(v);
      }
    }
}

// ---------- Wt prep (split hi/lo) ----------
__global__ __launch_bounds__(256) void k_prep_wt(const float* __restrict__ W, int Csrc,
                                                 int ncol, u16* __restrict__ Wh,
                                                 u16* __restrict__ Wl) {
  int idx = blockIdx.x * 256 + threadIdx.x;
  if (idx >= ncol * KP) return;
  int n = idx / KP, kp = idx % KP;
  int chunk = kp / Cc, c = kp % Cc;
  float v = 0.f;
  if (kp < 3 * Cc && c < Csrc) v = W[((size_t)chunk * Csrc + c) * ncol + n];
  u16 h, l;
  split_bf(v, h, l);
  Wh[idx] = h; Wl[idx] = l;
}

// ---------- fill enc: rid = b*Nn + n ----------
__global__ __launch_bounds__(256) void k_fill_enc(const float* __restrict__ x,
                                                  u16* __restrict__ XAh,
                                                  u16* __restrict__ Xth, int t) {
  int idx = blockIdx.x * 256 + threadIdx.x;
  if (idx >= NB) return;
  int n = idx & (Nn - 1), b = idx >> 10;
  u16 h = bf_rne(x[(size_t)b * TN + t * Nn + n]);
  XAh[(size_t)idx * SA] = h;
  Xth[(size_t)b * Cc * Nn + n] = h;
}

// ---------- dec init ----------
__global__ __launch_bounds__(256) void k_dec_init(const float* __restrict__ x,
                                                  const float* __restrict__ ycov,
                                                  u16* __restrict__ XAh,
                                                  u16* __restrict__ Xth) {
  int idx = blockIdx.x * 256 + threadIdx.x;
  if (idx >= NB) return;
  int n = idx & (Nn - 1), b = idx >> 10;
  u16 h0 = bf_rne(x[(size_t)b * TN + (size_t)(Tc - 1) * Nn + n]);
  u16 h1 = bf_rne(ycov[(size_t)b * TN + n]);
  XAh[(size_t)idx * SA] = h0;
  XAh[(size_t)idx * SA + 1] = h1;
  Xth[((size_t)b * Cc) * Nn + n] = h0;
  Xth[((size_t)b * Cc + 1) * Nn + n] = h1;
}

// ---------- ygemm: Y1 = S1@X, Y2 = S2@X. Single-bf16 S, dbuf LDS, XCD i0-cluster ----------
// 264 blocks: xcd = blk&7 -> i0 = xcd*128 (n-rows); s = blk>>3 -> j0 = s*128 ((b,c) cols).
__global__ __launch_bounds__(256, 2) void k_ygemm(const u16* __restrict__ S1h,
                                                  const u16* __restrict__ S2h,
                                                  const u16* __restrict__ Xth,
                                                  u16* __restrict__ XA) {
  __shared__ u16 lds[2][12288];
  const int tid = threadIdx.x;
  const int wave = tid >> 6, lane = tid & 63;
  const int blk = blockIdx.x;
  const int i0 = (blk & 7) * 128;
  const int j0 = (blk >> 3) * 128;
  const int wy = wave >> 1, wx = wave & 1;
  const int m = lane & 15, quad = lane >> 4;

  f32x4 acc1[4][4], acc2[4][4];
  f32x4 z4 = {0.f, 0.f, 0.f, 0.f};
#pragma unroll
  for (int a = 0; a < 4; a++)
#pragma unroll
    for (int q = 0; q < 4; q++) { acc1[a][q] = z4; acc2[a][q] = z4; }

  auto stage = [&](int k0, int buf) {
#pragma unroll
    for (int c = 0; c < 2; c++) {
      int ci = c * 256 + tid;
      int r = ci >> 2, kc = (ci & 3) ^ SWZ(r);
      gld16(S1h + (size_t)(i0 + r) * Nn + k0 + kc * 8, &lds[buf][c * 2048 + wave * 512]);
      gld16(S2h + (size_t)(i0 + r) * Nn + k0 + kc * 8, &lds[buf][4096 + c * 2048 + wave * 512]);
      gld16(Xth + (size_t)(j0 + r) * Nn + k0 + kc * 8, &lds[buf][8192 + c * 2048 + wave * 512]);
    }
  };

  stage(0, 0);
  for (int kt = 0; kt < 32; kt++) {
    int cur = kt & 1;
    __syncthreads();
    if (kt < 31) stage((kt + 1) * 32, cur ^ 1);

    bf16x8 bfr[4];
#pragma unroll
    for (int nb = 0; nb < 4; nb++) {
      int rj = wx * 64 + nb * 16 + m;
      int cj = rj * 4 + (quad ^ SWZ(rj));
      bfr[nb] = *(const bf16x8*)&lds[cur][8192 + cj * 8];
    }
    bf16x8 a1[4], a2[4];
#pragma unroll
    for (int mb = 0; mb < 4; mb++) {
      int r = wy * 64 + mb * 16 + m;
      int ci = r * 4 + (quad ^ SWZ(r));
      a1[mb] = *(const bf16x8*)&lds[cur][ci * 8];
      a2[mb] = *(const bf16x8*)&lds[cur][4096 + ci * 8];
    }
#pragma unroll
    for (int mb = 0; mb < 4; mb++)
#pragma unroll
      for (int nb = 0; nb < 4; nb++) {
        acc1[mb][nb] = __builtin_amdgcn_mfma_f32_16x16x32_bf16(a1[mb], bfr[nb], acc1[mb][nb], 0, 0, 0);
        acc2[mb][nb] = __builtin_amdgcn_mfma_f32_16x16x32_bf16(a2[mb], bfr[nb], acc2[mb][nb], 0, 0, 0);
      }
  }

  // epilogue: row = n, col = (bb, cc); XA row rid = bb*Nn + n
#pragma unroll
  for (int mb = 0; mb < 4; mb++)
#pragma unroll
    for (int nb = 0; nb < 4; nb++) {
      int col = j0 + wx * 64 + nb * 16 + m;
      int bb = col / Cc, cc = col % Cc;
#pragma unroll
      for (int p = 0; p < 4; p++) {
        int n = i0 + wy * 64 + mb * 16 + quad * 4 + p;
        size_t base = ((size_t)bb * Nn + n) * SA;
        XA[base + 66 + cc] = bf_rne(acc1[mb][nb][p]);
        XA[base + 132 + cc] = bf_rne(acc2[mb][nb][p]);
      }
    }
}

// ---------- gate: sigmoid(XA@W^T+b); A single bf16, W split 2-term ----------
__global__ __launch_bounds__(256) void k_gate(const u16* __restrict__ XA,
                                              const u16* __restrict__ Wh, const u16* __restrict__ Wl,
                                              const float* __restrict__ bias,
                                              const float* __restrict__ hst,
                                              u16* __restrict__ Rb,
                                              u16* __restrict__ XAo,
                                              u16* __restrict__ Xth, int off) {
  __shared__ u16 lds[12288];  // A 4096 | Wh 4096 | Wl 4096
  const int tid = threadIdx.x;
  const int wave = tid >> 6, lane = tid & 63;
  const int r0 = blockIdx.x * 128;
  const int wy = wave >> 1, wx = wave & 1;
  const int m = lane & 15, quad = lane >> 4;

  f32x4 acc[4][4];
  f32x4 z4 = {0.f, 0.f, 0.f, 0.f};
#pragma unroll
  for (int a = 0; a < 4; a++)
#pragma unroll
    for (int q = 0; q < 4; q++) acc[a][q] = z4;

  for (int kt = 0; kt < 7; kt++) {
    int k0 = kt * 32;
#pragma unroll
    for (int c = 0; c < 2; c++) {
      int ci = c * 256 + tid;
      int r = ci >> 2, kc = (ci & 3) ^ SWZ(r);
      gld16(XA + (size_t)(r0 + r) * SA + k0 + kc * 8, &lds[c * 2048 + wave * 512]);
      gld16(Wh + (size_t)r * KP + k0 + kc * 8, &lds[4096 + c * 2048 + wave * 512]);
      gld16(Wl + (size_t)r * KP + k0 + kc * 8, &lds[8192 + c * 2048 + wave * 512]);
    }
    __syncthreads();

    bf16x8 af[4], bh[4], bl[4];
#pragma unroll
    for (int mb = 0; mb < 4; mb++) {
      int r = wy * 64 + mb * 16 + m;
      int ci = r * 4 + (quad ^ SWZ(r));
      af[mb] = *(const bf16x8*)&lds[ci * 8];
    }
#pragma unroll
    for (int nb = 0; nb < 4; nb++) {
      int rj = wx * 64 + nb * 16 + m;
      int cj = rj * 4 + (quad ^ SWZ(rj));
      bh[nb] = *(const bf16x8*)&lds[4096 + cj * 8];
      bl[nb] = *(const bf16x8*)&lds[8192 + cj * 8];
    }
#pragma unroll
    for (int mb = 0; mb < 4; mb++)
#pragma unroll
      for (int nb = 0; nb < 4; nb++) {
        acc[mb][nb] = __builtin_amdgcn_mfma_f32_16x16x32_bf16(af[mb], bh[nb], acc[mb][nb], 0, 0, 0);
        acc[mb][nb] = __builtin_amdgcn_mfma_f32_16x16x32_bf16(af[mb], bl[nb], acc[mb][nb], 0, 0, 0);
      }
    __syncthreads();
  }

#pragma unroll
  for (int mb = 0; mb < 4; mb++)
#pragma unroll
    for (int nb = 0; nb < 4; nb++) {
      int col = wx * 64 + nb * 16 + m;
      float bv = bias[col];
#pragma unroll
      for (int p = 0; p < 4; p++) {
        int rid = r0 + wy * 64 + mb * 16 + quad * 4 + p;
        float sg = 1.f / (1.f + expf(-(acc[mb][nb][p] + bv)));
        if (col < 64) {
          float v = sg * hst[(size_t)rid * 64 + col];
          u16 vh = bf_rne(v);
          XAo[(size_t)rid * SA + off + col] = vh;
          int n = rid & (Nn - 1), b = rid >> 10;
          Xth[((size_t)b * Cc + off + col) * Nn + n] = vh;
        } else {
          Rb[(size_t)rid * 64 + col - 64] = bf_rne(sg);
        }
      }
    }
}

// ---------- update: hc=tanh(XA@Wu^T+b); h=r*h+(1-r)*hc ----------
__global__ __launch_bounds__(256) void k_upd(const u16* __restrict__ XA,
                                             const u16* __restrict__ Wh, const u16* __restrict__ Wl,
                                             const float* __restrict__ bias,
                                             const u16* __restrict__ Rb,
                                             float* __restrict__ h,
                                             u16* __restrict__ XAo,
                                             u16* __restrict__ Xth, int off_next) {
  __shared__ u16 lds[8192];  // A 4096 | Wh 2048 | Wl 2048
  const int tid = threadIdx.x;
  const int wave = tid >> 6, lane = tid & 63;
  const int r0 = blockIdx.x * 128;
  const int wy = wave >> 1, wx = wave & 1;
  const int m = lane & 15, quad = lane >> 4;

  f32x4 acc[4][2];
  f32x4 z4 = {0.f, 0.f, 0.f, 0.f};
#pragma unroll
  for (int a = 0; a < 4; a++) { acc[a][0] = z4; acc[a][1] = z4; }

  for (int kt = 0; kt < 7; kt++) {
    int k0 = kt * 32;
#pragma unroll
    for (int c = 0; c < 2; c++) {
      int ci = c * 256 + tid;
      int r = ci >> 2, kc = (ci & 3) ^ SWZ(r);
      gld16(XA + (size_t)(r0 + r) * SA + k0 + kc * 8, &lds[c * 2048 + wave * 512]);
    }
    {
      int ci = tid;
      int r = ci >> 2, kc = (ci & 3) ^ SWZ(r);
      gld16(Wh + (size_t)r * KP + k0 + kc * 8, &lds[4096 + wave * 512]);
      gld16(Wl + (size_t)r * KP + k0 + kc * 8, &lds[6144 + wave * 512]);
    }
    __syncthreads();

    bf16x8 af[4], bh[2], bl[2];
#pragma unroll
    for (int mb = 0; mb < 4; mb++) {
      int r = wy * 64 + mb * 16 + m;
      int ci = r * 4 + (quad ^ SWZ(r));
      af[mb] = *(const bf16x8*)&lds[ci * 8];
    }
#pragma unroll
    for (int nb = 0; nb < 2; nb++) {
      int rj = wx * 32 + nb * 16 + m;
      int cj = rj * 4 + (quad ^ SWZ(rj));
      bh[nb] = *(const bf16x8*)&lds[4096 + cj * 8];
      bl[nb] = *(const bf16x8*)&lds[6144 + cj * 8];
    }
#pragma unroll
    for (int mb = 0; mb < 4; mb++)
#pragma unroll
      for (int nb = 0; nb < 2; nb++) {
        acc[mb][nb] = __builtin_amdgcn_mfma_f32_16x16x32_bf16(af[mb], bh[nb], acc[mb][nb], 0, 0, 0);
        acc[mb][nb] = __builtin_amdgcn_mfma_f32_16x16x32_bf16(af[mb], bl[nb], acc[mb][nb], 0, 0, 0);
      }
    __syncthreads();
  }

#pragma unroll
  for (int mb = 0; mb < 4; mb++)
#pragma unroll
    for (int nb = 0; nb < 2; nb++) {
      int col = wx * 32 + nb * 16 + m;
      float bv = bias[col];
#pragma unroll
      for (int p = 0; p < 4; p++) {
        int rid = r0 + wy * 64 + mb * 16 + quad * 4 + p;
        float hc = tanhf(acc[mb][nb][p] + bv);
        size_t idx = (size_t)rid * 64 + col;
        float rr = bf_to_f(Rb[idx]);
        float hn = rr * h[idx] + (1.f - rr) * hc;
        h[idx] = hn;
        u16 vh = bf_rne(hn);
        XAo[(size_t)rid * SA + off_next + col] = vh;
        int n = rid & (Nn - 1), b = rid >> 10;
        Xth[((size_t)b * Cc + off_next + col) * Nn + n] = vh;
      }
    }
}

// ---------- de = h @ FC_E, split output (Hst rows rid = b*Nn + n; DE rows n) ----------
__global__ __launch_bounds__(256) void k_de(const float* __restrict__ h,
                                            const float* __restrict__ fc,
                                            u16* __restrict__ Dh, u16* __restrict__ Dl) {
  __shared__ float fcs[Hc * Ec];
  for (int j = threadIdx.x; j < Hc * Ec; j += 256) fcs[j] = fc[j];
  __syncthreads();
  int idx = blockIdx.x * 256 + threadIdx.x;
  if (idx >= Nn * KD) return;
  int n = idx / KD;
  int rem = idx % KD;
  int b = rem / Ec, e = rem % Ec;
  const float* hp = h + ((size_t)b * Nn + n) * Hc;
  float acc = 0.f;
#pragma unroll 8
  for (int hh = 0; hh < Hc; hh++) acc = fmaf(hp[hh], fcs[hh * Ec + e], acc);
  u16 vh, vl;
  split_bf(acc, vh, vl);
  Dh[idx] = vh; Dl[idx] = vl;
}

// ---------- proj + fill next dec step ----------
__global__ __launch_bounds__(256) void k_proj_fill(const float* __restrict__ h,
                                                   const float* __restrict__ pw,
                                                   const float* __restrict__ pb,
                                                   const float* __restrict__ ycov,
                                                   u16* __restrict__ XAh,
                                                   u16* __restrict__ Xth,
                                                   float* __restrict__ out, int t) {
  int idx = blockIdx.x * 256 + threadIdx.x;
  if (idx >= NB) return;
  int n = idx & (Nn - 1), b = idx >> 10;
  const float* hp = h + (size_t)idx * Hc;
  float acc = pb[0];
#pragma unroll 8
  for (int i = 0; i < Hc; i++) acc = fmaf(hp[i], pw[i], acc);
  out[(size_t)b * TN + (size_t)t * Nn + n] = acc;
  if (t + 1 < Tc) {
    u16 h0 = bf_rne(acc);
    u16 h1 = bf_rne(ycov[(size_t)b * TN + (size_t)(t + 1) * Nn + n]);
    XAh[(size_t)idx * SA] = h0;
    XAh[(size_t)idx * SA + 1] = h1;
    Xth[((size_t)b * Cc) * Nn + n] = h0;
    Xth[((size_t)b * Cc + 1) * Nn + n] = h1;
  }
}

extern "C" void kernel_launch(void* const* d_in, const int* in_sizes, int n_in,
                              void* d_out, int out_size, void* d_ws, size_t ws_size,
                              hipStream_t stream) {
  (void)in_sizes; (void)n_in; (void)out_size; (void)ws_size;
  const float* x    = (const float*)d_in[0];
  const float* ycov = (const float*)d_in[1];
  const float* emb  = (const float*)d_in[2];
  const float* fce  = (const float*)d_in[3];
  const float* egw  = (const float*)d_in[4];
  const float* egb  = (const float*)d_in[5];
  const float* euw  = (const float*)d_in[6];
  const float* eub  = (const float*)d_in[7];
  const float* dgw  = (const float*)d_in[8];
  const float* dgb  = (const float*)d_in[9];
  const float* duw  = (const float*)d_in[10];
  const float* dub  = (const float*)d_in[11];
  const float* pw   = (const float*)d_in[12];
  const float* pb   = (const float*)d_in[13];
  float* out = (float*)d_out;

  char* wsb = (char*)d_ws;
  size_t off = 0;
  auto alloc = [&](size_t bytes) {
    void* p = wsb + off;
    off = (off + bytes + 255) & ~(size_t)255;
    return p;
  };
  float* Gf = (float*)alloc((size_t)Nn * Nn * 4);
  u16* S1h = (u16*)alloc((size_t)Nn * Nn * 2);
  u16* S1l = (u16*)alloc((size_t)Nn * Nn * 2);
  u16* S2h = (u16*)alloc((size_t)Nn * Nn * 2);
  u16* Sth = (u16*)alloc((size_t)Nn * Nn * 2);
  u16* Stl = (u16*)alloc((size_t)Nn * Nn * 2);
  float* Hst = (float*)alloc((size_t)NB * Hc * 4);
  u16* XAh = (u16*)alloc((size_t)(NB + 4) * SA * 2);
  u16* Xth = (u16*)alloc((size_t)Bc * Cc * Nn * 2);
  u16* Rb = (u16*)alloc((size_t)NB * Hc * 2);
  u16* DEh = (u16*)alloc((size_t)Nn * KD * 2);
  u16* DEl = (u16*)alloc((size_t)Nn * KD * 2);
  u16* WgeH = (u16*)alloc(128 * KP * 2); u16* WgeL = (u16*)alloc(128 * KP * 2);
  u16* WueH = (u16*)alloc(64 * KP * 2);  u16* WueL = (u16*)alloc(64 * KP * 2);
  u16* WgdH = (u16*)alloc(128 * KP * 2); u16* WgdL = (u16*)alloc(128 * KP * 2);
  u16* WudH = (u16*)alloc(64 * KP * 2);  u16* WudL = (u16*)alloc(64 * KP * 2);

  hipMemsetAsync(Hst, 0, (size_t)NB * Hc * 4, stream);
  hipMemsetAsync(XAh, 0, (size_t)(NB + 4) * SA * 2, stream);
  hipMemsetAsync(Xth, 0, (size_t)Bc * Cc * Nn * 2, stream);

  k_prep_wt<<<(128 * KP + 255) / 256, 256, 0, stream>>>(egw, 65, 128, WgeH, WgeL);
  k_prep_wt<<<(64 * KP + 255) / 256, 256, 0, stream>>>(euw, 65, 64, WueH, WueL);
  k_prep_wt<<<(128 * KP + 255) / 256, 256, 0, stream>>>(dgw, 66, 128, WgdH, WgdL);
  k_prep_wt<<<(64 * KP + 255) / 256, 256, 0, stream>>>(duw, 66, 64, WudH, WudL);

  // encoder supports
  k_gram<<<dim3(16, 16), 256, 0, stream>>>(emb, Ec, Gf);
  k_softmax<<<Nn, 256, 0, stream>>>(Gf, S1h, S1l);
  k_tr2<<<dim3(16, 16), 256, 0, stream>>>(S1h, S1l, Sth, Stl);
  k_s2_mfma<<<dim3(8, 16), 256, 0, stream>>>(S1h, S1l, Sth, Stl, S2h);

  const int gNB = NB / 256;

  for (int t = 0; t < Tc; t++) {
    k_fill_enc<<<gNB, 256, 0, stream>>>(x, XAh, Xth, t);
    k_ygemm<<<264, 256, 0, stream>>>(S1h, S2h, Xth, XAh);
    k_gate<<<512, 256, 0, stream>>>(XAh, WgeH, WgeL, egb, Hst, Rb, XAh, Xth, 1);
    k_ygemm<<<264, 256, 0, stream>>>(S1h, S2h, Xth, XAh);
    k_upd<<<512, 256, 0, stream>>>(XAh, WueH, WueL, eub, Rb, Hst, XAh, Xth,
                                   (t == Tc - 1) ? 2 : 1);
  }

  // decoder supports
  k_de<<<(Nn * KD + 255) / 256, 256, 0, stream>>>(Hst, fce, DEh, DEl);
  k_gram_mfma<<<dim3(8, 16), 256, 0, stream>>>(DEh, DEl, Gf);
  k_softmax<<<Nn, 256, 0, stream>>>(Gf, S1h, S1l);
  k_tr2<<<dim3(16, 16), 256, 0, stream>>>(S1h, S1l, Sth, Stl);
  k_s2_mfma<<<dim3(8, 16), 256, 0, stream>>>(S1h, S1l, Sth, Stl, S2h);
  k_dec_init<<<gNB, 256, 0, stream>>>(x, ycov, XAh, Xth);

  for (int t = 0; t < Tc; t++) {
    k_ygemm<<<264, 256, 0, stream>>>(S1h, S2h, Xth, XAh);
    k_gate<<<512, 256, 0, stream>>>(XAh, WgdH, WgdL, dgb, Hst, Rb, XAh, Xth, 2);
    k_ygemm<<<264, 256, 0, stream>>>(S1h, S2h, Xth, XAh);
    k_upd<<<512, 256, 0, stream>>>(XAh, WudH, WudL, dub, Rb, Hst, XAh, Xth, 2);
    k_proj_fill<<<gNB, 256, 0, stream>>>(Hst, pw, pb, ycov, XAh, Xth, out, t);
  }
}

// Round 12
// 3321.630 us; speedup vs baseline: 2.9389x; 1.0023x over previous
//
#include <hip/hip_runtime.h>
#include <math.h>

typedef __attribute__((ext_vector_type(8))) short bf16x8;
typedef __attribute__((ext_vector_type(4))) float f32x4;
typedef unsigned short u16;

namespace {
constexpr int Bc = 64, Tc = 12, Nn = 1024, Hc = 64, Ec = 10;
constexpr int NB = Nn * Bc;  // 65536
constexpr int Cc = 66;       // unified channel count (enc uses 65, col 65 zeroed)
constexpr int SA = 208;      // XA row stride ([X(66)|Y1(66)|Y2(66)|pad10])
constexpr int KP = 224;      // padded K for gate/update GEMMs (7 x 32)
constexpr int KD = Bc * Ec;  // 640, dec gram K
constexpr int TN = Tc * Nn;  // 12288
// Row index convention: rid = b*Nn + n  (b outer, n inner).
}

#define SWZ(r) (((r) >> 1) & 3)
#define SW8(r) ((r) & 7)

__device__ __forceinline__ void gld16(const void* g, void* l) {
  __builtin_amdgcn_global_load_lds(
      (const __attribute__((address_space(1))) void*)g,
      (__attribute__((address_space(3))) void*)l, 16, 0, 0);
}

__device__ __forceinline__ void split_bf(float v, u16& h, u16& l) {
  unsigned u = __float_as_uint(v);
  unsigned hu = (u + 0x7FFFu + ((u >> 16) & 1u)) & 0xFFFF0000u;
  h = (u16)(hu >> 16);
  float r = v - __uint_as_float(hu);
  unsigned u2 = __float_as_uint(r);
  l = (u16)((u2 + 0x7FFFu + ((u2 >> 16) & 1u)) >> 16);
}
__device__ __forceinline__ u16 bf_rne(float v) {
  unsigned u = __float_as_uint(v);
  return (u16)((u + 0x7FFFu + ((u >> 16) & 1u)) >> 16);
}
__device__ __forceinline__ float bf_to_f(u16 v) {
  return __uint_as_float(((unsigned)v) << 16);
}
__device__ __forceinline__ bf16x8 ldfrag(const u16* p) { return *(const bf16x8*)p; }

// ---------- enc gram: G = emb @ emb^T (Kd small, fp32) ----------
__global__ __launch_bounds__(256) void k_gram(const float* __restrict__ in, int Kd,
                                              float* __restrict__ G) {
  __shared__ float At[16][64];
  __shared__ float Bt[16][64];
  int i0 = blockIdx.y * 64, j0 = blockIdx.x * 64;
  int tx = threadIdx.x & 15, ty = threadIdx.x >> 4;
  float acc[4][4] = {};
  for (int k0 = 0; k0 < Kd; k0 += 16) {
    for (int u = threadIdx.x; u < 1024; u += 256) {
      int i = u >> 4, k = u & 15;
      At[k][i] = (k0 + k < Kd) ? in[(size_t)(i0 + i) * Kd + k0 + k] : 0.f;
    }
    for (int u = threadIdx.x; u < 1024; u += 256) {
      int j = u >> 4, k = u & 15;
      Bt[k][j] = (k0 + k < Kd) ? in[(size_t)(j0 + j) * Kd + k0 + k] : 0.f;
    }
    __syncthreads();
#pragma unroll
    for (int kk = 0; kk < 16; kk++) {
      float a[4], b[4];
#pragma unroll
      for (int p = 0; p < 4; p++) a[p] = At[kk][ty * 4 + p];
#pragma unroll
      for (int q = 0; q < 4; q++) b[q] = Bt[kk][tx * 4 + q];
#pragma unroll
      for (int p = 0; p < 4; p++)
#pragma unroll
        for (int q = 0; q < 4; q++) acc[p][q] = fmaf(a[p], b[q], acc[p][q]);
    }
    __syncthreads();
  }
  for (int p = 0; p < 4; p++)
    for (int q = 0; q < 4; q++)
      G[(size_t)(i0 + ty * 4 + p) * Nn + j0 + tx * 4 + q] = acc[p][q];
}

// ---------- dec gram via split-MFMA: G = DE @ DE^T ----------
__global__ __launch_bounds__(256) void k_gram_mfma(const u16* __restrict__ Dh,
                                                   const u16* __restrict__ Dl,
                                                   float* __restrict__ G) {
  __shared__ u16 lds[12288];
  const int tid = threadIdx.x;
  const int wave = tid >> 6, lane = tid & 63;
  const int i0 = blockIdx.y * 64;
  const int j0 = blockIdx.x * 128;
  const int wy = wave >> 1, wx = wave & 1;
  const int m = lane & 15, quad = lane >> 4;

  f32x4 acc[2][4];
  f32x4 z4 = {0.f, 0.f, 0.f, 0.f};
#pragma unroll
  for (int a = 0; a < 2; a++)
#pragma unroll
    for (int q = 0; q < 4; q++) acc[a][q] = z4;

  const int ar = tid >> 2;
  const int akc = (tid & 3) ^ SWZ(ar);

  for (int k0 = 0; k0 < KD; k0 += 32) {
    gld16(Dh + (size_t)(i0 + ar) * KD + k0 + akc * 8, &lds[wave * 512]);
    gld16(Dl + (size_t)(i0 + ar) * KD + k0 + akc * 8, &lds[2048 + wave * 512]);
#pragma unroll
    for (int p = 0; p < 2; p++) {
      int r = p * 64 + (tid >> 2);
      int kc = (tid & 3) ^ SWZ(r);
      gld16(Dh + (size_t)(j0 + r) * KD + k0 + kc * 8, &lds[4096 + p * 2048 + wave * 512]);
      gld16(Dl + (size_t)(j0 + r) * KD + k0 + kc * 8, &lds[8192 + p * 2048 + wave * 512]);
    }
    __syncthreads();

    bf16x8 ah[2], al[2], bh[4], bl[4];
#pragma unroll
    for (int mb = 0; mb < 2; mb++) {
      int r = wy * 32 + mb * 16 + m;
      int ci = r * 4 + (quad ^ SWZ(r));
      ah[mb] = *(const bf16x8*)&lds[ci * 8];
      al[mb] = *(const bf16x8*)&lds[2048 + ci * 8];
    }
#pragma unroll
    for (int nb = 0; nb < 4; nb++) {
      int rj = wx * 64 + nb * 16 + m;
      int cj = rj * 4 + (quad ^ SWZ(rj));
      bh[nb] = *(const bf16x8*)&lds[4096 + cj * 8];
      bl[nb] = *(const bf16x8*)&lds[8192 + cj * 8];
    }
#pragma unroll
    for (int mb = 0; mb < 2; mb++)
#pragma unroll
      for (int nb = 0; nb < 4; nb++) {
        acc[mb][nb] = __builtin_amdgcn_mfma_f32_16x16x32_bf16(ah[mb], bh[nb], acc[mb][nb], 0, 0, 0);
        acc[mb][nb] = __builtin_amdgcn_mfma_f32_16x16x32_bf16(ah[mb], bl[nb], acc[mb][nb], 0, 0, 0);
        acc[mb][nb] = __builtin_amdgcn_mfma_f32_16x16x32_bf16(al[mb], bh[nb], acc[mb][nb], 0, 0, 0);
      }
    __syncthreads();
  }

#pragma unroll
  for (int mb = 0; mb < 2; mb++)
#pragma unroll
    for (int nb = 0; nb < 4; nb++) {
      int col = j0 + wx * 64 + nb * 16 + m;
#pragma unroll
      for (int p = 0; p < 4; p++) {
        int row = i0 + wy * 32 + mb * 16 + quad * 4 + p;
        G[(size_t)row * Nn + col] = acc[mb][nb][p];
      }
    }
}

// ---------- S = row_softmax(relu(G)) -> split to S1h/S1l ----------
__global__ __launch_bounds__(256) void k_softmax(const float* __restrict__ G,
                                                 u16* __restrict__ S1h,
                                                 u16* __restrict__ S1l) {
  __shared__ float sred[8];
  int n = blockIdx.x;
  float v[4];
#pragma unroll
  for (int i = 0; i < 4; i++)
    v[i] = fmaxf(G[(size_t)n * Nn + threadIdx.x + i * 256], 0.f);
  float mx = fmaxf(fmaxf(v[0], v[1]), fmaxf(v[2], v[3]));
  for (int off = 32; off > 0; off >>= 1) mx = fmaxf(mx, __shfl_down(mx, off));
  if ((threadIdx.x & 63) == 0) sred[threadIdx.x >> 6] = mx;
  __syncthreads();
  float rmax = fmaxf(fmaxf(sred[0], sred[1]), fmaxf(sred[2], sred[3]));
  float s = 0.f;
#pragma unroll
  for (int i = 0; i < 4; i++) { v[i] = expf(v[i] - rmax); s += v[i]; }
  for (int off = 32; off > 0; off >>= 1) s += __shfl_down(s, off);
  if ((threadIdx.x & 63) == 0) sred[4 + (threadIdx.x >> 6)] = s;
  __syncthreads();
  float inv = 1.f / (sred[4] + sred[5] + sred[6] + sred[7]);
#pragma unroll
  for (int i = 0; i < 4; i++) {
    u16 h, l;
    split_bf(v[i] * inv, h, l);
    size_t a = (size_t)n * Nn + threadIdx.x + i * 256;
    S1h[a] = h; S1l[a] = l;
  }
}

// ---------- transpose S1h/S1l -> Sth/Stl ----------
__global__ __launch_bounds__(256) void k_tr2(const u16* __restrict__ Ah,
                                             const u16* __restrict__ Al,
                                             u16* __restrict__ Th, u16* __restrict__ Tl) {
  __shared__ u16 sm[64][72];
  int i0 = blockIdx.y * 64, j0 = blockIdx.x * 64;
  int tid = threadIdx.x;
  for (int pass = 0; pass < 2; pass++) {
    const u16* src = pass ? Al : Ah;
    u16* dst = pass ? Tl : Th;
    for (int u = tid; u < 4096; u += 256) {
      int i = u >> 6, c = u & 63;
      sm[i][c] = src[(size_t)(i0 + i) * Nn + j0 + c];
    }
    __syncthreads();
    for (int u = tid; u < 4096; u += 256) {
      int c = u >> 6, i = u & 63;
      dst[(size_t)(j0 + c) * Nn + i0 + i] = sm[i][c];
    }
    __syncthreads();
  }
}

// ---------- S2 = 2*S@S - I via direct-fragment split MFMA (3-term, bf16 out) ----------
// 128 blocks 1D, XCD-clustered: xcd = blk&7 -> i0 pair {2*xcd, 2*xcd+1}.
__global__ __launch_bounds__(256) void k_s2_mfma(const u16* __restrict__ S1h,
                                                 const u16* __restrict__ S1l,
                                                 const u16* __restrict__ Sth,
                                                 const u16* __restrict__ Stl,
                                                 u16* __restrict__ S2h) {
  const int tid = threadIdx.x;
  const int wave = tid >> 6, lane = tid & 63;
  const int blk = blockIdx.x;
  const int s = blk >> 3;
  const int i0 = ((blk & 7) * 2 + (s & 1)) * 64;
  const int j0 = (s >> 1) * 128;
  const int wy = wave >> 1, wx = wave & 1;
  const int m = lane & 15, quad = lane >> 4;

  const size_t aoff = (size_t)(i0 + wy * 32 + m) * Nn + quad * 8;
  const size_t boff = (size_t)(j0 + wx * 64 + m) * Nn + quad * 8;

  f32x4 acc[2][4];
  f32x4 z4 = {0.f, 0.f, 0.f, 0.f};
#pragma unroll
  for (int a = 0; a < 2; a++)
#pragma unroll
    for (int q = 0; q < 4; q++) acc[a][q] = z4;

  bf16x8 fAh[2][2], fAl[2][2], fBh[2][4], fBl[2][4];
  auto ld = [&](int k0, int sb) {
#pragma unroll
    for (int mb = 0; mb < 2; mb++) {
      fAh[sb][mb] = ldfrag(S1h + aoff + (size_t)mb * 16 * Nn + k0);
      fAl[sb][mb] = ldfrag(S1l + aoff + (size_t)mb * 16 * Nn + k0);
    }
#pragma unroll
    for (int nb = 0; nb < 4; nb++) {
      fBh[sb][nb] = ldfrag(Sth + boff + (size_t)nb * 16 * Nn + k0);
      fBl[sb][nb] = ldfrag(Stl + boff + (size_t)nb * 16 * Nn + k0);
    }
  };
  ld(0, 0);
#pragma unroll 2
  for (int kt = 0; kt < 32; kt++) {
    int cur = kt & 1;
    if (kt < 31) ld((kt + 1) * 32, cur ^ 1);
#pragma unroll
    for (int mb = 0; mb < 2; mb++)
#pragma unroll
      for (int nb = 0; nb < 4; nb++) {
        acc[mb][nb] = __builtin_amdgcn_mfma_f32_16x16x32_bf16(fAh[cur][mb], fBh[cur][nb], acc[mb][nb], 0, 0, 0);
        acc[mb][nb] = __builtin_amdgcn_mfma_f32_16x16x32_bf16(fAh[cur][mb], fBl[cur][nb], acc[mb][nb], 0, 0, 0);
        acc[mb][nb] = __builtin_amdgcn_mfma_f32_16x16x32_bf16(fAl[cur][mb], fBh[cur][nb], acc[mb][nb], 0, 0, 0);
      }
  }

#pragma unroll
  for (int mb = 0; mb < 2; mb++)
#pragma unroll
    for (int nb = 0; nb < 4; nb++) {
      int col = j0 + wx * 64 + nb * 16 + m;
#pragma unroll
      for (int p = 0; p < 4; p++) {
        int row = i0 + wy * 32 + mb * 16 + quad * 4 + p;
        float v = 2.f * acc[mb][nb][p] - (row == col ? 1.f : 0.f);
        S2h[(size_t)row * Nn + col] = bf_rne(v);
      }
    }
}

// ---------- Wt prep (split hi/lo) ----------
__global__ __launch_bounds__(256) void k_prep_wt(const float* __restrict__ W, int Csrc,
                                                 int ncol, u16* __restrict__ Wh,
                                                 u16* __restrict__ Wl) {
  int idx = blockIdx.x * 256 + threadIdx.x;
  if (idx >= ncol * KP) return;
  int n = idx / KP, kp = idx % KP;
  int chunk = kp / Cc, c = kp % Cc;
  float v = 0.f;
  if (kp < 3 * Cc && c < Csrc) v = W[((size_t)chunk * Csrc + c) * ncol + n];
  u16 h, l;
  split_bf(v, h, l);
  Wh[idx] = h; Wl[idx] = l;
}

// ---------- fill enc: rid = b*Nn + n ----------
__global__ __launch_bounds__(256) void k_fill_enc(const float* __restrict__ x,
                                                  u16* __restrict__ XAh,
                                                  u16* __restrict__ Xth, int t) {
  int idx = blockIdx.x * 256 + threadIdx.x;
  if (idx >= NB) return;
  int n = idx & (Nn - 1), b = idx >> 10;
  u16 h = bf_rne(x[(size_t)b * TN + t * Nn + n]);
  XAh[(size_t)idx * SA] = h;
  Xth[(size_t)b * Cc * Nn + n] = h;
}

// ---------- dec init ----------
__global__ __launch_bounds__(256) void k_dec_init(const float* __restrict__ x,
                                                  const float* __restrict__ ycov,
                                                  u16* __restrict__ XAh,
                                                  u16* __restrict__ Xth) {
  int idx = blockIdx.x * 256 + threadIdx.x;
  if (idx >= NB) return;
  int n = idx & (Nn - 1), b = idx >> 10;
  u16 h0 = bf_rne(x[(size_t)b * TN + (size_t)(Tc - 1) * Nn + n]);
  u16 h1 = bf_rne(ycov[(size_t)b * TN + n]);
  XAh[(size_t)idx * SA] = h0;
  XAh[(size_t)idx * SA + 1] = h1;
  Xth[((size_t)b * Cc) * Nn + n] = h0;
  Xth[((size_t)b * Cc + 1) * Nn + n] = h1;
}

// ---------- ygemm: Y1 = S1@X, Y2 = S2@X. BK=64, single 48KB buffer, XCD i0-cluster ----------
// 264 blocks: i0 = (blk&7)*128; j0 = (blk>>3)*128. 16 barrier iterations.
// LDS (u16): S1 [0,8192) | S2 [8192,16384) | B [16384,24576); each 128 rows x 64 K.
__global__ __launch_bounds__(256, 2) void k_ygemm(const u16* __restrict__ S1h,
                                                  const u16* __restrict__ S2h,
                                                  const u16* __restrict__ Xth,
                                                  u16* __restrict__ XA) {
  __shared__ u16 lds[24576];  // 48KB
  const int tid = threadIdx.x;
  const int wave = tid >> 6;
  const int lane = tid & 63;
  const int blk = blockIdx.x;
  const int i0 = (blk & 7) * 128;
  const int j0 = (blk >> 3) * 128;
  const int wy = wave >> 1, wx = wave & 1;
  const int m = lane & 15, quad = lane >> 4;

  f32x4 acc1[4][4], acc2[4][4];
  f32x4 z4 = {0.f, 0.f, 0.f, 0.f};
#pragma unroll
  for (int a = 0; a < 4; a++)
#pragma unroll
    for (int q = 0; q < 4; q++) { acc1[a][q] = z4; acc2[a][q] = z4; }

  for (int k0 = 0; k0 < Nn; k0 += 64) {
    // stage: 1024 16B-chunks per matrix (128 rows x 8 chunks), 4 rounds of 256 lanes
#pragma unroll
    for (int c = 0; c < 4; c++) {
      int ci = c * 256 + tid;
      int r = ci >> 3, kc = (ci & 7) ^ SW8(r);
      gld16(S1h + (size_t)(i0 + r) * Nn + k0 + kc * 8, &lds[c * 2048 + wave * 512]);
      gld16(S2h + (size_t)(i0 + r) * Nn + k0 + kc * 8, &lds[8192 + c * 2048 + wave * 512]);
      gld16(Xth + (size_t)(j0 + r) * Nn + k0 + kc * 8, &lds[16384 + c * 2048 + wave * 512]);
    }
    __syncthreads();

#pragma unroll
    for (int ks = 0; ks < 2; ks++) {
      bf16x8 bfr[4];
#pragma unroll
      for (int nb = 0; nb < 4; nb++) {
        int rj = wx * 64 + nb * 16 + m;
        int cj = rj * 8 + ((ks * 4 + quad) ^ SW8(rj));
        bfr[nb] = *(const bf16x8*)&lds[16384 + cj * 8];
      }
      bf16x8 a1[4], a2[4];
#pragma unroll
      for (int mb = 0; mb < 4; mb++) {
        int r = wy * 64 + mb * 16 + m;
        int ci = r * 8 + ((ks * 4 + quad) ^ SW8(r));
        a1[mb] = *(const bf16x8*)&lds[ci * 8];
        a2[mb] = *(const bf16x8*)&lds[8192 + ci * 8];
      }
#pragma unroll
      for (int mb = 0; mb < 4; mb++)
#pragma unroll
        for (int nb = 0; nb < 4; nb++) {
          acc1[mb][nb] = __builtin_amdgcn_mfma_f32_16x16x32_bf16(a1[mb], bfr[nb], acc1[mb][nb], 0, 0, 0);
          acc2[mb][nb] = __builtin_amdgcn_mfma_f32_16x16x32_bf16(a2[mb], bfr[nb], acc2[mb][nb], 0, 0, 0);
        }
    }
    __syncthreads();
  }

  // epilogue: row = n, col = (bb, cc); XA row rid = bb*Nn + n
#pragma unroll
  for (int mb = 0; mb < 4; mb++)
#pragma unroll
    for (int nb = 0; nb < 4; nb++) {
      int col = j0 + wx * 64 + nb * 16 + m;
      int bb = col / Cc, cc = col % Cc;
#pragma unroll
      for (int p = 0; p < 4; p++) {
        int n = i0 + wy * 64 + mb * 16 + quad * 4 + p;
        size_t base = ((size_t)bb * Nn + n) * SA;
        XA[base + 66 + cc] = bf_rne(acc1[mb][nb][p]);
        XA[base + 132 + cc] = bf_rne(acc2[mb][nb][p]);
      }
    }
}

// ---------- gate: sigmoid(XA@W^T+b); A single bf16, W split 2-term ----------
__global__ __launch_bounds__(256) void k_gate(const u16* __restrict__ XA,
                                              const u16* __restrict__ Wh, const u16* __restrict__ Wl,
                                              const float* __restrict__ bias,
                                              const float* __restrict__ hst,
                                              u16* __restrict__ Rb,
                                              u16* __restrict__ XAo,
                                              u16* __restrict__ Xth, int off) {
  __shared__ u16 lds[12288];  // A 4096 | Wh 4096 | Wl 4096
  const int tid = threadIdx.x;
  const int wave = tid >> 6, lane = tid & 63;
  const int r0 = blockIdx.x * 128;
  const int wy = wave >> 1, wx = wave & 1;
  const int m = lane & 15, quad = lane >> 4;

  f32x4 acc[4][4];
  f32x4 z4 = {0.f, 0.f, 0.f, 0.f};
#pragma unroll
  for (int a = 0; a < 4; a++)
#pragma unroll
    for (int q = 0; q < 4; q++) acc[a][q] = z4;

  for (int kt = 0; kt < 7; kt++) {
    int k0 = kt * 32;
#pragma unroll
    for (int c = 0; c < 2; c++) {
      int ci = c * 256 + tid;
      int r = ci >> 2, kc = (ci & 3) ^ SWZ(r);
      gld16(XA + (size_t)(r0 + r) * SA + k0 + kc * 8, &lds[c * 2048 + wave * 512]);
      gld16(Wh + (size_t)r * KP + k0 + kc * 8, &lds[4096 + c * 2048 + wave * 512]);
      gld16(Wl + (size_t)r * KP + k0 + kc * 8, &lds[8192 + c * 2048 + wave * 512]);
    }
    __syncthreads();

    bf16x8 af[4], bh[4], bl[4];
#pragma unroll
    for (int mb = 0; mb < 4; mb++) {
      int r = wy * 64 + mb * 16 + m;
      int ci = r * 4 + (quad ^ SWZ(r));
      af[mb] = *(const bf16x8*)&lds[ci * 8];
    }
#pragma unroll
    for (int nb = 0; nb < 4; nb++) {
      int rj = wx * 64 + nb * 16 + m;
      int cj = rj * 4 + (quad ^ SWZ(rj));
      bh[nb] = *(const bf16x8*)&lds[4096 + cj * 8];
      bl[nb] = *(const bf16x8*)&lds[8192 + cj * 8];
    }
#pragma unroll
    for (int mb = 0; mb < 4; mb++)
#pragma unroll
      for (int nb = 0; nb < 4; nb++) {
        acc[mb][nb] = __builtin_amdgcn_mfma_f32_16x16x32_bf16(af[mb], bh[nb], acc[mb][nb], 0, 0, 0);
        acc[mb][nb] = __builtin_amdgcn_mfma_f32_16x16x32_bf16(af[mb], bl[nb], acc[mb][nb], 0, 0, 0);
      }
    __syncthreads();
  }

#pragma unroll
  for (int mb = 0; mb < 4; mb++)
#pragma unroll
    for (int nb = 0; nb < 4; nb++) {
      int col = wx * 64 + nb * 16 + m;
      float bv = bias[col];
#pragma unroll
      for (int p = 0; p < 4; p++) {
        int rid = r0 + wy * 64 + mb * 16 + quad * 4 + p;
        float sg = 1.f / (1.f + expf(-(acc[mb][nb][p] + bv)));
        if (col < 64) {
          float v = sg * hst[(size_t)rid * 64 + col];
          u16 vh = bf_rne(v);
          XAo[(size_t)rid * SA + off + col] = vh;
          int n = rid & (Nn - 1), b = rid >> 10;
          Xth[((size_t)b * Cc + off + col) * Nn + n] = vh;
        } else {
          Rb[(size_t)rid * 64 + col - 64] = bf_rne(sg);
        }
      }
    }
}

// ---------- update: hc=tanh(XA@Wu^T+b); h=r*h+(1-r)*hc; optional enc-fill of x[tnext] ----------
__global__ __launch_bounds__(256) void k_upd(const u16* __restrict__ XA,
                                             const u16* __restrict__ Wh, const u16* __restrict__ Wl,
                                             const float* __restrict__ bias,
                                             const u16* __restrict__ Rb,
                                             float* __restrict__ h,
                                             u16* __restrict__ XAo,
                                             u16* __restrict__ Xth,
                                             const float* __restrict__ xsrc, int tnext,
                                             int off_next) {
  __shared__ u16 lds[8192];  // A 4096 | Wh 2048 | Wl 2048
  const int tid = threadIdx.x;
  const int wave = tid >> 6, lane = tid & 63;
  const int r0 = blockIdx.x * 128;
  const int wy = wave >> 1, wx = wave & 1;
  const int m = lane & 15, quad = lane >> 4;

  f32x4 acc[4][2];
  f32x4 z4 = {0.f, 0.f, 0.f, 0.f};
#pragma unroll
  for (int a = 0; a < 4; a++) { acc[a][0] = z4; acc[a][1] = z4; }

  for (int kt = 0; kt < 7; kt++) {
    int k0 = kt * 32;
#pragma unroll
    for (int c = 0; c < 2; c++) {
      int ci = c * 256 + tid;
      int r = ci >> 2, kc = (ci & 3) ^ SWZ(r);
      gld16(XA + (size_t)(r0 + r) * SA + k0 + kc * 8, &lds[c * 2048 + wave * 512]);
    }
    {
      int ci = tid;
      int r = ci >> 2, kc = (ci & 3) ^ SWZ(r);
      gld16(Wh + (size_t)r * KP + k0 + kc * 8, &lds[4096 + wave * 512]);
      gld16(Wl + (size_t)r * KP + k0 + kc * 8, &lds[6144 + wave * 512]);
    }
    __syncthreads();

    bf16x8 af[4], bh[2], bl[2];
#pragma unroll
    for (int mb = 0; mb < 4; mb++) {
      int r = wy * 64 + mb * 16 + m;
      int ci = r * 4 + (quad ^ SWZ(r));
      af[mb] = *(const bf16x8*)&lds[ci * 8];
    }
#pragma unroll
    for (int nb = 0; nb < 2; nb++) {
      int rj = wx * 32 + nb * 16 + m;
      int cj = rj * 4 + (quad ^ SWZ(rj));
      bh[nb] = *(const bf16x8*)&lds[4096 + cj * 8];
      bl[nb] = *(const bf16x8*)&lds[6144 + cj * 8];
    }
#pragma unroll
    for (int mb = 0; mb < 4; mb++)
#pragma unroll
      for (int nb = 0; nb < 2; nb++) {
        acc[mb][nb] = __builtin_amdgcn_mfma_f32_16x16x32_bf16(af[mb], bh[nb], acc[mb][nb], 0, 0, 0);
        acc[mb][nb] = __builtin_amdgcn_mfma_f32_16x16x32_bf16(af[mb], bl[nb], acc[mb][nb], 0, 0, 0);
      }
    __syncthreads();
  }

#pragma unroll
  for (int mb = 0; mb < 4; mb++)
#pragma unroll
    for (int nb = 0; nb < 2; nb++) {
      int col = wx * 32 + nb * 16 + m;
      float bv = bias[col];
#pragma unroll
      for (int p = 0; p < 4; p++) {
        int rid = r0 + wy * 64 + mb * 16 + quad * 4 + p;
        float hc = tanhf(acc[mb][nb][p] + bv);
        size_t idx = (size_t)rid * 64 + col;
        float rr = bf_to_f(Rb[idx]);
        float hn = rr * h[idx] + (1.f - rr) * hc;
        h[idx] = hn;
        u16 vh = bf_rne(hn);
        XAo[(size_t)rid * SA + off_next + col] = vh;
        int n = rid & (Nn - 1), b = rid >> 10;
        Xth[((size_t)b * Cc + off_next + col) * Nn + n] = vh;
        if (col == 0 && xsrc != nullptr) {
          u16 xv = bf_rne(xsrc[(size_t)b * TN + (size_t)tnext * Nn + n]);
          XAo[(size_t)rid * SA] = xv;
          Xth[((size_t)b * Cc) * Nn + n] = xv;
        }
      }
    }
}

// ---------- de = h @ FC_E, split output ----------
__global__ __launch_bounds__(256) void k_de(const float* __restrict__ h,
                                            const float* __restrict__ fc,
                                            u16* __restrict__ Dh, u16* __restrict__ Dl) {
  __shared__ float fcs[Hc * Ec];
  for (int j = threadIdx.x; j < Hc * Ec; j += 256) fcs[j] = fc[j];
  __syncthreads();
  int idx = blockIdx.x * 256 + threadIdx.x;
  if (idx >= Nn * KD) return;
  int n = idx / KD;
  int rem = idx % KD;
  int b = rem / Ec, e = rem % Ec;
  const float* hp = h + ((size_t)b * Nn + n) * Hc;
  float acc = 0.f;
#pragma unroll 8
  for (int hh = 0; hh < Hc; hh++) acc = fmaf(hp[hh], fcs[hh * Ec + e], acc);
  u16 vh, vl;
  split_bf(acc, vh, vl);
  Dh[idx] = vh; Dl[idx] = vl;
}

// ---------- proj + fill next dec step ----------
__global__ __launch_bounds__(256) void k_proj_fill(const float* __restrict__ h,
                                                   const float* __restrict__ pw,
                                                   const float* __restrict__ pb,
                                                   const float* __restrict__ ycov,
                                                   u16* __restrict__ XAh,
                                                   u16* __restrict__ Xth,
                                                   float* __restrict__ out, int t) {
  int idx = blockIdx.x * 256 + threadIdx.x;
  if (idx >= NB) return;
  int n = idx & (Nn - 1), b = idx >> 10;
  const float* hp = h + (size_t)idx * Hc;
  float acc = pb[0];
#pragma unroll 8
  for (int i = 0; i < Hc; i++) acc = fmaf(hp[i], pw[i], acc);
  out[(size_t)b * TN + (size_t)t * Nn + n] = acc;
  if (t + 1 < Tc) {
    u16 h0 = bf_rne(acc);
    u16 h1 = bf_rne(ycov[(size_t)b * TN + (size_t)(t + 1) * Nn + n]);
    XAh[(size_t)idx * SA] = h0;
    XAh[(size_t)idx * SA + 1] = h1;
    Xth[((size_t)b * Cc) * Nn + n] = h0;
    Xth[((size_t)b * Cc + 1) * Nn + n] = h1;
  }
}

extern "C" void kernel_launch(void* const* d_in, const int* in_sizes, int n_in,
                              void* d_out, int out_size, void* d_ws, size_t ws_size,
                              hipStream_t stream) {
  (void)in_sizes; (void)n_in; (void)out_size; (void)ws_size;
  const float* x    = (const float*)d_in[0];
  const float* ycov = (const float*)d_in[1];
  const float* emb  = (const float*)d_in[2];
  const float* fce  = (const float*)d_in[3];
  const float* egw  = (const float*)d_in[4];
  const float* egb  = (const float*)d_in[5];
  const float* euw  = (const float*)d_in[6];
  const float* eub  = (const float*)d_in[7];
  const float* dgw  = (const float*)d_in[8];
  const float* dgb  = (const float*)d_in[9];
  const float* duw  = (const float*)d_in[10];
  const float* dub  = (const float*)d_in[11];
  const float* pw   = (const float*)d_in[12];
  const float* pb   = (const float*)d_in[13];
  float* out = (float*)d_out;

  char* wsb = (char*)d_ws;
  size_t off = 0;
  auto alloc = [&](size_t bytes) {
    void* p = wsb + off;
    off = (off + bytes + 255) & ~(size_t)255;
    return p;
  };
  float* Gf = (float*)alloc((size_t)Nn * Nn * 4);
  u16* S1h = (u16*)alloc((size_t)Nn * Nn * 2);
  u16* S1l = (u16*)alloc((size_t)Nn * Nn * 2);
  u16* S2h = (u16*)alloc((size_t)Nn * Nn * 2);
  u16* Sth = (u16*)alloc((size_t)Nn * Nn * 2);
  u16* Stl = (u16*)alloc((size_t)Nn * Nn * 2);
  float* Hst = (float*)alloc((size_t)NB * Hc * 4);
  u16* XAh = (u16*)alloc((size_t)(NB + 4) * SA * 2);
  u16* Xth = (u16*)alloc((size_t)Bc * Cc * Nn * 2);
  u16* Rb = (u16*)alloc((size_t)NB * Hc * 2);
  u16* DEh = (u16*)alloc((size_t)Nn * KD * 2);
  u16* DEl = (u16*)alloc((size_t)Nn * KD * 2);
  u16* WgeH = (u16*)alloc(128 * KP * 2); u16* WgeL = (u16*)alloc(128 * KP * 2);
  u16* WueH = (u16*)alloc(64 * KP * 2);  u16* WueL = (u16*)alloc(64 * KP * 2);
  u16* WgdH = (u16*)alloc(128 * KP * 2); u16* WgdL = (u16*)alloc(128 * KP * 2);
  u16* WudH = (u16*)alloc(64 * KP * 2);  u16* WudL = (u16*)alloc(64 * KP * 2);

  hipMemsetAsync(Hst, 0, (size_t)NB * Hc * 4, stream);
  hipMemsetAsync(XAh, 0, (size_t)(NB + 4) * SA * 2, stream);
  hipMemsetAsync(Xth, 0, (size_t)Bc * Cc * Nn * 2, stream);

  k_prep_wt<<<(128 * KP + 255) / 256, 256, 0, stream>>>(egw, 65, 128, WgeH, WgeL);
  k_prep_wt<<<(64 * KP + 255) / 256, 256, 0, stream>>>(euw, 65, 64, WueH, WueL);
  k_prep_wt<<<(128 * KP + 255) / 256, 256, 0, stream>>>(dgw, 66, 128, WgdH, WgdL);
  k_prep_wt<<<(64 * KP + 255) / 256, 256, 0, stream>>>(duw, 66, 64, WudH, WudL);

  // encoder supports
  k_gram<<<dim3(16, 16), 256, 0, stream>>>(emb, Ec, Gf);
  k_softmax<<<Nn, 256, 0, stream>>>(Gf, S1h, S1l);
  k_tr2<<<dim3(16, 16), 256, 0, stream>>>(S1h, S1l, Sth, Stl);
  k_s2_mfma<<<128, 256, 0, stream>>>(S1h, S1l, Sth, Stl, S2h);

  const int gNB = NB / 256;

  k_fill_enc<<<gNB, 256, 0, stream>>>(x, XAh, Xth, 0);
  for (int t = 0; t < Tc; t++) {
    k_ygemm<<<264, 256, 0, stream>>>(S1h, S2h, Xth, XAh);
    k_gate<<<512, 256, 0, stream>>>(XAh, WgeH, WgeL, egb, Hst, Rb, XAh, Xth, 1);
    k_ygemm<<<264, 256, 0, stream>>>(S1h, S2h, Xth, XAh);
    k_upd<<<512, 256, 0, stream>>>(XAh, WueH, WueL, eub, Rb, Hst, XAh, Xth,
                                   (t + 1 < Tc) ? x : nullptr, t + 1,
                                   (t == Tc - 1) ? 2 : 1);
  }

  // decoder supports
  k_de<<<(Nn * KD + 255) / 256, 256, 0, stream>>>(Hst, fce, DEh, DEl);
  k_gram_mfma<<<dim3(8, 16), 256, 0, stream>>>(DEh, DEl, Gf);
  k_softmax<<<Nn, 256, 0, stream>>>(Gf, S1h, S1l);
  k_tr2<<<dim3(16, 16), 256, 0, stream>>>(S1h, S1l, Sth, Stl);
  k_s2_mfma<<<128, 256, 0, stream>>>(S1h, S1l, Sth, Stl, S2h);
  k_dec_init<<<gNB, 256, 0, stream>>>(x, ycov, XAh, Xth);

  for (int t = 0; t < Tc; t++) {
    k_ygemm<<<264, 256, 0, stream>>>(S1h, S2h, Xth, XAh);
    k_gate<<<512, 256, 0, stream>>>(XAh, WgdH, WgdL, dgb, Hst, Rb, XAh, Xth, 2);
    k_ygemm<<<264, 256, 0, stream>>>(S1h, S2h, Xth, XAh);
    k_upd<<<512, 256, 0, stream>>>(XAh, WudH, WudL, dub, Rb, Hst, XAh, Xth,
                                   nullptr, 0, 2);
    k_proj_fill<<<gNB, 256, 0, stream>>>(Hst, pw, pb, ycov, XAh, Xth, out, t);
  }
}